// Round 1
// baseline (790.224 us; speedup 1.0000x reference)
//
#include <hip/hip_runtime.h>
#include <math.h>

#define EPS_BN 1e-5f

constexpr int BATCH = 32;
constexpr int NPTS  = 2048;
constexpr int BP    = BATCH * NPTS;   // 65536

// ---------------- curvature: 5-NN mean distance -> 1/(1e-8+dmean) ----------------
__global__ __launch_bounds__(256) void curv_kernel(const float* __restrict__ x,
                                                   float* __restrict__ feat) {
  __shared__ float sx[NPTS], sy[NPTS], sz[NPTS];
  int b = blockIdx.y;
  const float* xb = x + (size_t)b * NPTS * 3;
  for (int i = threadIdx.x; i < NPTS; i += 256) {
    sx[i] = xb[i * 3 + 0];
    sy[i] = xb[i * 3 + 1];
    sz[i] = xb[i * 3 + 2];
  }
  __syncthreads();
  int row = blockIdx.x * 256 + threadIdx.x;
  float px = sx[row], py = sy[row], pz = sz[row];
  float nn[6];
#pragma unroll
  for (int j = 0; j < 6; j++) nn[j] = 3.4e38f;
  for (int j = 0; j < NPTS; j++) {
    float dx = px - sx[j], dy = py - sy[j], dz = pz - sz[j];
    float d2 = dx * dx + dy * dy + dz * dz;
    if (d2 < nn[5]) {
      nn[5] = d2;
#pragma unroll
      for (int t = 5; t > 0; t--) {
        float a = nn[t], bb = nn[t - 1];
        if (a < bb) { nn[t] = bb; nn[t - 1] = a; }
      }
    }
  }
  // nn[0] is self (0); mean of sqrt of the 5 nearest
  float dm = 0.2f * (sqrtf(nn[1]) + sqrtf(nn[2]) + sqrtf(nn[3]) + sqrtf(nn[4]) + sqrtf(nn[5]));
  float curv = 1.0f / (1e-8f + dm);
  size_t o = ((size_t)b * NPTS + row) * 4;
  feat[o + 0] = px;
  feat[o + 1] = py;
  feat[o + 2] = pz;
  feat[o + 3] = curv;
}

// ---------------- layer1: [BP,4] @ [4,64]^T + b -> z1 [BP,64] ----------------
__global__ __launch_bounds__(256) void gemm1_kernel(const float* __restrict__ feat,
                                                    const float* __restrict__ w,
                                                    const float* __restrict__ bias,
                                                    float* __restrict__ z1) {
  __shared__ float wT[4 * 64];
  int tid = threadIdx.x;
  {
    int k = tid >> 6, c = tid & 63;
    wT[k * 64 + c] = w[c * 4 + k];
  }
  __syncthreads();
  int g = blockIdx.x * 256 + tid;
  int row = g >> 6, col = g & 63;
  const float* fr = feat + (size_t)row * 4;
  float acc = bias[col];
#pragma unroll
  for (int k = 0; k < 4; k++) acc += fr[k] * wT[k * 64 + col];
  z1[g] = acc;
}

// ---------------- per-column sum/sumsq partials of [65536, C] ----------------
template <int C>
__global__ __launch_bounds__(256) void colstats_kernel(const float* __restrict__ z,
                                                       float* __restrict__ part) {
  const int RPB = 256;  // rows per block; grid = 256
  int r0 = blockIdx.x * RPB;
  int col = threadIdx.x % C;
  int rsub = threadIdx.x / C;
  const int rstep = 256 / C;
  float s = 0.f, q = 0.f;
  for (int r = rsub; r < RPB; r += rstep) {
    float v = z[(size_t)(r0 + r) * C + col];
    s += v;
    q += v * v;
  }
  __shared__ float ls[256], lq[256];
  ls[threadIdx.x] = s;
  lq[threadIdx.x] = q;
  __syncthreads();
  if (threadIdx.x < C) {
    float ss = 0.f, qq = 0.f;
#pragma unroll
    for (int i = 0; i < rstep; i++) {
      ss += ls[i * C + threadIdx.x];
      qq += lq[i * C + threadIdx.x];
    }
    part[(size_t)(blockIdx.x * C + threadIdx.x) * 2 + 0] = ss;
    part[(size_t)(blockIdx.x * C + threadIdx.x) * 2 + 1] = qq;
  }
}

template <int C>
__global__ __launch_bounds__(256) void bnfin_kernel(const float* __restrict__ part,
                                                    const float* __restrict__ g,
                                                    const float* __restrict__ be,
                                                    float* __restrict__ scale,
                                                    float* __restrict__ shift) {
  int c = blockIdx.x, tid = threadIdx.x;
  __shared__ float ls[256], lq[256];
  ls[tid] = part[(size_t)(tid * C + c) * 2 + 0];
  lq[tid] = part[(size_t)(tid * C + c) * 2 + 1];
  __syncthreads();
  for (int off = 128; off > 0; off >>= 1) {
    if (tid < off) { ls[tid] += ls[tid + off]; lq[tid] += lq[tid + off]; }
    __syncthreads();
  }
  if (tid == 0) {
    float m = ls[0] * (1.0f / 65536.0f);
    float v = lq[0] * (1.0f / 65536.0f) - m * m;
    float a = g[c] / sqrtf(v + EPS_BN);
    scale[c] = a;
    shift[c] = be[c] - m * a;
  }
}

// ---------------- layer2: relu(bn(z1)) @ [64,128]^T + b -> z2 [BP,128] ----------------
__global__ __launch_bounds__(256) void gemm2_kernel(const float* __restrict__ z1,
                                                    const float* __restrict__ s1,
                                                    const float* __restrict__ h1,
                                                    const float* __restrict__ w2,
                                                    const float* __restrict__ bias2,
                                                    float* __restrict__ z2) {
  __shared__ float As[32 * 65];
  __shared__ float Bs[128 * 65];
  int tid = threadIdx.x;
  int row0 = blockIdx.x * 32;
#pragma unroll
  for (int i = 0; i < 8; i++) {
    int idx = tid + i * 256;
    int r = idx >> 6, k = idx & 63;
    float v = z1[(size_t)(row0 + r) * 64 + k];
    As[r * 65 + k] = fmaxf(v * s1[k] + h1[k], 0.f);
  }
#pragma unroll
  for (int i = 0; i < 32; i++) {
    int idx = tid + i * 256;
    int c = idx >> 6, k = idx & 63;
    Bs[c * 65 + k] = w2[(size_t)c * 64 + k];
  }
  __syncthreads();
  int tr = tid & 7, tc = tid >> 3;  // rows: tr*4+j (0..31), cols: tc*4+l (0..127)
  float acc[4][4] = {};
  for (int k = 0; k < 64; k++) {
    float a[4], bb[4];
#pragma unroll
    for (int j = 0; j < 4; j++) a[j] = As[(tr * 4 + j) * 65 + k];
#pragma unroll
    for (int l = 0; l < 4; l++) bb[l] = Bs[(tc * 4 + l) * 65 + k];
#pragma unroll
    for (int j = 0; j < 4; j++)
#pragma unroll
      for (int l = 0; l < 4; l++) acc[j][l] += a[j] * bb[l];
  }
  float bb0 = bias2[tc * 4 + 0], bb1 = bias2[tc * 4 + 1];
  float bb2 = bias2[tc * 4 + 2], bb3 = bias2[tc * 4 + 3];
#pragma unroll
  for (int j = 0; j < 4; j++) {
    int row = row0 + tr * 4 + j;
    float4 v = make_float4(acc[j][0] + bb0, acc[j][1] + bb1, acc[j][2] + bb2, acc[j][3] + bb3);
    *(float4*)&z2[(size_t)row * 128 + tc * 4] = v;
  }
}

// ---------------- layer3: relu(bn(z2)) @ [128,1024]^T + b -> per-block stats only ----------------
__global__ __launch_bounds__(256) void gemm3_kernel(const float* __restrict__ z2,
                                                    const float* __restrict__ s2,
                                                    const float* __restrict__ h2,
                                                    const float* __restrict__ w3,
                                                    const float* __restrict__ bias3,
                                                    float* __restrict__ pS,
                                                    float* __restrict__ pQ,
                                                    float* __restrict__ pMx,
                                                    float* __restrict__ pMn) {
  __shared__ float As[64 * 65];
  __shared__ float Bs[64 * 65];
  __shared__ float scr[64 * 17];
  int tid = threadIdx.x;
  int row0 = blockIdx.y * 64, col0 = blockIdx.x * 64;
  int tr = tid & 15, tc = tid >> 4;  // rows: tr*4+j (0..63), cols: tc*4+l (0..63)
  float acc[4][4] = {};
  for (int ks = 0; ks < 128; ks += 64) {
    __syncthreads();
#pragma unroll
    for (int i = 0; i < 16; i++) {
      int idx = tid + i * 256;
      int r = idx >> 6, k = idx & 63;
      float v = z2[(size_t)(row0 + r) * 128 + ks + k];
      As[r * 65 + k] = fmaxf(v * s2[ks + k] + h2[ks + k], 0.f);
      Bs[r * 65 + k] = w3[(size_t)(col0 + r) * 128 + ks + k];
    }
    __syncthreads();
    for (int k = 0; k < 64; k++) {
      float a[4], bb[4];
#pragma unroll
      for (int j = 0; j < 4; j++) a[j] = As[(tr * 4 + j) * 65 + k];
#pragma unroll
      for (int l = 0; l < 4; l++) bb[l] = Bs[(tc * 4 + l) * 65 + k];
#pragma unroll
      for (int j = 0; j < 4; j++)
#pragma unroll
        for (int l = 0; l < 4; l++) acc[j][l] += a[j] * bb[l];
    }
  }
  int cbase = tc * 4;
  float bb[4];
#pragma unroll
  for (int l = 0; l < 4; l++) bb[l] = bias3[col0 + cbase + l];
#pragma unroll
  for (int j = 0; j < 4; j++)
#pragma unroll
    for (int l = 0; l < 4; l++) acc[j][l] += bb[l];

  // --- block reductions over the 64 rows, per column ---
  __syncthreads();
  // sum
#pragma unroll
  for (int l = 0; l < 4; l++)
    scr[(cbase + l) * 17 + tr] = acc[0][l] + acc[1][l] + acc[2][l] + acc[3][l];
  __syncthreads();
  if (tid < 64) {
    float s = 0.f;
#pragma unroll
    for (int i = 0; i < 16; i++) s += scr[tid * 17 + i];
    pS[(size_t)blockIdx.y * 1024 + col0 + tid] = s;
  }
  __syncthreads();
  // sumsq
#pragma unroll
  for (int l = 0; l < 4; l++)
    scr[(cbase + l) * 17 + tr] = acc[0][l] * acc[0][l] + acc[1][l] * acc[1][l] +
                                 acc[2][l] * acc[2][l] + acc[3][l] * acc[3][l];
  __syncthreads();
  if (tid < 64) {
    float s = 0.f;
#pragma unroll
    for (int i = 0; i < 16; i++) s += scr[tid * 17 + i];
    pQ[(size_t)blockIdx.y * 1024 + col0 + tid] = s;
  }
  __syncthreads();
  // max
#pragma unroll
  for (int l = 0; l < 4; l++)
    scr[(cbase + l) * 17 + tr] =
        fmaxf(fmaxf(acc[0][l], acc[1][l]), fmaxf(acc[2][l], acc[3][l]));
  __syncthreads();
  if (tid < 64) {
    float s = -3.4e38f;
#pragma unroll
    for (int i = 0; i < 16; i++) s = fmaxf(s, scr[tid * 17 + i]);
    pMx[(size_t)blockIdx.y * 1024 + col0 + tid] = s;
  }
  __syncthreads();
  // min
#pragma unroll
  for (int l = 0; l < 4; l++)
    scr[(cbase + l) * 17 + tr] =
        fminf(fminf(acc[0][l], acc[1][l]), fminf(acc[2][l], acc[3][l]));
  __syncthreads();
  if (tid < 64) {
    float s = 3.4e38f;
#pragma unroll
    for (int i = 0; i < 16; i++) s = fminf(s, scr[tid * 17 + i]);
    pMn[(size_t)blockIdx.y * 1024 + col0 + tid] = s;
  }
}

// ---------------- bn3 finalize + masked max-pool (affine is monotone) ----------------
__global__ __launch_bounds__(256) void bn3fin_pool_kernel(const float* __restrict__ pS,
                                                          const float* __restrict__ pQ,
                                                          const float* __restrict__ pMx,
                                                          const float* __restrict__ pMn,
                                                          const float* __restrict__ g,
                                                          const float* __restrict__ be,
                                                          float* __restrict__ pooled) {
  int tid = threadIdx.x;
  int chl = tid & 15, grp = tid >> 4;
  int c = blockIdx.x * 16 + chl;
  float s = 0.f, q = 0.f;
  for (int i = grp; i < 1024; i += 16) {
    s += pS[(size_t)i * 1024 + c];
    q += pQ[(size_t)i * 1024 + c];
  }
  __shared__ float ls[256], lq[256], sa[16], sc[16];
  ls[chl * 16 + grp] = s;
  lq[chl * 16 + grp] = q;
  __syncthreads();
  if (tid < 16) {
    float ss = 0.f, qq = 0.f;
#pragma unroll
    for (int i = 0; i < 16; i++) { ss += ls[tid * 16 + i]; qq += lq[tid * 16 + i]; }
    float m = ss * (1.0f / 65536.0f);
    float v = qq * (1.0f / 65536.0f) - m * m;
    float a = g[blockIdx.x * 16 + tid] / sqrtf(v + EPS_BN);
    sa[tid] = a;
    sc[tid] = be[blockIdx.x * 16 + tid] - m * a;
  }
  __syncthreads();
  for (int idx = tid; idx < 512; idx += 256) {
    int b = idx >> 4, l = idx & 15;
    int cc = blockIdx.x * 16 + l;
    float mx = -3.4e38f, mn = 3.4e38f;
    for (int i = 0; i < 32; i++) {
      mx = fmaxf(mx, pMx[(size_t)(b * 32 + i) * 1024 + cc]);
      mn = fminf(mn, pMn[(size_t)(b * 32 + i) * 1024 + cc]);
    }
    float a = sa[l];
    float v = (a > 0.f) ? (a * mx + sc[l]) : (a * mn + sc[l]);
    pooled[(size_t)b * 1024 + cc] = fmaxf(v, 0.f);
  }
}

// ---------------- fc1: pooled[32,1024] @ [1024,512]^T + b -> zf1 ----------------
__global__ __launch_bounds__(256) void fc1_kernel(const float* __restrict__ pooled,
                                                  const float* __restrict__ w,
                                                  const float* __restrict__ bias,
                                                  float* __restrict__ zf1) {
  int g = blockIdx.x * 256 + threadIdx.x;  // 16384 outputs
  int b = g >> 9, o = g & 511;
  const float4* pr = (const float4*)(pooled + (size_t)b * 1024);
  const float4* wr = (const float4*)(w + (size_t)o * 1024);
  float acc = 0.f;
  for (int k = 0; k < 256; k++) {
    float4 p = pr[k], q = wr[k];
    acc += p.x * q.x + p.y * q.y + p.z * q.z + p.w * q.w;
  }
  zf1[g] = acc + bias[o];
}

// per-channel BN stats over the 32-batch axis
__global__ __launch_bounds__(256) void statsF_kernel(const float* __restrict__ z,
                                                     const float* __restrict__ g,
                                                     const float* __restrict__ be, int C,
                                                     float* __restrict__ scale,
                                                     float* __restrict__ shift) {
  int c = blockIdx.x * 256 + threadIdx.x;
  if (c >= C) return;
  float s = 0.f, q = 0.f;
  for (int b = 0; b < 32; b++) {
    float v = z[(size_t)b * C + c];
    s += v;
    q += v * v;
  }
  float m = s * (1.0f / 32.0f);
  float v = q * (1.0f / 32.0f) - m * m;
  float a = g[c] / sqrtf(v + EPS_BN);
  scale[c] = a;
  shift[c] = be[c] - m * a;
}

// ---------------- fc2: relu(bn(zf1)) @ [512,256]^T + b -> zf2 ----------------
__global__ __launch_bounds__(256) void fc2_kernel(const float* __restrict__ zf1,
                                                  const float* __restrict__ sf1,
                                                  const float* __restrict__ hf1,
                                                  const float* __restrict__ w,
                                                  const float* __restrict__ bias,
                                                  float* __restrict__ zf2) {
  int g = blockIdx.x * 256 + threadIdx.x;  // 8192 outputs
  int b = g >> 8, o = g & 255;
  const float* zr = zf1 + (size_t)b * 512;
  const float* wr = w + (size_t)o * 512;
  float acc = 0.f;
  for (int k = 0; k < 512; k++) {
    float v = fmaxf(zr[k] * sf1[k] + hf1[k], 0.f);
    acc += v * wr[k];
  }
  zf2[g] = acc + bias[o];
}

// ---------------- head: relu(bn(zf2)) @ [256,40]^T + b -> log_softmax ----------------
__global__ __launch_bounds__(64) void head_kernel(const float* __restrict__ zf2,
                                                  const float* __restrict__ sf2,
                                                  const float* __restrict__ hf2,
                                                  const float* __restrict__ w,
                                                  const float* __restrict__ bias,
                                                  float* __restrict__ out) {
  int b = blockIdx.x, t = threadIdx.x;
  __shared__ float lg[40];
  __shared__ float red[2];
  if (t < 40) {
    const float* zr = zf2 + (size_t)b * 256;
    const float* wr = w + (size_t)t * 256;
    float acc = bias[t];
    for (int k = 0; k < 256; k++) {
      float v = fmaxf(zr[k] * sf2[k] + hf2[k], 0.f);
      acc += v * wr[k];
    }
    lg[t] = acc;
  }
  __syncthreads();
  if (t == 0) {
    float mx = -3.4e38f;
    for (int i = 0; i < 40; i++) mx = fmaxf(mx, lg[i]);
    float s = 0.f;
    for (int i = 0; i < 40; i++) s += expf(lg[i] - mx);
    red[0] = mx;
    red[1] = logf(s);
  }
  __syncthreads();
  if (t < 40) out[(size_t)b * 40 + t] = lg[t] - red[0] - red[1];
}

extern "C" void kernel_launch(void* const* d_in, const int* in_sizes, int n_in,
                              void* d_out, int out_size, void* d_ws, size_t ws_size,
                              hipStream_t stream) {
  const float* x    = (const float*)d_in[0];
  const float* c1w  = (const float*)d_in[1];
  const float* c1b  = (const float*)d_in[2];
  const float* g1   = (const float*)d_in[3];
  const float* be1  = (const float*)d_in[4];
  const float* c2w  = (const float*)d_in[5];
  const float* c2b  = (const float*)d_in[6];
  const float* g2   = (const float*)d_in[7];
  const float* be2  = (const float*)d_in[8];
  const float* c3w  = (const float*)d_in[9];
  const float* c3b  = (const float*)d_in[10];
  const float* g3   = (const float*)d_in[11];
  const float* be3  = (const float*)d_in[12];
  const float* f1w  = (const float*)d_in[13];
  const float* f1b  = (const float*)d_in[14];
  const float* gf1  = (const float*)d_in[15];
  const float* bef1 = (const float*)d_in[16];
  const float* f2w  = (const float*)d_in[17];
  const float* f2b  = (const float*)d_in[18];
  const float* gf2  = (const float*)d_in[19];
  const float* bef2 = (const float*)d_in[20];
  const float* ow   = (const float*)d_in[21];
  const float* ob   = (const float*)d_in[22];
  float* out = (float*)d_out;

  float* W = (float*)d_ws;
  float* feat   = W;                   // 262144
  float* z1     = feat + 262144;       // 4194304
  float* z2     = z1 + 4194304;        // 8388608
  float* pS     = z2 + 8388608;        // 1048576
  float* pQ     = pS + 1048576;        // 1048576
  float* pMx    = pQ + 1048576;        // 1048576
  float* pMn    = pMx + 1048576;       // 1048576
  float* pooled = pMn + 1048576;       // 32768
  float* zf1    = pooled + 32768;      // 16384
  float* zf2    = zf1 + 16384;         // 8192
  float* spart  = zf2 + 8192;          // 65536
  float* s1     = spart + 65536;       // 64
  float* h1     = s1 + 64;
  float* s2     = h1 + 64;             // 128
  float* h2     = s2 + 128;
  float* sf1    = h2 + 128;            // 512
  float* hf1    = sf1 + 512;
  float* sf2    = hf1 + 512;           // 256
  float* hf2    = sf2 + 256;

  curv_kernel<<<dim3(8, 32), 256, 0, stream>>>(x, feat);
  gemm1_kernel<<<16384, 256, 0, stream>>>(feat, c1w, c1b, z1);
  colstats_kernel<64><<<256, 256, 0, stream>>>(z1, spart);
  bnfin_kernel<64><<<64, 256, 0, stream>>>(spart, g1, be1, s1, h1);
  gemm2_kernel<<<2048, 256, 0, stream>>>(z1, s1, h1, c2w, c2b, z2);
  colstats_kernel<128><<<256, 256, 0, stream>>>(z2, spart);
  bnfin_kernel<128><<<128, 256, 0, stream>>>(spart, g2, be2, s2, h2);
  gemm3_kernel<<<dim3(16, 1024), 256, 0, stream>>>(z2, s2, h2, c3w, c3b, pS, pQ, pMx, pMn);
  bn3fin_pool_kernel<<<64, 256, 0, stream>>>(pS, pQ, pMx, pMn, g3, be3, pooled);
  fc1_kernel<<<64, 256, 0, stream>>>(pooled, f1w, f1b, zf1);
  statsF_kernel<<<2, 256, 0, stream>>>(zf1, gf1, bef1, 512, sf1, hf1);
  fc2_kernel<<<32, 256, 0, stream>>>(zf1, sf1, hf1, f2w, f2b, zf2);
  statsF_kernel<<<1, 256, 0, stream>>>(zf2, gf2, bef2, 256, sf2, hf2);
  head_kernel<<<32, 64, 0, stream>>>(zf2, sf2, hf2, ow, ob, out);
}

// Round 2
// 490.332 us; speedup vs baseline: 1.6116x; 1.6116x over previous
//
#include <hip/hip_runtime.h>
#include <math.h>

#define EPS_BN 1e-5f

constexpr int BATCH = 32;
constexpr int NPTS  = 2048;
constexpr int BP    = BATCH * NPTS;   // 65536

using s16x8 = __attribute__((ext_vector_type(8))) short;
using f32x4 = __attribute__((ext_vector_type(4))) float;

static __device__ __forceinline__ unsigned short f2bf(float f) {
  union { float f; unsigned u; } x{f};
  unsigned r = x.u + 0x7fffu + ((x.u >> 16) & 1u);  // RNE
  return (unsigned short)(r >> 16);
}

static __device__ __forceinline__ void gload_lds16(const void* g, void* l) {
  __builtin_amdgcn_global_load_lds((const __attribute__((address_space(1))) void*)g,
                                   (__attribute__((address_space(3))) void*)l, 16, 0, 0);
}

// ---------------- curvature: 5-NN mean distance -> 1/(1e-8+dmean) ----------------
__global__ __launch_bounds__(256) void curv_kernel(const float* __restrict__ x,
                                                   float* __restrict__ feat) {
  __shared__ float sx[NPTS], sy[NPTS], sz[NPTS];
  int b = blockIdx.y;
  const float* xb = x + (size_t)b * NPTS * 3;
  for (int i = threadIdx.x; i < NPTS; i += 256) {
    sx[i] = xb[i * 3 + 0];
    sy[i] = xb[i * 3 + 1];
    sz[i] = xb[i * 3 + 2];
  }
  __syncthreads();
  int row = blockIdx.x * 256 + threadIdx.x;
  float px = sx[row], py = sy[row], pz = sz[row];
  float nn[6];
#pragma unroll
  for (int j = 0; j < 6; j++) nn[j] = 3.4e38f;
  for (int j = 0; j < NPTS; j++) {
    float dx = px - sx[j], dy = py - sy[j], dz = pz - sz[j];
    float d2 = dx * dx + dy * dy + dz * dz;
    if (d2 < nn[5]) {
      nn[5] = d2;
#pragma unroll
      for (int t = 5; t > 0; t--) {
        float a = nn[t], bb = nn[t - 1];
        if (a < bb) { nn[t] = bb; nn[t - 1] = a; }
      }
    }
  }
  float dm = 0.2f * (sqrtf(nn[1]) + sqrtf(nn[2]) + sqrtf(nn[3]) + sqrtf(nn[4]) + sqrtf(nn[5]));
  float curv = 1.0f / (1e-8f + dm);
  size_t o = ((size_t)b * NPTS + row) * 4;
  feat[o + 0] = px;
  feat[o + 1] = py;
  feat[o + 2] = pz;
  feat[o + 3] = curv;
}

// ---------------- layer1: [BP,4] @ [4,64]^T + b -> z1 [BP,64] ----------------
__global__ __launch_bounds__(256) void gemm1_kernel(const float* __restrict__ feat,
                                                    const float* __restrict__ w,
                                                    const float* __restrict__ bias,
                                                    float* __restrict__ z1) {
  __shared__ float wT[4 * 64];
  int tid = threadIdx.x;
  {
    int k = tid >> 6, c = tid & 63;
    wT[k * 64 + c] = w[c * 4 + k];
  }
  __syncthreads();
  int g = blockIdx.x * 256 + tid;
  int row = g >> 6, col = g & 63;
  const float* fr = feat + (size_t)row * 4;
  float acc = bias[col];
#pragma unroll
  for (int k = 0; k < 4; k++) acc += fr[k] * wT[k * 64 + col];
  z1[g] = acc;
}

// ---------------- per-column sum/sumsq partials of [65536, C] ----------------
template <int C>
__global__ __launch_bounds__(256) void colstats_kernel(const float* __restrict__ z,
                                                       float* __restrict__ part) {
  const int RPB = 256;
  int r0 = blockIdx.x * RPB;
  int col = threadIdx.x % C;
  int rsub = threadIdx.x / C;
  const int rstep = 256 / C;
  float s = 0.f, q = 0.f;
  for (int r = rsub; r < RPB; r += rstep) {
    float v = z[(size_t)(r0 + r) * C + col];
    s += v;
    q += v * v;
  }
  __shared__ float ls[256], lq[256];
  ls[threadIdx.x] = s;
  lq[threadIdx.x] = q;
  __syncthreads();
  if (threadIdx.x < C) {
    float ss = 0.f, qq = 0.f;
#pragma unroll
    for (int i = 0; i < rstep; i++) {
      ss += ls[i * C + threadIdx.x];
      qq += lq[i * C + threadIdx.x];
    }
    part[(size_t)(blockIdx.x * C + threadIdx.x) * 2 + 0] = ss;
    part[(size_t)(blockIdx.x * C + threadIdx.x) * 2 + 1] = qq;
  }
}

template <int C>
__global__ __launch_bounds__(256) void bnfin_kernel(const float* __restrict__ part,
                                                    const float* __restrict__ g,
                                                    const float* __restrict__ be,
                                                    float* __restrict__ scale,
                                                    float* __restrict__ shift) {
  int c = blockIdx.x, tid = threadIdx.x;
  __shared__ float ls[256], lq[256];
  ls[tid] = part[(size_t)(tid * C + c) * 2 + 0];
  lq[tid] = part[(size_t)(tid * C + c) * 2 + 1];
  __syncthreads();
  for (int off = 128; off > 0; off >>= 1) {
    if (tid < off) { ls[tid] += ls[tid + off]; lq[tid] += lq[tid + off]; }
    __syncthreads();
  }
  if (tid == 0) {
    float m = ls[0] * (1.0f / 65536.0f);
    float v = lq[0] * (1.0f / 65536.0f) - m * m;
    float a = g[c] / sqrtf(v + EPS_BN);
    scale[c] = a;
    shift[c] = be[c] - m * a;
  }
}

// ---------------- layer2: relu(bn(z1)) @ [64,128]^T + b -> z2 [BP,128] ----------------
__global__ __launch_bounds__(256) void gemm2_kernel(const float* __restrict__ z1,
                                                    const float* __restrict__ s1,
                                                    const float* __restrict__ h1,
                                                    const float* __restrict__ w2,
                                                    const float* __restrict__ bias2,
                                                    float* __restrict__ z2) {
  __shared__ float As[32 * 65];
  __shared__ float Bs[128 * 65];
  int tid = threadIdx.x;
  int row0 = blockIdx.x * 32;
#pragma unroll
  for (int i = 0; i < 8; i++) {
    int idx = tid + i * 256;
    int r = idx >> 6, k = idx & 63;
    float v = z1[(size_t)(row0 + r) * 64 + k];
    As[r * 65 + k] = fmaxf(v * s1[k] + h1[k], 0.f);
  }
#pragma unroll
  for (int i = 0; i < 32; i++) {
    int idx = tid + i * 256;
    int c = idx >> 6, k = idx & 63;
    Bs[c * 65 + k] = w2[(size_t)c * 64 + k];
  }
  __syncthreads();
  int tr = tid & 7, tc = tid >> 3;
  float acc[4][4] = {};
  for (int k = 0; k < 64; k++) {
    float a[4], bb[4];
#pragma unroll
    for (int j = 0; j < 4; j++) a[j] = As[(tr * 4 + j) * 65 + k];
#pragma unroll
    for (int l = 0; l < 4; l++) bb[l] = Bs[(tc * 4 + l) * 65 + k];
#pragma unroll
    for (int j = 0; j < 4; j++)
#pragma unroll
      for (int l = 0; l < 4; l++) acc[j][l] += a[j] * bb[l];
  }
  float bb0 = bias2[tc * 4 + 0], bb1 = bias2[tc * 4 + 1];
  float bb2 = bias2[tc * 4 + 2], bb3 = bias2[tc * 4 + 3];
#pragma unroll
  for (int j = 0; j < 4; j++) {
    int row = row0 + tr * 4 + j;
    float4 v = make_float4(acc[j][0] + bb0, acc[j][1] + bb1, acc[j][2] + bb2, acc[j][3] + bb3);
    *(float4*)&z2[(size_t)row * 128 + tc * 4] = v;
  }
}

// ---------------- bn2+relu -> bf16 convert: abf [65536][128] ----------------
__global__ __launch_bounds__(256) void bnrelu_bf16_kernel(const float* __restrict__ z2,
                                                          const float* __restrict__ s2,
                                                          const float* __restrict__ h2,
                                                          unsigned short* __restrict__ abf) {
  __shared__ float ss[128], hh[128];
  int tid = threadIdx.x;
  if (tid < 128) { ss[tid] = s2[tid]; hh[tid] = h2[tid]; }
  __syncthreads();
  int g = blockIdx.x * 256 + tid;  // 1048576 groups of 8
  int row = g >> 4, seg = g & 15;
  const float4* src = (const float4*)(z2 + (size_t)row * 128 + seg * 8);
  float4 v0 = src[0], v1 = src[1];
  int c = seg * 8;
  float vals[8] = {v0.x, v0.y, v0.z, v0.w, v1.x, v1.y, v1.z, v1.w};
  s16x8 o;
#pragma unroll
  for (int j = 0; j < 8; j++) {
    float v = fmaxf(vals[j] * ss[c + j] + hh[c + j], 0.f);
    o[j] = (short)f2bf(v);
  }
  *(s16x8*)(abf + (size_t)row * 128 + seg * 8) = o;
}

// ---------------- w3 -> bf16 ----------------
__global__ __launch_bounds__(256) void wconv_kernel(const float* __restrict__ w,
                                                    unsigned short* __restrict__ wbf) {
  int g = blockIdx.x * 256 + threadIdx.x;  // 32768 threads, 4 elems each
  const float4 v = ((const float4*)w)[g];
  unsigned short o0 = f2bf(v.x), o1 = f2bf(v.y), o2 = f2bf(v.z), o3 = f2bf(v.w);
  unsigned short* d = wbf + (size_t)g * 4;
  d[0] = o0; d[1] = o1; d[2] = o2; d[3] = o3;
}

// ---------------- layer3 MFMA: abf[BP,128] @ wbf[1024,128]^T + b3 -> col stats ----------------
__global__ __launch_bounds__(256) void gemm3_mfma_kernel(const unsigned short* __restrict__ abf,
                                                         const unsigned short* __restrict__ wbf,
                                                         const float* __restrict__ bias3,
                                                         float* __restrict__ pS,
                                                         float* __restrict__ pQ,
                                                         float* __restrict__ pMx,
                                                         float* __restrict__ pMn) {
  __shared__ char lds[65536];  // A: [0,32768)  B: [32768,65536); reused for stats after compute
  int tid = threadIdx.x;
  int w = tid >> 6, lane = tid & 63;
  int row0 = blockIdx.y * 128, col0 = blockIdx.x * 128;

  // ---- stage A and B via global_load_lds, LDS linear, source pre-swizzled (T2/m173) ----
#pragma unroll
  for (int i = 0; i < 8; i++) {
    int ldsoff = w * 8192 + i * 1024;
    int lin = ldsoff + lane * 16;
    int row = lin >> 8;          // 0..127
    int gc = (lin >> 4) & 15;    // 16B group within row
    int gcl = gc ^ (row & 7);    // inverse swizzle on source
    gload_lds16(abf + (size_t)(row0 + row) * 128 + gcl * 8, &lds[ldsoff]);
  }
#pragma unroll
  for (int i = 0; i < 8; i++) {
    int ldsoff = w * 8192 + i * 1024;
    int lin = ldsoff + lane * 16;
    int row = lin >> 8;
    int gc = (lin >> 4) & 15;
    int gcl = gc ^ (row & 7);
    gload_lds16(wbf + (size_t)(col0 + row) * 128 + gcl * 8, &lds[32768 + ldsoff]);
  }
  __syncthreads();

  // ---- compute: each wave does 64x64 (wm, wn in 2x2), K=128 ----
  int wm = w >> 1, wn = w & 1;
  int lrow = lane & 15, lg = lane >> 4;
  int sw = (lrow & 7) << 4;  // (row&7)<<4 is uniform in m since m*16 % 8 == 0
  f32x4 acc[4][4] = {};
#pragma unroll
  for (int kstep = 0; kstep < 4; kstep++) {
    s16x8 a[4], b[4];
#pragma unroll
    for (int m = 0; m < 4; m++) {
      int row = wm * 64 + m * 16 + lrow;
      int byte = (row * 256 + kstep * 64 + lg * 16) ^ sw;
      a[m] = *(const s16x8*)(lds + byte);
    }
#pragma unroll
    for (int n = 0; n < 4; n++) {
      int col = wn * 64 + n * 16 + lrow;
      int byte = 32768 + ((col * 256 + kstep * 64 + lg * 16) ^ sw);
      b[n] = *(const s16x8*)(lds + byte);
    }
#pragma unroll
    for (int m = 0; m < 4; m++)
#pragma unroll
      for (int n = 0; n < 4; n++)
        acc[m][n] = __builtin_amdgcn_mfma_f32_16x16x32_bf16(a[m], b[n], acc[m][n], 0, 0, 0);
  }
  __syncthreads();  // done reading A/B; LDS reusable

  // ---- per-column {sum, sumsq, max, min} over this block's 128 rows ----
  float* sS = (float*)lds;       // [2][128]
  float* sQ = sS + 256;
  float* sMx = sQ + 256;
  float* sMn = sMx + 256;
#pragma unroll
  for (int n = 0; n < 4; n++) {
    float bb = bias3[col0 + wn * 64 + n * 16 + lrow];
    float s = 0.f, q = 0.f, mx = -3.4e38f, mn = 3.4e38f;
#pragma unroll
    for (int m = 0; m < 4; m++)
#pragma unroll
      for (int r = 0; r < 4; r++) {
        float v = acc[m][n][r] + bb;
        s += v;
        q += v * v;
        mx = fmaxf(mx, v);
        mn = fminf(mn, v);
      }
    s += __shfl_xor(s, 16); s += __shfl_xor(s, 32);
    q += __shfl_xor(q, 16); q += __shfl_xor(q, 32);
    mx = fmaxf(mx, __shfl_xor(mx, 16)); mx = fmaxf(mx, __shfl_xor(mx, 32));
    mn = fminf(mn, __shfl_xor(mn, 16)); mn = fminf(mn, __shfl_xor(mn, 32));
    if (lane < 16) {
      int cidx = wn * 64 + n * 16 + lane;
      sS[wm * 128 + cidx] = s;
      sQ[wm * 128 + cidx] = q;
      sMx[wm * 128 + cidx] = mx;
      sMn[wm * 128 + cidx] = mn;
    }
  }
  __syncthreads();
  if (tid < 128) {
    size_t o = (size_t)blockIdx.y * 1024 + col0 + tid;
    pS[o] = sS[tid] + sS[128 + tid];
    pQ[o] = sQ[tid] + sQ[128 + tid];
    pMx[o] = fmaxf(sMx[tid], sMx[128 + tid]);
    pMn[o] = fminf(sMn[tid], sMn[128 + tid]);
  }
}

// ---------------- bn3 finalize + masked max-pool (512 rowblocks of 128) ----------------
__global__ __launch_bounds__(256) void bn3fin_pool_kernel(const float* __restrict__ pS,
                                                          const float* __restrict__ pQ,
                                                          const float* __restrict__ pMx,
                                                          const float* __restrict__ pMn,
                                                          const float* __restrict__ g,
                                                          const float* __restrict__ be,
                                                          float* __restrict__ pooled) {
  int tid = threadIdx.x;
  int chl = tid & 15, grp = tid >> 4;
  int c = blockIdx.x * 16 + chl;
  float s = 0.f, q = 0.f;
  for (int i = grp; i < 512; i += 16) {
    s += pS[(size_t)i * 1024 + c];
    q += pQ[(size_t)i * 1024 + c];
  }
  __shared__ float ls[256], lq[256], sa[16], sc[16];
  ls[chl * 16 + grp] = s;
  lq[chl * 16 + grp] = q;
  __syncthreads();
  if (tid < 16) {
    float ss = 0.f, qq = 0.f;
#pragma unroll
    for (int i = 0; i < 16; i++) { ss += ls[tid * 16 + i]; qq += lq[tid * 16 + i]; }
    float m = ss * (1.0f / 65536.0f);
    float v = qq * (1.0f / 65536.0f) - m * m;
    float a = g[blockIdx.x * 16 + tid] / sqrtf(v + EPS_BN);
    sa[tid] = a;
    sc[tid] = be[blockIdx.x * 16 + tid] - m * a;
  }
  __syncthreads();
  for (int idx = tid; idx < 512; idx += 256) {
    int b = idx >> 4, l = idx & 15;
    int cc = blockIdx.x * 16 + l;
    float mx = -3.4e38f, mn = 3.4e38f;
    for (int i = 0; i < 16; i++) {
      mx = fmaxf(mx, pMx[(size_t)(b * 16 + i) * 1024 + cc]);
      mn = fminf(mn, pMn[(size_t)(b * 16 + i) * 1024 + cc]);
    }
    float a = sa[l];
    float v = (a > 0.f) ? (a * mx + sc[l]) : (a * mn + sc[l]);
    pooled[(size_t)b * 1024 + cc] = fmaxf(v, 0.f);
  }
}

// ---------------- fc1: pooled[32,1024] @ [1024,512]^T + b -> zf1 ----------------
__global__ __launch_bounds__(256) void fc1_kernel(const float* __restrict__ pooled,
                                                  const float* __restrict__ w,
                                                  const float* __restrict__ bias,
                                                  float* __restrict__ zf1) {
  int g = blockIdx.x * 256 + threadIdx.x;
  int b = g >> 9, o = g & 511;
  const float4* pr = (const float4*)(pooled + (size_t)b * 1024);
  const float4* wr = (const float4*)(w + (size_t)o * 1024);
  float acc = 0.f;
  for (int k = 0; k < 256; k++) {
    float4 p = pr[k], q = wr[k];
    acc += p.x * q.x + p.y * q.y + p.z * q.z + p.w * q.w;
  }
  zf1[g] = acc + bias[o];
}

__global__ __launch_bounds__(256) void statsF_kernel(const float* __restrict__ z,
                                                     const float* __restrict__ g,
                                                     const float* __restrict__ be, int C,
                                                     float* __restrict__ scale,
                                                     float* __restrict__ shift) {
  int c = blockIdx.x * 256 + threadIdx.x;
  if (c >= C) return;
  float s = 0.f, q = 0.f;
  for (int b = 0; b < 32; b++) {
    float v = z[(size_t)b * C + c];
    s += v;
    q += v * v;
  }
  float m = s * (1.0f / 32.0f);
  float v = q * (1.0f / 32.0f) - m * m;
  float a = g[c] / sqrtf(v + EPS_BN);
  scale[c] = a;
  shift[c] = be[c] - m * a;
}

__global__ __launch_bounds__(256) void fc2_kernel(const float* __restrict__ zf1,
                                                  const float* __restrict__ sf1,
                                                  const float* __restrict__ hf1,
                                                  const float* __restrict__ w,
                                                  const float* __restrict__ bias,
                                                  float* __restrict__ zf2) {
  int g = blockIdx.x * 256 + threadIdx.x;
  int b = g >> 8, o = g & 255;
  const float* zr = zf1 + (size_t)b * 512;
  const float* wr = w + (size_t)o * 512;
  float acc = 0.f;
  for (int k = 0; k < 512; k++) {
    float v = fmaxf(zr[k] * sf1[k] + hf1[k], 0.f);
    acc += v * wr[k];
  }
  zf2[g] = acc + bias[o];
}

__global__ __launch_bounds__(64) void head_kernel(const float* __restrict__ zf2,
                                                  const float* __restrict__ sf2,
                                                  const float* __restrict__ hf2,
                                                  const float* __restrict__ w,
                                                  const float* __restrict__ bias,
                                                  float* __restrict__ out) {
  int b = blockIdx.x, t = threadIdx.x;
  __shared__ float lg[40];
  __shared__ float red[2];
  if (t < 40) {
    const float* zr = zf2 + (size_t)b * 256;
    const float* wr = w + (size_t)t * 256;
    float acc = bias[t];
    for (int k = 0; k < 256; k++) {
      float v = fmaxf(zr[k] * sf2[k] + hf2[k], 0.f);
      acc += v * wr[k];
    }
    lg[t] = acc;
  }
  __syncthreads();
  if (t == 0) {
    float mx = -3.4e38f;
    for (int i = 0; i < 40; i++) mx = fmaxf(mx, lg[i]);
    float s = 0.f;
    for (int i = 0; i < 40; i++) s += expf(lg[i] - mx);
    red[0] = mx;
    red[1] = logf(s);
  }
  __syncthreads();
  if (t < 40) out[(size_t)b * 40 + t] = lg[t] - red[0] - red[1];
}

extern "C" void kernel_launch(void* const* d_in, const int* in_sizes, int n_in,
                              void* d_out, int out_size, void* d_ws, size_t ws_size,
                              hipStream_t stream) {
  const float* x    = (const float*)d_in[0];
  const float* c1w  = (const float*)d_in[1];
  const float* c1b  = (const float*)d_in[2];
  const float* g1   = (const float*)d_in[3];
  const float* be1  = (const float*)d_in[4];
  const float* c2w  = (const float*)d_in[5];
  const float* c2b  = (const float*)d_in[6];
  const float* g2   = (const float*)d_in[7];
  const float* be2  = (const float*)d_in[8];
  const float* c3w  = (const float*)d_in[9];
  const float* c3b  = (const float*)d_in[10];
  const float* g3   = (const float*)d_in[11];
  const float* be3  = (const float*)d_in[12];
  const float* f1w  = (const float*)d_in[13];
  const float* f1b  = (const float*)d_in[14];
  const float* gf1  = (const float*)d_in[15];
  const float* bef1 = (const float*)d_in[16];
  const float* f2w  = (const float*)d_in[17];
  const float* f2b  = (const float*)d_in[18];
  const float* gf2  = (const float*)d_in[19];
  const float* bef2 = (const float*)d_in[20];
  const float* ow   = (const float*)d_in[21];
  const float* ob   = (const float*)d_in[22];
  float* out = (float*)d_out;

  float* W = (float*)d_ws;
  float* feat   = W;                   // 262144
  float* z1     = feat + 262144;       // 4194304 (reused as abf bf16 after gemm2)
  float* z2     = z1 + 4194304;        // 8388608
  float* pS     = z2 + 8388608;        // 524288
  float* pQ     = pS + 524288;
  float* pMx    = pQ + 524288;
  float* pMn    = pMx + 524288;
  float* pooled = pMn + 524288;        // 32768
  float* zf1    = pooled + 32768;      // 16384
  float* zf2    = zf1 + 16384;         // 8192
  float* spart  = zf2 + 8192;          // 65536
  float* s1     = spart + 65536;       // 64
  float* h1     = s1 + 64;
  float* s2     = h1 + 64;             // 128
  float* h2     = s2 + 128;
  float* sf1    = h2 + 128;            // 512
  float* hf1    = sf1 + 512;
  float* sf2    = hf1 + 512;           // 256
  float* hf2    = sf2 + 256;
  unsigned short* wbf = (unsigned short*)(hf2 + 256);  // 131072 bf16 (64K floats)
  unsigned short* abf = (unsigned short*)z1;           // 65536x128 bf16

  wconv_kernel<<<128, 256, 0, stream>>>(c3w, wbf);
  curv_kernel<<<dim3(8, 32), 256, 0, stream>>>(x, feat);
  gemm1_kernel<<<16384, 256, 0, stream>>>(feat, c1w, c1b, z1);
  colstats_kernel<64><<<256, 256, 0, stream>>>(z1, spart);
  bnfin_kernel<64><<<64, 256, 0, stream>>>(spart, g1, be1, s1, h1);
  gemm2_kernel<<<2048, 256, 0, stream>>>(z1, s1, h1, c2w, c2b, z2);
  colstats_kernel<128><<<256, 256, 0, stream>>>(z2, spart);
  bnfin_kernel<128><<<128, 256, 0, stream>>>(spart, g2, be2, s2, h2);
  bnrelu_bf16_kernel<<<4096, 256, 0, stream>>>(z2, s2, h2, abf);
  gemm3_mfma_kernel<<<dim3(8, 512), 256, 0, stream>>>(abf, wbf, c3b, pS, pQ, pMx, pMn);
  bn3fin_pool_kernel<<<64, 256, 0, stream>>>(pS, pQ, pMx, pMn, g3, be3, pooled);
  fc1_kernel<<<64, 256, 0, stream>>>(pooled, f1w, f1b, zf1);
  statsF_kernel<<<2, 256, 0, stream>>>(zf1, gf1, bef1, 512, sf1, hf1);
  fc2_kernel<<<32, 256, 0, stream>>>(zf1, sf1, hf1, f2w, f2b, zf2);
  statsF_kernel<<<1, 256, 0, stream>>>(zf2, gf2, bef2, 256, sf2, hf2);
  head_kernel<<<32, 64, 0, stream>>>(zf2, sf2, hf2, ow, ob, out);
}

// Round 4
// 307.119 us; speedup vs baseline: 2.5730x; 1.5966x over previous
//
#include <hip/hip_runtime.h>
#include <math.h>

#define EPS_BN 1e-5f

constexpr int BATCH = 32;
constexpr int NPTS  = 2048;
constexpr int BP    = BATCH * NPTS;   // 65536

using s16x8 = __attribute__((ext_vector_type(8))) short;
using f32x4 = __attribute__((ext_vector_type(4))) float;

static __device__ __forceinline__ unsigned short f2bf(float f) {
  union { float f; unsigned u; } x{f};
  unsigned r = x.u + 0x7fffu + ((x.u >> 16) & 1u);  // RNE
  return (unsigned short)(r >> 16);
}

static __device__ __forceinline__ void gload_lds16(const void* g, void* l) {
  __builtin_amdgcn_global_load_lds((const __attribute__((address_space(1))) void*)g,
                                   (__attribute__((address_space(3))) void*)l, 16, 0, 0);
}

// ---------------- curvature: 5-NN mean distance -> 1/(1e-8+dmean) ----------------
// 32 rows/block, 8 subthreads/row each scanning a 256-pt chunk; snapshot butterfly merge.
constexpr int CH = 260;  // padded chunk stride (floats)
__global__ __launch_bounds__(256) void curv_kernel(const float* __restrict__ x,
                                                   float* __restrict__ feat) {
  __shared__ float sx[8 * CH], sy[8 * CH], sz[8 * CH];
  int b = blockIdx.y;
  const float* xb = x + (size_t)b * NPTS * 3;
  int tid = threadIdx.x;
#pragma unroll
  for (int k = 0; k < 8; k++) {
    int i = k * 256 + tid;
    sx[k * CH + tid] = xb[i * 3 + 0];
    sy[k * CH + tid] = xb[i * 3 + 1];
    sz[k * CH + tid] = xb[i * 3 + 2];
  }
  __syncthreads();
  int row = blockIdx.x * 32 + (tid >> 3);
  int sub = tid & 7;
  float px = sx[(row >> 8) * CH + (row & 255)];
  float py = sy[(row >> 8) * CH + (row & 255)];
  float pz = sz[(row >> 8) * CH + (row & 255)];
  float nn[6];
#pragma unroll
  for (int j = 0; j < 6; j++) nn[j] = 3.4e38f;
  const float4* cx = (const float4*)(sx + sub * CH);
  const float4* cy = (const float4*)(sy + sub * CH);
  const float4* cz = (const float4*)(sz + sub * CH);
  for (int j = 0; j < 64; j++) {
    float4 qx = cx[j], qy = cy[j], qz = cz[j];
    float d2v[4];
    {
      float dx = px - qx.x, dy = py - qy.x, dz = pz - qz.x;
      d2v[0] = dx * dx + dy * dy + dz * dz;
      dx = px - qx.y; dy = py - qy.y; dz = pz - qz.y;
      d2v[1] = dx * dx + dy * dy + dz * dz;
      dx = px - qx.z; dy = py - qy.z; dz = pz - qz.z;
      d2v[2] = dx * dx + dy * dy + dz * dz;
      dx = px - qx.w; dy = py - qy.w; dz = pz - qz.w;
      d2v[3] = dx * dx + dy * dy + dz * dz;
    }
#pragma unroll
    for (int p = 0; p < 4; p++) {
      float d2 = d2v[p];
      if (d2 < nn[5]) {
        nn[5] = d2;
#pragma unroll
        for (int t = 5; t > 0; t--) {
          float a = nn[t], bb = nn[t - 1];
          if (a < bb) { nn[t] = bb; nn[t - 1] = a; }
        }
      }
    }
  }
  // butterfly merge across the 8 subthreads: snapshot partner's list FIRST,
  // then insert (reading while inserting races with the partner's inserts).
#pragma unroll
  for (int m = 1; m <= 4; m <<= 1) {
    float other[6];
#pragma unroll
    for (int k = 0; k < 6; k++) other[k] = __shfl_xor(nn[k], m);
#pragma unroll
    for (int k = 0; k < 6; k++) {
      float o = other[k];
      if (o < nn[5]) {
        nn[5] = o;
#pragma unroll
        for (int t = 5; t > 0; t--) {
          float a = nn[t], bb = nn[t - 1];
          if (a < bb) { nn[t] = bb; nn[t - 1] = a; }
        }
      }
    }
  }
  if (sub == 0) {
    float dm = 0.2f * (sqrtf(nn[1]) + sqrtf(nn[2]) + sqrtf(nn[3]) + sqrtf(nn[4]) + sqrtf(nn[5]));
    float curv = 1.0f / (1e-8f + dm);
    size_t o = ((size_t)b * NPTS + row) * 4;
    feat[o + 0] = px;
    feat[o + 1] = py;
    feat[o + 2] = pz;
    feat[o + 3] = curv;
  }
}

// ---------------- layer1: [BP,4] @ [4,64]^T + b -> z1 [BP,64] ----------------
__global__ __launch_bounds__(256) void gemm1_kernel(const float* __restrict__ feat,
                                                    const float* __restrict__ w,
                                                    const float* __restrict__ bias,
                                                    float* __restrict__ z1) {
  __shared__ float wT[4 * 64];
  int tid = threadIdx.x;
  {
    int k = tid >> 6, c = tid & 63;
    wT[k * 64 + c] = w[c * 4 + k];
  }
  __syncthreads();
  int g = blockIdx.x * 256 + tid;
  int row = g >> 6, col = g & 63;
  const float* fr = feat + (size_t)row * 4;
  float acc = bias[col];
#pragma unroll
  for (int k = 0; k < 4; k++) acc += fr[k] * wT[k * 64 + col];
  z1[g] = acc;
}

// ---------------- per-column sum/sumsq partials of [65536, C] ----------------
template <int C>
__global__ __launch_bounds__(256) void colstats_kernel(const float* __restrict__ z,
                                                       float* __restrict__ part) {
  const int RPB = 256;
  int r0 = blockIdx.x * RPB;
  int col = threadIdx.x % C;
  int rsub = threadIdx.x / C;
  const int rstep = 256 / C;
  float s = 0.f, q = 0.f;
  for (int r = rsub; r < RPB; r += rstep) {
    float v = z[(size_t)(r0 + r) * C + col];
    s += v;
    q += v * v;
  }
  __shared__ float ls[256], lq[256];
  ls[threadIdx.x] = s;
  lq[threadIdx.x] = q;
  __syncthreads();
  if (threadIdx.x < C) {
    float ss = 0.f, qq = 0.f;
#pragma unroll
    for (int i = 0; i < rstep; i++) {
      ss += ls[i * C + threadIdx.x];
      qq += lq[i * C + threadIdx.x];
    }
    part[(size_t)(blockIdx.x * C + threadIdx.x) * 2 + 0] = ss;
    part[(size_t)(blockIdx.x * C + threadIdx.x) * 2 + 1] = qq;
  }
}

template <int C>
__global__ __launch_bounds__(256) void bnfin_kernel(const float* __restrict__ part,
                                                    const float* __restrict__ g,
                                                    const float* __restrict__ be,
                                                    float* __restrict__ scale,
                                                    float* __restrict__ shift) {
  int c = blockIdx.x, tid = threadIdx.x;
  __shared__ float ls[256], lq[256];
  ls[tid] = part[(size_t)(tid * C + c) * 2 + 0];
  lq[tid] = part[(size_t)(tid * C + c) * 2 + 1];
  __syncthreads();
  for (int off = 128; off > 0; off >>= 1) {
    if (tid < off) { ls[tid] += ls[tid + off]; lq[tid] += lq[tid + off]; }
    __syncthreads();
  }
  if (tid == 0) {
    float m = ls[0] * (1.0f / 65536.0f);
    float v = lq[0] * (1.0f / 65536.0f) - m * m;
    float a = g[c] / sqrtf(v + EPS_BN);
    scale[c] = a;
    shift[c] = be[c] - m * a;
  }
}

// ---------------- layer2: relu(bn(z1)) @ [64,128]^T + b -> z2 [BP,128] ----------------
__global__ __launch_bounds__(256) void gemm2_kernel(const float* __restrict__ z1,
                                                    const float* __restrict__ s1,
                                                    const float* __restrict__ h1,
                                                    const float* __restrict__ w2,
                                                    const float* __restrict__ bias2,
                                                    float* __restrict__ z2) {
  __shared__ float As[32 * 65];
  __shared__ float Bs[128 * 65];
  int tid = threadIdx.x;
  int row0 = blockIdx.x * 32;
#pragma unroll
  for (int i = 0; i < 8; i++) {
    int idx = tid + i * 256;
    int r = idx >> 6, k = idx & 63;
    float v = z1[(size_t)(row0 + r) * 64 + k];
    As[r * 65 + k] = fmaxf(v * s1[k] + h1[k], 0.f);
  }
#pragma unroll
  for (int i = 0; i < 32; i++) {
    int idx = tid + i * 256;
    int c = idx >> 6, k = idx & 63;
    Bs[c * 65 + k] = w2[(size_t)c * 64 + k];
  }
  __syncthreads();
  int tr = tid & 7, tc = tid >> 3;
  float acc[4][4] = {};
  for (int k = 0; k < 64; k++) {
    float a[4], bb[4];
#pragma unroll
    for (int j = 0; j < 4; j++) a[j] = As[(tr * 4 + j) * 65 + k];
#pragma unroll
    for (int l = 0; l < 4; l++) bb[l] = Bs[(tc * 4 + l) * 65 + k];
#pragma unroll
    for (int j = 0; j < 4; j++)
#pragma unroll
      for (int l = 0; l < 4; l++) acc[j][l] += a[j] * bb[l];
  }
  float bb0 = bias2[tc * 4 + 0], bb1 = bias2[tc * 4 + 1];
  float bb2 = bias2[tc * 4 + 2], bb3 = bias2[tc * 4 + 3];
#pragma unroll
  for (int j = 0; j < 4; j++) {
    int row = row0 + tr * 4 + j;
    float4 v = make_float4(acc[j][0] + bb0, acc[j][1] + bb1, acc[j][2] + bb2, acc[j][3] + bb3);
    *(float4*)&z2[(size_t)row * 128 + tc * 4] = v;
  }
}

// ---------------- bn2+relu -> bf16 convert: abf [65536][128] ----------------
__global__ __launch_bounds__(256) void bnrelu_bf16_kernel(const float* __restrict__ z2,
                                                          const float* __restrict__ s2,
                                                          const float* __restrict__ h2,
                                                          unsigned short* __restrict__ abf) {
  __shared__ float ss[128], hh[128];
  int tid = threadIdx.x;
  if (tid < 128) { ss[tid] = s2[tid]; hh[tid] = h2[tid]; }
  __syncthreads();
  int g = blockIdx.x * 256 + tid;
  int row = g >> 4, seg = g & 15;
  const float4* src = (const float4*)(z2 + (size_t)row * 128 + seg * 8);
  float4 v0 = src[0], v1 = src[1];
  int c = seg * 8;
  float vals[8] = {v0.x, v0.y, v0.z, v0.w, v1.x, v1.y, v1.z, v1.w};
  s16x8 o;
#pragma unroll
  for (int j = 0; j < 8; j++) {
    float v = fmaxf(vals[j] * ss[c + j] + hh[c + j], 0.f);
    o[j] = (short)f2bf(v);
  }
  *(s16x8*)(abf + (size_t)row * 128 + seg * 8) = o;
}

// ---------------- w3 -> bf16 ----------------
__global__ __launch_bounds__(256) void wconv_kernel(const float* __restrict__ w,
                                                    unsigned short* __restrict__ wbf) {
  int g = blockIdx.x * 256 + threadIdx.x;
  const float4 v = ((const float4*)w)[g];
  unsigned short o0 = f2bf(v.x), o1 = f2bf(v.y), o2 = f2bf(v.z), o3 = f2bf(v.w);
  unsigned short* d = wbf + (size_t)g * 4;
  d[0] = o0; d[1] = o1; d[2] = o2; d[3] = o3;
}

// ---------------- layer3 MFMA: abf[BP,128] @ wbf[1024,128]^T + b3 -> col stats ----------------
__global__ __launch_bounds__(256) void gemm3_mfma_kernel(const unsigned short* __restrict__ abf,
                                                         const unsigned short* __restrict__ wbf,
                                                         const float* __restrict__ bias3,
                                                         float* __restrict__ pS,
                                                         float* __restrict__ pQ,
                                                         float* __restrict__ pMx,
                                                         float* __restrict__ pMn) {
  __shared__ char lds[65536];
  int tid = threadIdx.x;
  int w = tid >> 6, lane = tid & 63;
  int row0 = blockIdx.y * 128, col0 = blockIdx.x * 128;

#pragma unroll
  for (int i = 0; i < 8; i++) {
    int ldsoff = w * 8192 + i * 1024;
    int lin = ldsoff + lane * 16;
    int row = lin >> 8;
    int gc = (lin >> 4) & 15;
    int gcl = gc ^ (row & 7);
    gload_lds16(abf + (size_t)(row0 + row) * 128 + gcl * 8, &lds[ldsoff]);
  }
#pragma unroll
  for (int i = 0; i < 8; i++) {
    int ldsoff = w * 8192 + i * 1024;
    int lin = ldsoff + lane * 16;
    int row = lin >> 8;
    int gc = (lin >> 4) & 15;
    int gcl = gc ^ (row & 7);
    gload_lds16(wbf + (size_t)(col0 + row) * 128 + gcl * 8, &lds[32768 + ldsoff]);
  }
  __syncthreads();

  int wm = w >> 1, wn = w & 1;
  int lrow = lane & 15, lg = lane >> 4;
  int sw = (lrow & 7) << 4;
  f32x4 acc[4][4] = {};
#pragma unroll
  for (int kstep = 0; kstep < 4; kstep++) {
    s16x8 a[4], b[4];
#pragma unroll
    for (int m = 0; m < 4; m++) {
      int row = wm * 64 + m * 16 + lrow;
      int byte = (row * 256 + kstep * 64 + lg * 16) ^ sw;
      a[m] = *(const s16x8*)(lds + byte);
    }
#pragma unroll
    for (int n = 0; n < 4; n++) {
      int col = wn * 64 + n * 16 + lrow;
      int byte = 32768 + ((col * 256 + kstep * 64 + lg * 16) ^ sw);
      b[n] = *(const s16x8*)(lds + byte);
    }
#pragma unroll
    for (int m = 0; m < 4; m++)
#pragma unroll
      for (int n = 0; n < 4; n++)
        acc[m][n] = __builtin_amdgcn_mfma_f32_16x16x32_bf16(a[m], b[n], acc[m][n], 0, 0, 0);
  }
  __syncthreads();

  float* sS = (float*)lds;
  float* sQ = sS + 256;
  float* sMx = sQ + 256;
  float* sMn = sMx + 256;
#pragma unroll
  for (int n = 0; n < 4; n++) {
    float bb = bias3[col0 + wn * 64 + n * 16 + lrow];
    float s = 0.f, q = 0.f, mx = -3.4e38f, mn = 3.4e38f;
#pragma unroll
    for (int m = 0; m < 4; m++)
#pragma unroll
      for (int r = 0; r < 4; r++) {
        float v = acc[m][n][r] + bb;
        s += v;
        q += v * v;
        mx = fmaxf(mx, v);
        mn = fminf(mn, v);
      }
    s += __shfl_xor(s, 16); s += __shfl_xor(s, 32);
    q += __shfl_xor(q, 16); q += __shfl_xor(q, 32);
    mx = fmaxf(mx, __shfl_xor(mx, 16)); mx = fmaxf(mx, __shfl_xor(mx, 32));
    mn = fminf(mn, __shfl_xor(mn, 16)); mn = fminf(mn, __shfl_xor(mn, 32));
    if (lane < 16) {
      int cidx = wn * 64 + n * 16 + lane;
      sS[wm * 128 + cidx] = s;
      sQ[wm * 128 + cidx] = q;
      sMx[wm * 128 + cidx] = mx;
      sMn[wm * 128 + cidx] = mn;
    }
  }
  __syncthreads();
  if (tid < 128) {
    size_t o = (size_t)blockIdx.y * 1024 + col0 + tid;
    pS[o] = sS[tid] + sS[128 + tid];
    pQ[o] = sQ[tid] + sQ[128 + tid];
    pMx[o] = fmaxf(sMx[tid], sMx[128 + tid]);
    pMn[o] = fminf(sMn[tid], sMn[128 + tid]);
  }
}

// ---------------- bn3 finalize + masked max-pool ----------------
__global__ __launch_bounds__(256) void bn3fin_pool_kernel(const float* __restrict__ pS,
                                                          const float* __restrict__ pQ,
                                                          const float* __restrict__ pMx,
                                                          const float* __restrict__ pMn,
                                                          const float* __restrict__ g,
                                                          const float* __restrict__ be,
                                                          float* __restrict__ pooled) {
  int tid = threadIdx.x;
  int chl = tid & 15, grp = tid >> 4;
  int c = blockIdx.x * 16 + chl;
  float s = 0.f, q = 0.f;
  for (int i = grp; i < 512; i += 16) {
    s += pS[(size_t)i * 1024 + c];
    q += pQ[(size_t)i * 1024 + c];
  }
  __shared__ float ls[256], lq[256], sa[16], sc[16];
  ls[chl * 16 + grp] = s;
  lq[chl * 16 + grp] = q;
  __syncthreads();
  if (tid < 16) {
    float ss = 0.f, qq = 0.f;
#pragma unroll
    for (int i = 0; i < 16; i++) { ss += ls[tid * 16 + i]; qq += lq[tid * 16 + i]; }
    float m = ss * (1.0f / 65536.0f);
    float v = qq * (1.0f / 65536.0f) - m * m;
    float a = g[blockIdx.x * 16 + tid] / sqrtf(v + EPS_BN);
    sa[tid] = a;
    sc[tid] = be[blockIdx.x * 16 + tid] - m * a;
  }
  __syncthreads();
  for (int idx = tid; idx < 512; idx += 256) {
    int b = idx >> 4, l = idx & 15;
    int cc = blockIdx.x * 16 + l;
    float mx = -3.4e38f, mn = 3.4e38f;
    for (int i = 0; i < 16; i++) {
      mx = fmaxf(mx, pMx[(size_t)(b * 16 + i) * 1024 + cc]);
      mn = fminf(mn, pMn[(size_t)(b * 16 + i) * 1024 + cc]);
    }
    float a = sa[l];
    float v = (a > 0.f) ? (a * mx + sc[l]) : (a * mn + sc[l]);
    pooled[(size_t)b * 1024 + cc] = fmaxf(v, 0.f);
  }
}

// ---------------- fc1 ----------------
__global__ __launch_bounds__(256) void fc1_kernel(const float* __restrict__ pooled,
                                                  const float* __restrict__ w,
                                                  const float* __restrict__ bias,
                                                  float* __restrict__ zf1) {
  int g = blockIdx.x * 256 + threadIdx.x;
  int b = g >> 9, o = g & 511;
  const float4* pr = (const float4*)(pooled + (size_t)b * 1024);
  const float4* wr = (const float4*)(w + (size_t)o * 1024);
  float acc = 0.f;
  for (int k = 0; k < 256; k++) {
    float4 p = pr[k], q = wr[k];
    acc += p.x * q.x + p.y * q.y + p.z * q.z + p.w * q.w;
  }
  zf1[g] = acc + bias[o];
}

__global__ __launch_bounds__(256) void statsF_kernel(const float* __restrict__ z,
                                                     const float* __restrict__ g,
                                                     const float* __restrict__ be, int C,
                                                     float* __restrict__ scale,
                                                     float* __restrict__ shift) {
  int c = blockIdx.x * 256 + threadIdx.x;
  if (c >= C) return;
  float s = 0.f, q = 0.f;
  for (int b = 0; b < 32; b++) {
    float v = z[(size_t)b * C + c];
    s += v;
    q += v * v;
  }
  float m = s * (1.0f / 32.0f);
  float v = q * (1.0f / 32.0f) - m * m;
  float a = g[c] / sqrtf(v + EPS_BN);
  scale[c] = a;
  shift[c] = be[c] - m * a;
}

__global__ __launch_bounds__(256) void fc2_kernel(const float* __restrict__ zf1,
                                                  const float* __restrict__ sf1,
                                                  const float* __restrict__ hf1,
                                                  const float* __restrict__ w,
                                                  const float* __restrict__ bias,
                                                  float* __restrict__ zf2) {
  int g = blockIdx.x * 256 + threadIdx.x;
  int b = g >> 8, o = g & 255;
  const float* zr = zf1 + (size_t)b * 512;
  const float* wr = w + (size_t)o * 512;
  float acc = 0.f;
  for (int k = 0; k < 512; k++) {
    float v = fmaxf(zr[k] * sf1[k] + hf1[k], 0.f);
    acc += v * wr[k];
  }
  zf2[g] = acc + bias[o];
}

__global__ __launch_bounds__(64) void head_kernel(const float* __restrict__ zf2,
                                                  const float* __restrict__ sf2,
                                                  const float* __restrict__ hf2,
                                                  const float* __restrict__ w,
                                                  const float* __restrict__ bias,
                                                  float* __restrict__ out) {
  int b = blockIdx.x, t = threadIdx.x;
  __shared__ float lg[40];
  __shared__ float red[2];
  if (t < 40) {
    const float* zr = zf2 + (size_t)b * 256;
    const float* wr = w + (size_t)t * 256;
    float acc = bias[t];
    for (int k = 0; k < 256; k++) {
      float v = fmaxf(zr[k] * sf2[k] + hf2[k], 0.f);
      acc += v * wr[k];
    }
    lg[t] = acc;
  }
  __syncthreads();
  if (t == 0) {
    float mx = -3.4e38f;
    for (int i = 0; i < 40; i++) mx = fmaxf(mx, lg[i]);
    float s = 0.f;
    for (int i = 0; i < 40; i++) s += expf(lg[i] - mx);
    red[0] = mx;
    red[1] = logf(s);
  }
  __syncthreads();
  if (t < 40) out[(size_t)b * 40 + t] = lg[t] - red[0] - red[1];
}

extern "C" void kernel_launch(void* const* d_in, const int* in_sizes, int n_in,
                              void* d_out, int out_size, void* d_ws, size_t ws_size,
                              hipStream_t stream) {
  const float* x    = (const float*)d_in[0];
  const float* c1w  = (const float*)d_in[1];
  const float* c1b  = (const float*)d_in[2];
  const float* g1   = (const float*)d_in[3];
  const float* be1  = (const float*)d_in[4];
  const float* c2w  = (const float*)d_in[5];
  const float* c2b  = (const float*)d_in[6];
  const float* g2   = (const float*)d_in[7];
  const float* be2  = (const float*)d_in[8];
  const float* c3w  = (const float*)d_in[9];
  const float* c3b  = (const float*)d_in[10];
  const float* g3   = (const float*)d_in[11];
  const float* be3  = (const float*)d_in[12];
  const float* f1w  = (const float*)d_in[13];
  const float* f1b  = (const float*)d_in[14];
  const float* gf1  = (const float*)d_in[15];
  const float* bef1 = (const float*)d_in[16];
  const float* f2w  = (const float*)d_in[17];
  const float* f2b  = (const float*)d_in[18];
  const float* gf2  = (const float*)d_in[19];
  const float* bef2 = (const float*)d_in[20];
  const float* ow   = (const float*)d_in[21];
  const float* ob   = (const float*)d_in[22];
  float* out = (float*)d_out;

  float* W = (float*)d_ws;
  float* feat   = W;                   // 262144
  float* z1     = feat + 262144;       // 4194304 (reused as abf bf16)
  float* z2     = z1 + 4194304;        // 8388608
  float* pS     = z2 + 8388608;        // 524288
  float* pQ     = pS + 524288;
  float* pMx    = pQ + 524288;
  float* pMn    = pMx + 524288;
  float* pooled = pMn + 524288;        // 32768
  float* zf1    = pooled + 32768;      // 16384
  float* zf2    = zf1 + 16384;         // 8192
  float* spart  = zf2 + 8192;          // 65536
  float* s1     = spart + 65536;       // 64
  float* h1     = s1 + 64;
  float* s2     = h1 + 64;             // 128
  float* h2     = s2 + 128;
  float* sf1    = h2 + 128;            // 512
  float* hf1    = sf1 + 512;
  float* sf2    = hf1 + 512;           // 256
  float* hf2    = sf2 + 256;
  unsigned short* wbf = (unsigned short*)(hf2 + 256);
  unsigned short* abf = (unsigned short*)z1;

  wconv_kernel<<<128, 256, 0, stream>>>(c3w, wbf);
  curv_kernel<<<dim3(64, 32), 256, 0, stream>>>(x, feat);
  gemm1_kernel<<<16384, 256, 0, stream>>>(feat, c1w, c1b, z1);
  colstats_kernel<64><<<256, 256, 0, stream>>>(z1, spart);
  bnfin_kernel<64><<<64, 256, 0, stream>>>(spart, g1, be1, s1, h1);
  gemm2_kernel<<<2048, 256, 0, stream>>>(z1, s1, h1, c2w, c2b, z2);
  colstats_kernel<128><<<256, 256, 0, stream>>>(z2, spart);
  bnfin_kernel<128><<<128, 256, 0, stream>>>(spart, g2, be2, s2, h2);
  bnrelu_bf16_kernel<<<4096, 256, 0, stream>>>(z2, s2, h2, abf);
  gemm3_mfma_kernel<<<dim3(8, 512), 256, 0, stream>>>(abf, wbf, c3b, pS, pQ, pMx, pMn);
  bn3fin_pool_kernel<<<64, 256, 0, stream>>>(pS, pQ, pMx, pMn, g3, be3, pooled);
  fc1_kernel<<<64, 256, 0, stream>>>(pooled, f1w, f1b, zf1);
  statsF_kernel<<<2, 256, 0, stream>>>(zf1, gf1, bef1, 512, sf1, hf1);
  fc2_kernel<<<32, 256, 0, stream>>>(zf1, sf1, hf1, f2w, f2b, zf2);
  statsF_kernel<<<1, 256, 0, stream>>>(zf2, gf2, bef2, 256, sf2, hf2);
  head_kernel<<<32, 64, 0, stream>>>(zf2, sf2, hf2, ow, ob, out);
}

// Round 5
// 304.799 us; speedup vs baseline: 2.5926x; 1.0076x over previous
//
#include <hip/hip_runtime.h>
#include <math.h>

#define EPS_BN 1e-5f

constexpr int BATCH = 32;
constexpr int NPTS  = 2048;
constexpr int BP    = BATCH * NPTS;   // 65536

using s16x8 = __attribute__((ext_vector_type(8))) short;
using f32x4 = __attribute__((ext_vector_type(4))) float;

static __device__ __forceinline__ unsigned short f2bf(float f) {
  union { float f; unsigned u; } x{f};
  unsigned r = x.u + 0x7fffu + ((x.u >> 16) & 1u);  // RNE
  return (unsigned short)(r >> 16);
}

static __device__ __forceinline__ void gload_lds16(const void* g, void* l) {
  __builtin_amdgcn_global_load_lds((const __attribute__((address_space(1))) void*)g,
                                   (__attribute__((address_space(3))) void*)l, 16, 0, 0);
}

// branchless keep-6-smallest: nn sorted DESCENDING (nn[0]=largest kept).
// Evicts max(nn[0], c); 11 min/max ops, no divergence.
static __device__ __forceinline__ void ins6(float (&nn)[6], float c) {
  float x = fminf(nn[0], c);
#pragma unroll
  for (int t = 1; t < 6; t++) {
    float lo = fminf(x, nn[t]);
    nn[t - 1] = fmaxf(x, nn[t]);
    x = lo;
  }
  nn[5] = x;
}

// ---------------- curvature: 5-NN mean distance -> 1/(1e-8+dmean) ----------------
// 32 rows/block, 8 subthreads/row each scanning a 256-pt chunk; snapshot butterfly merge.
constexpr int CH = 260;  // padded chunk stride (floats)
__global__ __launch_bounds__(256) void curv_kernel(const float* __restrict__ x,
                                                   float* __restrict__ feat) {
  __shared__ float sx[8 * CH], sy[8 * CH], sz[8 * CH];
  int b = blockIdx.y;
  const float* xb = x + (size_t)b * NPTS * 3;
  int tid = threadIdx.x;
#pragma unroll
  for (int k = 0; k < 8; k++) {
    int i = k * 256 + tid;
    sx[k * CH + tid] = xb[i * 3 + 0];
    sy[k * CH + tid] = xb[i * 3 + 1];
    sz[k * CH + tid] = xb[i * 3 + 2];
  }
  __syncthreads();
  int row = blockIdx.x * 32 + (tid >> 3);
  int sub = tid & 7;
  float px = sx[(row >> 8) * CH + (row & 255)];
  float py = sy[(row >> 8) * CH + (row & 255)];
  float pz = sz[(row >> 8) * CH + (row & 255)];
  float nn[6];
#pragma unroll
  for (int j = 0; j < 6; j++) nn[j] = 3.4e38f;
  const float4* cx = (const float4*)(sx + sub * CH);
  const float4* cy = (const float4*)(sy + sub * CH);
  const float4* cz = (const float4*)(sz + sub * CH);
  for (int j = 0; j < 64; j++) {
    float4 qx = cx[j], qy = cy[j], qz = cz[j];
    float dx, dy, dz;
    dx = px - qx.x; dy = py - qy.x; dz = pz - qz.x;
    ins6(nn, dx * dx + dy * dy + dz * dz);
    dx = px - qx.y; dy = py - qy.y; dz = pz - qz.y;
    ins6(nn, dx * dx + dy * dy + dz * dz);
    dx = px - qx.z; dy = py - qy.z; dz = pz - qz.z;
    ins6(nn, dx * dx + dy * dy + dz * dz);
    dx = px - qx.w; dy = py - qy.w; dz = pz - qz.w;
    ins6(nn, dx * dx + dy * dy + dz * dz);
  }
  // butterfly merge across the 8 subthreads: snapshot partner's list, then insert.
#pragma unroll
  for (int m = 1; m <= 4; m <<= 1) {
    float other[6];
#pragma unroll
    for (int k = 0; k < 6; k++) other[k] = __shfl_xor(nn[k], m);
#pragma unroll
    for (int k = 0; k < 6; k++) ins6(nn, other[k]);
  }
  if (sub == 0) {
    // descending list: nn[5] is the self-0; mean of sqrt of nn[0..4]
    float dm = 0.2f * (sqrtf(nn[0]) + sqrtf(nn[1]) + sqrtf(nn[2]) + sqrtf(nn[3]) + sqrtf(nn[4]));
    float curv = 1.0f / (1e-8f + dm);
    size_t o = ((size_t)b * NPTS + row) * 4;
    feat[o + 0] = px;
    feat[o + 1] = py;
    feat[o + 2] = pz;
    feat[o + 3] = curv;
  }
}

// ---------------- layer1: [BP,4] @ [4,64]^T + b -> z1 [BP,64] ----------------
__global__ __launch_bounds__(256) void gemm1_kernel(const float* __restrict__ feat,
                                                    const float* __restrict__ w,
                                                    const float* __restrict__ bias,
                                                    float* __restrict__ z1) {
  __shared__ float wT[4 * 64];
  int tid = threadIdx.x;
  {
    int k = tid >> 6, c = tid & 63;
    wT[k * 64 + c] = w[c * 4 + k];
  }
  __syncthreads();
  int g = blockIdx.x * 256 + tid;
  int row = g >> 6, col = g & 63;
  const float* fr = feat + (size_t)row * 4;
  float acc = bias[col];
#pragma unroll
  for (int k = 0; k < 4; k++) acc += fr[k] * wT[k * 64 + col];
  z1[g] = acc;
}

// ---------------- per-column sum/sumsq partials of [65536, C] ----------------
template <int C>
__global__ __launch_bounds__(256) void colstats_kernel(const float* __restrict__ z,
                                                       float* __restrict__ part) {
  const int RPB = 256;
  int r0 = blockIdx.x * RPB;
  int col = threadIdx.x % C;
  int rsub = threadIdx.x / C;
  const int rstep = 256 / C;
  float s = 0.f, q = 0.f;
  for (int r = rsub; r < RPB; r += rstep) {
    float v = z[(size_t)(r0 + r) * C + col];
    s += v;
    q += v * v;
  }
  __shared__ float ls[256], lq[256];
  ls[threadIdx.x] = s;
  lq[threadIdx.x] = q;
  __syncthreads();
  if (threadIdx.x < C) {
    float ss = 0.f, qq = 0.f;
#pragma unroll
    for (int i = 0; i < rstep; i++) {
      ss += ls[i * C + threadIdx.x];
      qq += lq[i * C + threadIdx.x];
    }
    part[(size_t)(blockIdx.x * C + threadIdx.x) * 2 + 0] = ss;
    part[(size_t)(blockIdx.x * C + threadIdx.x) * 2 + 1] = qq;
  }
}

template <int C>
__global__ __launch_bounds__(256) void bnfin_kernel(const float* __restrict__ part,
                                                    const float* __restrict__ g,
                                                    const float* __restrict__ be,
                                                    float* __restrict__ scale,
                                                    float* __restrict__ shift) {
  int c = blockIdx.x, tid = threadIdx.x;
  __shared__ float ls[256], lq[256];
  ls[tid] = part[(size_t)(tid * C + c) * 2 + 0];
  lq[tid] = part[(size_t)(tid * C + c) * 2 + 1];
  __syncthreads();
  for (int off = 128; off > 0; off >>= 1) {
    if (tid < off) { ls[tid] += ls[tid + off]; lq[tid] += lq[tid + off]; }
    __syncthreads();
  }
  if (tid == 0) {
    float m = ls[0] * (1.0f / 65536.0f);
    float v = lq[0] * (1.0f / 65536.0f) - m * m;
    float a = g[c] / sqrtf(v + EPS_BN);
    scale[c] = a;
    shift[c] = be[c] - m * a;
  }
}

// ---------------- layer2: relu(bn(z1)) @ [64,128]^T + b -> z2 [BP,128] ----------------
__global__ __launch_bounds__(256) void gemm2_kernel(const float* __restrict__ z1,
                                                    const float* __restrict__ s1,
                                                    const float* __restrict__ h1,
                                                    const float* __restrict__ w2,
                                                    const float* __restrict__ bias2,
                                                    float* __restrict__ z2) {
  __shared__ float As[32 * 65];
  __shared__ float Bs[128 * 65];
  int tid = threadIdx.x;
  int row0 = blockIdx.x * 32;
#pragma unroll
  for (int i = 0; i < 8; i++) {
    int idx = tid + i * 256;
    int r = idx >> 6, k = idx & 63;
    float v = z1[(size_t)(row0 + r) * 64 + k];
    As[r * 65 + k] = fmaxf(v * s1[k] + h1[k], 0.f);
  }
#pragma unroll
  for (int i = 0; i < 32; i++) {
    int idx = tid + i * 256;
    int c = idx >> 6, k = idx & 63;
    Bs[c * 65 + k] = w2[(size_t)c * 64 + k];
  }
  __syncthreads();
  int tr = tid & 7, tc = tid >> 3;
  float acc[4][4] = {};
  for (int k = 0; k < 64; k++) {
    float a[4], bb[4];
#pragma unroll
    for (int j = 0; j < 4; j++) a[j] = As[(tr * 4 + j) * 65 + k];
#pragma unroll
    for (int l = 0; l < 4; l++) bb[l] = Bs[(tc * 4 + l) * 65 + k];
#pragma unroll
    for (int j = 0; j < 4; j++)
#pragma unroll
      for (int l = 0; l < 4; l++) acc[j][l] += a[j] * bb[l];
  }
  float bb0 = bias2[tc * 4 + 0], bb1 = bias2[tc * 4 + 1];
  float bb2 = bias2[tc * 4 + 2], bb3 = bias2[tc * 4 + 3];
#pragma unroll
  for (int j = 0; j < 4; j++) {
    int row = row0 + tr * 4 + j;
    float4 v = make_float4(acc[j][0] + bb0, acc[j][1] + bb1, acc[j][2] + bb2, acc[j][3] + bb3);
    *(float4*)&z2[(size_t)row * 128 + tc * 4] = v;
  }
}

// ---------------- bn2+relu -> bf16 convert: abf [65536][128] ----------------
__global__ __launch_bounds__(256) void bnrelu_bf16_kernel(const float* __restrict__ z2,
                                                          const float* __restrict__ s2,
                                                          const float* __restrict__ h2,
                                                          unsigned short* __restrict__ abf) {
  __shared__ float ss[128], hh[128];
  int tid = threadIdx.x;
  if (tid < 128) { ss[tid] = s2[tid]; hh[tid] = h2[tid]; }
  __syncthreads();
  int g = blockIdx.x * 256 + tid;
  int row = g >> 4, seg = g & 15;
  const float4* src = (const float4*)(z2 + (size_t)row * 128 + seg * 8);
  float4 v0 = src[0], v1 = src[1];
  int c = seg * 8;
  float vals[8] = {v0.x, v0.y, v0.z, v0.w, v1.x, v1.y, v1.z, v1.w};
  s16x8 o;
#pragma unroll
  for (int j = 0; j < 8; j++) {
    float v = fmaxf(vals[j] * ss[c + j] + hh[c + j], 0.f);
    o[j] = (short)f2bf(v);
  }
  *(s16x8*)(abf + (size_t)row * 128 + seg * 8) = o;
}

// ---------------- w3 -> bf16 ----------------
__global__ __launch_bounds__(256) void wconv_kernel(const float* __restrict__ w,
                                                    unsigned short* __restrict__ wbf) {
  int g = blockIdx.x * 256 + threadIdx.x;
  const float4 v = ((const float4*)w)[g];
  unsigned short o0 = f2bf(v.x), o1 = f2bf(v.y), o2 = f2bf(v.z), o3 = f2bf(v.w);
  unsigned short* d = wbf + (size_t)g * 4;
  d[0] = o0; d[1] = o1; d[2] = o2; d[3] = o3;
}

// ---------------- layer3 MFMA: abf[BP,128] @ wbf[1024,128]^T + b3 -> col stats ----------------
__global__ __launch_bounds__(256) void gemm3_mfma_kernel(const unsigned short* __restrict__ abf,
                                                         const unsigned short* __restrict__ wbf,
                                                         const float* __restrict__ bias3,
                                                         float* __restrict__ pS,
                                                         float* __restrict__ pQ,
                                                         float* __restrict__ pMx,
                                                         float* __restrict__ pMn) {
  __shared__ char lds[65536];
  int tid = threadIdx.x;
  int w = tid >> 6, lane = tid & 63;
  int row0 = blockIdx.y * 128, col0 = blockIdx.x * 128;

#pragma unroll
  for (int i = 0; i < 8; i++) {
    int ldsoff = w * 8192 + i * 1024;
    int lin = ldsoff + lane * 16;
    int row = lin >> 8;
    int gc = (lin >> 4) & 15;
    int gcl = gc ^ (row & 7);
    gload_lds16(abf + (size_t)(row0 + row) * 128 + gcl * 8, &lds[ldsoff]);
  }
#pragma unroll
  for (int i = 0; i < 8; i++) {
    int ldsoff = w * 8192 + i * 1024;
    int lin = ldsoff + lane * 16;
    int row = lin >> 8;
    int gc = (lin >> 4) & 15;
    int gcl = gc ^ (row & 7);
    gload_lds16(wbf + (size_t)(col0 + row) * 128 + gcl * 8, &lds[32768 + ldsoff]);
  }
  __syncthreads();

  int wm = w >> 1, wn = w & 1;
  int lrow = lane & 15, lg = lane >> 4;
  int sw = (lrow & 7) << 4;
  f32x4 acc[4][4] = {};
#pragma unroll
  for (int kstep = 0; kstep < 4; kstep++) {
    s16x8 a[4], b[4];
#pragma unroll
    for (int m = 0; m < 4; m++) {
      int row = wm * 64 + m * 16 + lrow;
      int byte = (row * 256 + kstep * 64 + lg * 16) ^ sw;
      a[m] = *(const s16x8*)(lds + byte);
    }
#pragma unroll
    for (int n = 0; n < 4; n++) {
      int col = wn * 64 + n * 16 + lrow;
      int byte = 32768 + ((col * 256 + kstep * 64 + lg * 16) ^ sw);
      b[n] = *(const s16x8*)(lds + byte);
    }
#pragma unroll
    for (int m = 0; m < 4; m++)
#pragma unroll
      for (int n = 0; n < 4; n++)
        acc[m][n] = __builtin_amdgcn_mfma_f32_16x16x32_bf16(a[m], b[n], acc[m][n], 0, 0, 0);
  }
  __syncthreads();

  float* sS = (float*)lds;
  float* sQ = sS + 256;
  float* sMx = sQ + 256;
  float* sMn = sMx + 256;
#pragma unroll
  for (int n = 0; n < 4; n++) {
    float bb = bias3[col0 + wn * 64 + n * 16 + lrow];
    float s = 0.f, q = 0.f, mx = -3.4e38f, mn = 3.4e38f;
#pragma unroll
    for (int m = 0; m < 4; m++)
#pragma unroll
      for (int r = 0; r < 4; r++) {
        float v = acc[m][n][r] + bb;
        s += v;
        q += v * v;
        mx = fmaxf(mx, v);
        mn = fminf(mn, v);
      }
    s += __shfl_xor(s, 16); s += __shfl_xor(s, 32);
    q += __shfl_xor(q, 16); q += __shfl_xor(q, 32);
    mx = fmaxf(mx, __shfl_xor(mx, 16)); mx = fmaxf(mx, __shfl_xor(mx, 32));
    mn = fminf(mn, __shfl_xor(mn, 16)); mn = fminf(mn, __shfl_xor(mn, 32));
    if (lane < 16) {
      int cidx = wn * 64 + n * 16 + lane;
      sS[wm * 128 + cidx] = s;
      sQ[wm * 128 + cidx] = q;
      sMx[wm * 128 + cidx] = mx;
      sMn[wm * 128 + cidx] = mn;
    }
  }
  __syncthreads();
  if (tid < 128) {
    size_t o = (size_t)blockIdx.y * 1024 + col0 + tid;
    pS[o] = sS[tid] + sS[128 + tid];
    pQ[o] = sQ[tid] + sQ[128 + tid];
    pMx[o] = fmaxf(sMx[tid], sMx[128 + tid]);
    pMn[o] = fminf(sMn[tid], sMn[128 + tid]);
  }
}

// ---------------- bn3 finalize + masked max-pool ----------------
__global__ __launch_bounds__(256) void bn3fin_pool_kernel(const float* __restrict__ pS,
                                                          const float* __restrict__ pQ,
                                                          const float* __restrict__ pMx,
                                                          const float* __restrict__ pMn,
                                                          const float* __restrict__ g,
                                                          const float* __restrict__ be,
                                                          float* __restrict__ pooled) {
  int tid = threadIdx.x;
  int chl = tid & 15, grp = tid >> 4;
  int c = blockIdx.x * 16 + chl;
  float s = 0.f, q = 0.f;
  for (int i = grp; i < 512; i += 16) {
    s += pS[(size_t)i * 1024 + c];
    q += pQ[(size_t)i * 1024 + c];
  }
  __shared__ float ls[256], lq[256], sa[16], sc[16];
  ls[chl * 16 + grp] = s;
  lq[chl * 16 + grp] = q;
  __syncthreads();
  if (tid < 16) {
    float ss = 0.f, qq = 0.f;
#pragma unroll
    for (int i = 0; i < 16; i++) { ss += ls[tid * 16 + i]; qq += lq[tid * 16 + i]; }
    float m = ss * (1.0f / 65536.0f);
    float v = qq * (1.0f / 65536.0f) - m * m;
    float a = g[blockIdx.x * 16 + tid] / sqrtf(v + EPS_BN);
    sa[tid] = a;
    sc[tid] = be[blockIdx.x * 16 + tid] - m * a;
  }
  __syncthreads();
  for (int idx = tid; idx < 512; idx += 256) {
    int b = idx >> 4, l = idx & 15;
    int cc = blockIdx.x * 16 + l;
    float mx = -3.4e38f, mn = 3.4e38f;
    for (int i = 0; i < 16; i++) {
      mx = fmaxf(mx, pMx[(size_t)(b * 16 + i) * 1024 + cc]);
      mn = fminf(mn, pMn[(size_t)(b * 16 + i) * 1024 + cc]);
    }
    float a = sa[l];
    float v = (a > 0.f) ? (a * mx + sc[l]) : (a * mn + sc[l]);
    pooled[(size_t)b * 1024 + cc] = fmaxf(v, 0.f);
  }
}

// ---------------- fc1 ----------------
__global__ __launch_bounds__(256) void fc1_kernel(const float* __restrict__ pooled,
                                                  const float* __restrict__ w,
                                                  const float* __restrict__ bias,
                                                  float* __restrict__ zf1) {
  int g = blockIdx.x * 256 + threadIdx.x;
  int b = g >> 9, o = g & 511;
  const float4* pr = (const float4*)(pooled + (size_t)b * 1024);
  const float4* wr = (const float4*)(w + (size_t)o * 1024);
  float acc = 0.f;
  for (int k = 0; k < 256; k++) {
    float4 p = pr[k], q = wr[k];
    acc += p.x * q.x + p.y * q.y + p.z * q.z + p.w * q.w;
  }
  zf1[g] = acc + bias[o];
}

__global__ __launch_bounds__(256) void statsF_kernel(const float* __restrict__ z,
                                                     const float* __restrict__ g,
                                                     const float* __restrict__ be, int C,
                                                     float* __restrict__ scale,
                                                     float* __restrict__ shift) {
  int c = blockIdx.x * 256 + threadIdx.x;
  if (c >= C) return;
  float s = 0.f, q = 0.f;
  for (int b = 0; b < 32; b++) {
    float v = z[(size_t)b * C + c];
    s += v;
    q += v * v;
  }
  float m = s * (1.0f / 32.0f);
  float v = q * (1.0f / 32.0f) - m * m;
  float a = g[c] / sqrtf(v + EPS_BN);
  scale[c] = a;
  shift[c] = be[c] - m * a;
}

__global__ __launch_bounds__(256) void fc2_kernel(const float* __restrict__ zf1,
                                                  const float* __restrict__ sf1,
                                                  const float* __restrict__ hf1,
                                                  const float* __restrict__ w,
                                                  const float* __restrict__ bias,
                                                  float* __restrict__ zf2) {
  int g = blockIdx.x * 256 + threadIdx.x;
  int b = g >> 8, o = g & 255;
  const float* zr = zf1 + (size_t)b * 512;
  const float* wr = w + (size_t)o * 512;
  float acc = 0.f;
  for (int k = 0; k < 512; k++) {
    float v = fmaxf(zr[k] * sf1[k] + hf1[k], 0.f);
    acc += v * wr[k];
  }
  zf2[g] = acc + bias[o];
}

__global__ __launch_bounds__(64) void head_kernel(const float* __restrict__ zf2,
                                                  const float* __restrict__ sf2,
                                                  const float* __restrict__ hf2,
                                                  const float* __restrict__ w,
                                                  const float* __restrict__ bias,
                                                  float* __restrict__ out) {
  int b = blockIdx.x, t = threadIdx.x;
  __shared__ float lg[40];
  __shared__ float red[2];
  if (t < 40) {
    const float* zr = zf2 + (size_t)b * 256;
    const float* wr = w + (size_t)t * 256;
    float acc = bias[t];
    for (int k = 0; k < 256; k++) {
      float v = fmaxf(zr[k] * sf2[k] + hf2[k], 0.f);
      acc += v * wr[k];
    }
    lg[t] = acc;
  }
  __syncthreads();
  if (t == 0) {
    float mx = -3.4e38f;
    for (int i = 0; i < 40; i++) mx = fmaxf(mx, lg[i]);
    float s = 0.f;
    for (int i = 0; i < 40; i++) s += expf(lg[i] - mx);
    red[0] = mx;
    red[1] = logf(s);
  }
  __syncthreads();
  if (t < 40) out[(size_t)b * 40 + t] = lg[t] - red[0] - red[1];
}

extern "C" void kernel_launch(void* const* d_in, const int* in_sizes, int n_in,
                              void* d_out, int out_size, void* d_ws, size_t ws_size,
                              hipStream_t stream) {
  const float* x    = (const float*)d_in[0];
  const float* c1w  = (const float*)d_in[1];
  const float* c1b  = (const float*)d_in[2];
  const float* g1   = (const float*)d_in[3];
  const float* be1  = (const float*)d_in[4];
  const float* c2w  = (const float*)d_in[5];
  const float* c2b  = (const float*)d_in[6];
  const float* g2   = (const float*)d_in[7];
  const float* be2  = (const float*)d_in[8];
  const float* c3w  = (const float*)d_in[9];
  const float* c3b  = (const float*)d_in[10];
  const float* g3   = (const float*)d_in[11];
  const float* be3  = (const float*)d_in[12];
  const float* f1w  = (const float*)d_in[13];
  const float* f1b  = (const float*)d_in[14];
  const float* gf1  = (const float*)d_in[15];
  const float* bef1 = (const float*)d_in[16];
  const float* f2w  = (const float*)d_in[17];
  const float* f2b  = (const float*)d_in[18];
  const float* gf2  = (const float*)d_in[19];
  const float* bef2 = (const float*)d_in[20];
  const float* ow   = (const float*)d_in[21];
  const float* ob   = (const float*)d_in[22];
  float* out = (float*)d_out;

  float* W = (float*)d_ws;
  float* feat   = W;                   // 262144
  float* z1     = feat + 262144;       // 4194304 (reused as abf bf16)
  float* z2     = z1 + 4194304;        // 8388608
  float* pS     = z2 + 8388608;        // 524288
  float* pQ     = pS + 524288;
  float* pMx    = pQ + 524288;
  float* pMn    = pMx + 524288;
  float* pooled = pMn + 524288;        // 32768
  float* zf1    = pooled + 32768;      // 16384
  float* zf2    = zf1 + 16384;         // 8192
  float* spart  = zf2 + 8192;          // 65536
  float* s1     = spart + 65536;       // 64
  float* h1     = s1 + 64;
  float* s2     = h1 + 64;             // 128
  float* h2     = s2 + 128;
  float* sf1    = h2 + 128;            // 512
  float* hf1    = sf1 + 512;
  float* sf2    = hf1 + 512;           // 256
  float* hf2    = sf2 + 256;
  unsigned short* wbf = (unsigned short*)(hf2 + 256);
  unsigned short* abf = (unsigned short*)z1;

  wconv_kernel<<<128, 256, 0, stream>>>(c3w, wbf);
  curv_kernel<<<dim3(64, 32), 256, 0, stream>>>(x, feat);
  gemm1_kernel<<<16384, 256, 0, stream>>>(feat, c1w, c1b, z1);
  colstats_kernel<64><<<256, 256, 0, stream>>>(z1, spart);
  bnfin_kernel<64><<<64, 256, 0, stream>>>(spart, g1, be1, s1, h1);
  gemm2_kernel<<<2048, 256, 0, stream>>>(z1, s1, h1, c2w, c2b, z2);
  colstats_kernel<128><<<256, 256, 0, stream>>>(z2, spart);
  bnfin_kernel<128><<<128, 256, 0, stream>>>(spart, g2, be2, s2, h2);
  bnrelu_bf16_kernel<<<4096, 256, 0, stream>>>(z2, s2, h2, abf);
  gemm3_mfma_kernel<<<dim3(8, 512), 256, 0, stream>>>(abf, wbf, c3b, pS, pQ, pMx, pMn);
  bn3fin_pool_kernel<<<64, 256, 0, stream>>>(pS, pQ, pMx, pMn, g3, be3, pooled);
  fc1_kernel<<<64, 256, 0, stream>>>(pooled, f1w, f1b, zf1);
  statsF_kernel<<<2, 256, 0, stream>>>(zf1, gf1, bef1, 512, sf1, hf1);
  fc2_kernel<<<32, 256, 0, stream>>>(zf1, sf1, hf1, f2w, f2b, zf2);
  statsF_kernel<<<1, 256, 0, stream>>>(zf2, gf2, bef2, 256, sf2, hf2);
  head_kernel<<<32, 64, 0, stream>>>(zf2, sf2, hf2, ow, ob, out);
}

// Round 6
// 284.452 us; speedup vs baseline: 2.7781x; 1.0715x over previous
//
#include <hip/hip_runtime.h>
#include <math.h>

#define EPS_BN 1e-5f

constexpr int BATCH = 32;
constexpr int NPTS  = 2048;
constexpr int BP    = BATCH * NPTS;   // 65536

using s16x8 = __attribute__((ext_vector_type(8))) short;
using f32x4 = __attribute__((ext_vector_type(4))) float;

static __device__ __forceinline__ unsigned short f2bf(float f) {
  union { float f; unsigned u; } x{f};
  unsigned r = x.u + 0x7fffu + ((x.u >> 16) & 1u);  // RNE
  return (unsigned short)(r >> 16);
}

static __device__ __forceinline__ void gload_lds16(const void* g, void* l) {
  __builtin_amdgcn_global_load_lds((const __attribute__((address_space(1))) void*)g,
                                   (__attribute__((address_space(3))) void*)l, 16, 0, 0);
}

// keep-6-smallest, ASCENDING list, depth-1 branchless insert:
//   b0 = min(a0, c);  b[t] = med3(c, a[t], a[t-1])   (evicts the current max)
// 6 independent ops (1 v_min + 5 v_med3), no serial chain.
static __device__ __forceinline__ void ins6(float (&nn)[6], float c) {
  float b0 = fminf(nn[0], c);
  float b1 = __builtin_amdgcn_fmed3f(c, nn[1], nn[0]);
  float b2 = __builtin_amdgcn_fmed3f(c, nn[2], nn[1]);
  float b3 = __builtin_amdgcn_fmed3f(c, nn[3], nn[2]);
  float b4 = __builtin_amdgcn_fmed3f(c, nn[4], nn[3]);
  float b5 = __builtin_amdgcn_fmed3f(c, nn[5], nn[4]);
  nn[0] = b0; nn[1] = b1; nn[2] = b2; nn[3] = b3; nn[4] = b4; nn[5] = b5;
}

// ---------------- curvature: 5-NN mean distance -> 1/(1e-8+dmean) ----------------
// 32 rows/block, 8 subthreads/row each scanning a 256-pt chunk; snapshot butterfly merge.
constexpr int CH = 260;  // padded chunk stride (floats)
__global__ __launch_bounds__(256) void curv_kernel(const float* __restrict__ x,
                                                   float* __restrict__ feat) {
  __shared__ float sx[8 * CH], sy[8 * CH], sz[8 * CH];
  int b = blockIdx.y;
  const float* xb = x + (size_t)b * NPTS * 3;
  int tid = threadIdx.x;
#pragma unroll
  for (int k = 0; k < 8; k++) {
    int i = k * 256 + tid;
    sx[k * CH + tid] = xb[i * 3 + 0];
    sy[k * CH + tid] = xb[i * 3 + 1];
    sz[k * CH + tid] = xb[i * 3 + 2];
  }
  __syncthreads();
  int row = blockIdx.x * 32 + (tid >> 3);
  int sub = tid & 7;
  float px = sx[(row >> 8) * CH + (row & 255)];
  float py = sy[(row >> 8) * CH + (row & 255)];
  float pz = sz[(row >> 8) * CH + (row & 255)];
  float nn[6];
#pragma unroll
  for (int j = 0; j < 6; j++) nn[j] = 3.4e38f;
  const float4* cx = (const float4*)(sx + sub * CH);
  const float4* cy = (const float4*)(sy + sub * CH);
  const float4* cz = (const float4*)(sz + sub * CH);
  for (int j = 0; j < 64; j++) {
    float4 qx = cx[j], qy = cy[j], qz = cz[j];
    float dx, dy, dz;
    dx = px - qx.x; dy = py - qy.x; dz = pz - qz.x;
    ins6(nn, dx * dx + dy * dy + dz * dz);
    dx = px - qx.y; dy = py - qy.y; dz = pz - qz.y;
    ins6(nn, dx * dx + dy * dy + dz * dz);
    dx = px - qx.z; dy = py - qy.z; dz = pz - qz.z;
    ins6(nn, dx * dx + dy * dy + dz * dz);
    dx = px - qx.w; dy = py - qy.w; dz = pz - qz.w;
    ins6(nn, dx * dx + dy * dy + dz * dz);
  }
  // butterfly merge across the 8 subthreads: snapshot partner's list, then insert.
#pragma unroll
  for (int m = 1; m <= 4; m <<= 1) {
    float other[6];
#pragma unroll
    for (int k = 0; k < 6; k++) other[k] = __shfl_xor(nn[k], m);
#pragma unroll
    for (int k = 0; k < 6; k++) ins6(nn, other[k]);
  }
  if (sub == 0) {
    // ascending list: nn[0] is the self-0; mean of sqrt of nn[1..5]
    float dm = 0.2f * (sqrtf(nn[1]) + sqrtf(nn[2]) + sqrtf(nn[3]) + sqrtf(nn[4]) + sqrtf(nn[5]));
    float curv = 1.0f / (1e-8f + dm);
    size_t o = ((size_t)b * NPTS + row) * 4;
    feat[o + 0] = px;
    feat[o + 1] = py;
    feat[o + 2] = pz;
    feat[o + 3] = curv;
  }
}

// ---------------- layer1: [BP,4] @ [4,64]^T + b -> z1 [BP,64] ----------------
__global__ __launch_bounds__(256) void gemm1_kernel(const float* __restrict__ feat,
                                                    const float* __restrict__ w,
                                                    const float* __restrict__ bias,
                                                    float* __restrict__ z1) {
  __shared__ float wT[4 * 64];
  int tid = threadIdx.x;
  {
    int k = tid >> 6, c = tid & 63;
    wT[k * 64 + c] = w[c * 4 + k];
  }
  __syncthreads();
  int g = blockIdx.x * 256 + tid;
  int row = g >> 6, col = g & 63;
  const float* fr = feat + (size_t)row * 4;
  float acc = bias[col];
#pragma unroll
  for (int k = 0; k < 4; k++) acc += fr[k] * wT[k * 64 + col];
  z1[g] = acc;
}

// ---------------- per-column sum/sumsq partials of [65536, C] ----------------
template <int C>
__global__ __launch_bounds__(256) void colstats_kernel(const float* __restrict__ z,
                                                       float* __restrict__ part) {
  const int RPB = 256;
  int r0 = blockIdx.x * RPB;
  int col = threadIdx.x % C;
  int rsub = threadIdx.x / C;
  const int rstep = 256 / C;
  float s = 0.f, q = 0.f;
  for (int r = rsub; r < RPB; r += rstep) {
    float v = z[(size_t)(r0 + r) * C + col];
    s += v;
    q += v * v;
  }
  __shared__ float ls[256], lq[256];
  ls[threadIdx.x] = s;
  lq[threadIdx.x] = q;
  __syncthreads();
  if (threadIdx.x < C) {
    float ss = 0.f, qq = 0.f;
#pragma unroll
    for (int i = 0; i < rstep; i++) {
      ss += ls[i * C + threadIdx.x];
      qq += lq[i * C + threadIdx.x];
    }
    part[(size_t)(blockIdx.x * C + threadIdx.x) * 2 + 0] = ss;
    part[(size_t)(blockIdx.x * C + threadIdx.x) * 2 + 1] = qq;
  }
}

template <int C>
__global__ __launch_bounds__(256) void bnfin_kernel(const float* __restrict__ part,
                                                    const float* __restrict__ g,
                                                    const float* __restrict__ be,
                                                    float* __restrict__ scale,
                                                    float* __restrict__ shift) {
  int c = blockIdx.x, tid = threadIdx.x;
  __shared__ float ls[256], lq[256];
  ls[tid] = part[(size_t)(tid * C + c) * 2 + 0];
  lq[tid] = part[(size_t)(tid * C + c) * 2 + 1];
  __syncthreads();
  for (int off = 128; off > 0; off >>= 1) {
    if (tid < off) { ls[tid] += ls[tid + off]; lq[tid] += lq[tid + off]; }
    __syncthreads();
  }
  if (tid == 0) {
    float m = ls[0] * (1.0f / 65536.0f);
    float v = lq[0] * (1.0f / 65536.0f) - m * m;
    float a = g[c] / sqrtf(v + EPS_BN);
    scale[c] = a;
    shift[c] = be[c] - m * a;
  }
}

// ---------------- layer2: relu(bn(z1)) @ [64,128]^T + b -> z2 [BP,128] ----------------
__global__ __launch_bounds__(256) void gemm2_kernel(const float* __restrict__ z1,
                                                    const float* __restrict__ s1,
                                                    const float* __restrict__ h1,
                                                    const float* __restrict__ w2,
                                                    const float* __restrict__ bias2,
                                                    float* __restrict__ z2) {
  __shared__ float As[32 * 65];
  __shared__ float Bs[128 * 65];
  int tid = threadIdx.x;
  int row0 = blockIdx.x * 32;
#pragma unroll
  for (int i = 0; i < 8; i++) {
    int idx = tid + i * 256;
    int r = idx >> 6, k = idx & 63;
    float v = z1[(size_t)(row0 + r) * 64 + k];
    As[r * 65 + k] = fmaxf(v * s1[k] + h1[k], 0.f);
  }
#pragma unroll
  for (int i = 0; i < 32; i++) {
    int idx = tid + i * 256;
    int c = idx >> 6, k = idx & 63;
    Bs[c * 65 + k] = w2[(size_t)c * 64 + k];
  }
  __syncthreads();
  int tr = tid & 7, tc = tid >> 3;
  float acc[4][4] = {};
  for (int k = 0; k < 64; k++) {
    float a[4], bb[4];
#pragma unroll
    for (int j = 0; j < 4; j++) a[j] = As[(tr * 4 + j) * 65 + k];
#pragma unroll
    for (int l = 0; l < 4; l++) bb[l] = Bs[(tc * 4 + l) * 65 + k];
#pragma unroll
    for (int j = 0; j < 4; j++)
#pragma unroll
      for (int l = 0; l < 4; l++) acc[j][l] += a[j] * bb[l];
  }
  float bb0 = bias2[tc * 4 + 0], bb1 = bias2[tc * 4 + 1];
  float bb2 = bias2[tc * 4 + 2], bb3 = bias2[tc * 4 + 3];
#pragma unroll
  for (int j = 0; j < 4; j++) {
    int row = row0 + tr * 4 + j;
    float4 v = make_float4(acc[j][0] + bb0, acc[j][1] + bb1, acc[j][2] + bb2, acc[j][3] + bb3);
    *(float4*)&z2[(size_t)row * 128 + tc * 4] = v;
  }
}

// ---------------- bn2+relu -> bf16 convert: abf [65536][128] ----------------
__global__ __launch_bounds__(256) void bnrelu_bf16_kernel(const float* __restrict__ z2,
                                                          const float* __restrict__ s2,
                                                          const float* __restrict__ h2,
                                                          unsigned short* __restrict__ abf) {
  __shared__ float ss[128], hh[128];
  int tid = threadIdx.x;
  if (tid < 128) { ss[tid] = s2[tid]; hh[tid] = h2[tid]; }
  __syncthreads();
  int g = blockIdx.x * 256 + tid;
  int row = g >> 4, seg = g & 15;
  const float4* src = (const float4*)(z2 + (size_t)row * 128 + seg * 8);
  float4 v0 = src[0], v1 = src[1];
  int c = seg * 8;
  float vals[8] = {v0.x, v0.y, v0.z, v0.w, v1.x, v1.y, v1.z, v1.w};
  s16x8 o;
#pragma unroll
  for (int j = 0; j < 8; j++) {
    float v = fmaxf(vals[j] * ss[c + j] + hh[c + j], 0.f);
    o[j] = (short)f2bf(v);
  }
  *(s16x8*)(abf + (size_t)row * 128 + seg * 8) = o;
}

// ---------------- w3 -> bf16 ----------------
__global__ __launch_bounds__(256) void wconv_kernel(const float* __restrict__ w,
                                                    unsigned short* __restrict__ wbf) {
  int g = blockIdx.x * 256 + threadIdx.x;
  const float4 v = ((const float4*)w)[g];
  unsigned short o0 = f2bf(v.x), o1 = f2bf(v.y), o2 = f2bf(v.z), o3 = f2bf(v.w);
  unsigned short* d = wbf + (size_t)g * 4;
  d[0] = o0; d[1] = o1; d[2] = o2; d[3] = o3;
}

// ---------------- layer3 MFMA: abf[BP,128] @ wbf[1024,128]^T + b3 -> col stats ----------------
__global__ __launch_bounds__(256) void gemm3_mfma_kernel(const unsigned short* __restrict__ abf,
                                                         const unsigned short* __restrict__ wbf,
                                                         const float* __restrict__ bias3,
                                                         float* __restrict__ pS,
                                                         float* __restrict__ pQ,
                                                         float* __restrict__ pMx,
                                                         float* __restrict__ pMn) {
  __shared__ char lds[65536];
  int tid = threadIdx.x;
  int w = tid >> 6, lane = tid & 63;
  int row0 = blockIdx.y * 128, col0 = blockIdx.x * 128;

#pragma unroll
  for (int i = 0; i < 8; i++) {
    int ldsoff = w * 8192 + i * 1024;
    int lin = ldsoff + lane * 16;
    int row = lin >> 8;
    int gc = (lin >> 4) & 15;
    int gcl = gc ^ (row & 7);
    gload_lds16(abf + (size_t)(row0 + row) * 128 + gcl * 8, &lds[ldsoff]);
  }
#pragma unroll
  for (int i = 0; i < 8; i++) {
    int ldsoff = w * 8192 + i * 1024;
    int lin = ldsoff + lane * 16;
    int row = lin >> 8;
    int gc = (lin >> 4) & 15;
    int gcl = gc ^ (row & 7);
    gload_lds16(wbf + (size_t)(col0 + row) * 128 + gcl * 8, &lds[32768 + ldsoff]);
  }
  __syncthreads();

  int wm = w >> 1, wn = w & 1;
  int lrow = lane & 15, lg = lane >> 4;
  int sw = (lrow & 7) << 4;
  f32x4 acc[4][4] = {};
#pragma unroll
  for (int kstep = 0; kstep < 4; kstep++) {
    s16x8 a[4], b[4];
#pragma unroll
    for (int m = 0; m < 4; m++) {
      int row = wm * 64 + m * 16 + lrow;
      int byte = (row * 256 + kstep * 64 + lg * 16) ^ sw;
      a[m] = *(const s16x8*)(lds + byte);
    }
#pragma unroll
    for (int n = 0; n < 4; n++) {
      int col = wn * 64 + n * 16 + lrow;
      int byte = 32768 + ((col * 256 + kstep * 64 + lg * 16) ^ sw);
      b[n] = *(const s16x8*)(lds + byte);
    }
#pragma unroll
    for (int m = 0; m < 4; m++)
#pragma unroll
      for (int n = 0; n < 4; n++)
        acc[m][n] = __builtin_amdgcn_mfma_f32_16x16x32_bf16(a[m], b[n], acc[m][n], 0, 0, 0);
  }
  __syncthreads();

  float* sS = (float*)lds;
  float* sQ = sS + 256;
  float* sMx = sQ + 256;
  float* sMn = sMx + 256;
#pragma unroll
  for (int n = 0; n < 4; n++) {
    float bb = bias3[col0 + wn * 64 + n * 16 + lrow];
    float s = 0.f, q = 0.f, mx = -3.4e38f, mn = 3.4e38f;
#pragma unroll
    for (int m = 0; m < 4; m++)
#pragma unroll
      for (int r = 0; r < 4; r++) {
        float v = acc[m][n][r] + bb;
        s += v;
        q += v * v;
        mx = fmaxf(mx, v);
        mn = fminf(mn, v);
      }
    s += __shfl_xor(s, 16); s += __shfl_xor(s, 32);
    q += __shfl_xor(q, 16); q += __shfl_xor(q, 32);
    mx = fmaxf(mx, __shfl_xor(mx, 16)); mx = fmaxf(mx, __shfl_xor(mx, 32));
    mn = fminf(mn, __shfl_xor(mn, 16)); mn = fminf(mn, __shfl_xor(mn, 32));
    if (lane < 16) {
      int cidx = wn * 64 + n * 16 + lane;
      sS[wm * 128 + cidx] = s;
      sQ[wm * 128 + cidx] = q;
      sMx[wm * 128 + cidx] = mx;
      sMn[wm * 128 + cidx] = mn;
    }
  }
  __syncthreads();
  if (tid < 128) {
    size_t o = (size_t)blockIdx.y * 1024 + col0 + tid;
    pS[o] = sS[tid] + sS[128 + tid];
    pQ[o] = sQ[tid] + sQ[128 + tid];
    pMx[o] = fmaxf(sMx[tid], sMx[128 + tid]);
    pMn[o] = fminf(sMn[tid], sMn[128 + tid]);
  }
}

// ---------------- bn3 finalize + masked max-pool ----------------
__global__ __launch_bounds__(256) void bn3fin_pool_kernel(const float* __restrict__ pS,
                                                          const float* __restrict__ pQ,
                                                          const float* __restrict__ pMx,
                                                          const float* __restrict__ pMn,
                                                          const float* __restrict__ g,
                                                          const float* __restrict__ be,
                                                          float* __restrict__ pooled) {
  int tid = threadIdx.x;
  int chl = tid & 15, grp = tid >> 4;
  int c = blockIdx.x * 16 + chl;
  float s = 0.f, q = 0.f;
  for (int i = grp; i < 512; i += 16) {
    s += pS[(size_t)i * 1024 + c];
    q += pQ[(size_t)i * 1024 + c];
  }
  __shared__ float ls[256], lq[256], sa[16], sc[16];
  ls[chl * 16 + grp] = s;
  lq[chl * 16 + grp] = q;
  __syncthreads();
  if (tid < 16) {
    float ss = 0.f, qq = 0.f;
#pragma unroll
    for (int i = 0; i < 16; i++) { ss += ls[tid * 16 + i]; qq += lq[tid * 16 + i]; }
    float m = ss * (1.0f / 65536.0f);
    float v = qq * (1.0f / 65536.0f) - m * m;
    float a = g[blockIdx.x * 16 + tid] / sqrtf(v + EPS_BN);
    sa[tid] = a;
    sc[tid] = be[blockIdx.x * 16 + tid] - m * a;
  }
  __syncthreads();
  for (int idx = tid; idx < 512; idx += 256) {
    int b = idx >> 4, l = idx & 15;
    int cc = blockIdx.x * 16 + l;
    float mx = -3.4e38f, mn = 3.4e38f;
    for (int i = 0; i < 16; i++) {
      mx = fmaxf(mx, pMx[(size_t)(b * 16 + i) * 1024 + cc]);
      mn = fminf(mn, pMn[(size_t)(b * 16 + i) * 1024 + cc]);
    }
    float a = sa[l];
    float v = (a > 0.f) ? (a * mx + sc[l]) : (a * mn + sc[l]);
    pooled[(size_t)b * 1024 + cc] = fmaxf(v, 0.f);
  }
}

// ---------------- fc1 ----------------
__global__ __launch_bounds__(256) void fc1_kernel(const float* __restrict__ pooled,
                                                  const float* __restrict__ w,
                                                  const float* __restrict__ bias,
                                                  float* __restrict__ zf1) {
  int g = blockIdx.x * 256 + threadIdx.x;
  int b = g >> 9, o = g & 511;
  const float4* pr = (const float4*)(pooled + (size_t)b * 1024);
  const float4* wr = (const float4*)(w + (size_t)o * 1024);
  float acc = 0.f;
  for (int k = 0; k < 256; k++) {
    float4 p = pr[k], q = wr[k];
    acc += p.x * q.x + p.y * q.y + p.z * q.z + p.w * q.w;
  }
  zf1[g] = acc + bias[o];
}

__global__ __launch_bounds__(256) void statsF_kernel(const float* __restrict__ z,
                                                     const float* __restrict__ g,
                                                     const float* __restrict__ be, int C,
                                                     float* __restrict__ scale,
                                                     float* __restrict__ shift) {
  int c = blockIdx.x * 256 + threadIdx.x;
  if (c >= C) return;
  float s = 0.f, q = 0.f;
  for (int b = 0; b < 32; b++) {
    float v = z[(size_t)b * C + c];
    s += v;
    q += v * v;
  }
  float m = s * (1.0f / 32.0f);
  float v = q * (1.0f / 32.0f) - m * m;
  float a = g[c] / sqrtf(v + EPS_BN);
  scale[c] = a;
  shift[c] = be[c] - m * a;
}

__global__ __launch_bounds__(256) void fc2_kernel(const float* __restrict__ zf1,
                                                  const float* __restrict__ sf1,
                                                  const float* __restrict__ hf1,
                                                  const float* __restrict__ w,
                                                  const float* __restrict__ bias,
                                                  float* __restrict__ zf2) {
  int g = blockIdx.x * 256 + threadIdx.x;
  int b = g >> 8, o = g & 255;
  const float* zr = zf1 + (size_t)b * 512;
  const float* wr = w + (size_t)o * 512;
  float acc = 0.f;
  for (int k = 0; k < 512; k++) {
    float v = fmaxf(zr[k] * sf1[k] + hf1[k], 0.f);
    acc += v * wr[k];
  }
  zf2[g] = acc + bias[o];
}

__global__ __launch_bounds__(64) void head_kernel(const float* __restrict__ zf2,
                                                  const float* __restrict__ sf2,
                                                  const float* __restrict__ hf2,
                                                  const float* __restrict__ w,
                                                  const float* __restrict__ bias,
                                                  float* __restrict__ out) {
  int b = blockIdx.x, t = threadIdx.x;
  __shared__ float lg[40];
  __shared__ float red[2];
  if (t < 40) {
    const float* zr = zf2 + (size_t)b * 256;
    const float* wr = w + (size_t)t * 256;
    float acc = bias[t];
    for (int k = 0; k < 256; k++) {
      float v = fmaxf(zr[k] * sf2[k] + hf2[k], 0.f);
      acc += v * wr[k];
    }
    lg[t] = acc;
  }
  __syncthreads();
  if (t == 0) {
    float mx = -3.4e38f;
    for (int i = 0; i < 40; i++) mx = fmaxf(mx, lg[i]);
    float s = 0.f;
    for (int i = 0; i < 40; i++) s += expf(lg[i] - mx);
    red[0] = mx;
    red[1] = logf(s);
  }
  __syncthreads();
  if (t < 40) out[(size_t)b * 40 + t] = lg[t] - red[0] - red[1];
}

extern "C" void kernel_launch(void* const* d_in, const int* in_sizes, int n_in,
                              void* d_out, int out_size, void* d_ws, size_t ws_size,
                              hipStream_t stream) {
  const float* x    = (const float*)d_in[0];
  const float* c1w  = (const float*)d_in[1];
  const float* c1b  = (const float*)d_in[2];
  const float* g1   = (const float*)d_in[3];
  const float* be1  = (const float*)d_in[4];
  const float* c2w  = (const float*)d_in[5];
  const float* c2b  = (const float*)d_in[6];
  const float* g2   = (const float*)d_in[7];
  const float* be2  = (const float*)d_in[8];
  const float* c3w  = (const float*)d_in[9];
  const float* c3b  = (const float*)d_in[10];
  const float* g3   = (const float*)d_in[11];
  const float* be3  = (const float*)d_in[12];
  const float* f1w  = (const float*)d_in[13];
  const float* f1b  = (const float*)d_in[14];
  const float* gf1  = (const float*)d_in[15];
  const float* bef1 = (const float*)d_in[16];
  const float* f2w  = (const float*)d_in[17];
  const float* f2b  = (const float*)d_in[18];
  const float* gf2  = (const float*)d_in[19];
  const float* bef2 = (const float*)d_in[20];
  const float* ow   = (const float*)d_in[21];
  const float* ob   = (const float*)d_in[22];
  float* out = (float*)d_out;

  float* W = (float*)d_ws;
  float* feat   = W;                   // 262144
  float* z1     = feat + 262144;       // 4194304 (reused as abf bf16)
  float* z2     = z1 + 4194304;        // 8388608
  float* pS     = z2 + 8388608;        // 524288
  float* pQ     = pS + 524288;
  float* pMx    = pQ + 524288;
  float* pMn    = pMx + 524288;
  float* pooled = pMn + 524288;        // 32768
  float* zf1    = pooled + 32768;      // 16384
  float* zf2    = zf1 + 16384;         // 8192
  float* spart  = zf2 + 8192;          // 65536
  float* s1     = spart + 65536;       // 64
  float* h1     = s1 + 64;
  float* s2     = h1 + 64;             // 128
  float* h2     = s2 + 128;
  float* sf1    = h2 + 128;            // 512
  float* hf1    = sf1 + 512;
  float* sf2    = hf1 + 512;           // 256
  float* hf2    = sf2 + 256;
  unsigned short* wbf = (unsigned short*)(hf2 + 256);
  unsigned short* abf = (unsigned short*)z1;

  wconv_kernel<<<128, 256, 0, stream>>>(c3w, wbf);
  curv_kernel<<<dim3(64, 32), 256, 0, stream>>>(x, feat);
  gemm1_kernel<<<16384, 256, 0, stream>>>(feat, c1w, c1b, z1);
  colstats_kernel<64><<<256, 256, 0, stream>>>(z1, spart);
  bnfin_kernel<64><<<64, 256, 0, stream>>>(spart, g1, be1, s1, h1);
  gemm2_kernel<<<2048, 256, 0, stream>>>(z1, s1, h1, c2w, c2b, z2);
  colstats_kernel<128><<<256, 256, 0, stream>>>(z2, spart);
  bnfin_kernel<128><<<128, 256, 0, stream>>>(spart, g2, be2, s2, h2);
  bnrelu_bf16_kernel<<<4096, 256, 0, stream>>>(z2, s2, h2, abf);
  gemm3_mfma_kernel<<<dim3(8, 512), 256, 0, stream>>>(abf, wbf, c3b, pS, pQ, pMx, pMn);
  bn3fin_pool_kernel<<<64, 256, 0, stream>>>(pS, pQ, pMx, pMn, g3, be3, pooled);
  fc1_kernel<<<64, 256, 0, stream>>>(pooled, f1w, f1b, zf1);
  statsF_kernel<<<2, 256, 0, stream>>>(zf1, gf1, bef1, 512, sf1, hf1);
  fc2_kernel<<<32, 256, 0, stream>>>(zf1, sf1, hf1, f2w, f2b, zf2);
  statsF_kernel<<<1, 256, 0, stream>>>(zf2, gf2, bef2, 256, sf2, hf2);
  head_kernel<<<32, 64, 0, stream>>>(zf2, sf2, hf2, ow, ob, out);
}

// Round 7
// 214.765 us; speedup vs baseline: 3.6795x; 1.3245x over previous
//
#include <hip/hip_runtime.h>
#include <math.h>

#define EPS_BN 1e-5f

constexpr int BATCH = 32;
constexpr int NPTS  = 2048;
constexpr int BP    = BATCH * NPTS;   // 65536

using s16x8 = __attribute__((ext_vector_type(8))) short;
using u16x4 = __attribute__((ext_vector_type(4))) unsigned short;
using f32x4 = __attribute__((ext_vector_type(4))) float;

static __device__ __forceinline__ unsigned short f2bf(float f) {
  union { float f; unsigned u; } x{f};
  unsigned r = x.u + 0x7fffu + ((x.u >> 16) & 1u);  // RNE
  return (unsigned short)(r >> 16);
}
static __device__ __forceinline__ float bf2f(unsigned short s) {
  union { unsigned u; float f; } x;
  x.u = ((unsigned)s) << 16;
  return x.f;
}

static __device__ __forceinline__ void gload_lds16(const void* g, void* l) {
  __builtin_amdgcn_global_load_lds((const __attribute__((address_space(1))) void*)g,
                                   (__attribute__((address_space(3))) void*)l, 16, 0, 0);
}

// keep-6-smallest, ASCENDING list, depth-1 branchless insert (1 min + 5 med3).
static __device__ __forceinline__ void ins6(float (&nn)[6], float c) {
  float b0 = fminf(nn[0], c);
  float b1 = __builtin_amdgcn_fmed3f(c, nn[1], nn[0]);
  float b2 = __builtin_amdgcn_fmed3f(c, nn[2], nn[1]);
  float b3 = __builtin_amdgcn_fmed3f(c, nn[3], nn[2]);
  float b4 = __builtin_amdgcn_fmed3f(c, nn[4], nn[3]);
  float b5 = __builtin_amdgcn_fmed3f(c, nn[5], nn[4]);
  nn[0] = b0; nn[1] = b1; nn[2] = b2; nn[3] = b3; nn[4] = b4; nn[5] = b5;
}

// ---------------- curvature: rank by r = 0.5|q|^2 - p.q  (d2 = |p|^2 + 2r) ----------------
constexpr int CH = 260;  // padded chunk stride (floats)
__global__ __launch_bounds__(256) void curv_kernel(const float* __restrict__ x,
                                                   float* __restrict__ feat) {
  __shared__ float sx[8 * CH], sy[8 * CH], sz[8 * CH], sh[8 * CH];
  int b = blockIdx.y;
  const float* xb = x + (size_t)b * NPTS * 3;
  int tid = threadIdx.x;
#pragma unroll
  for (int k = 0; k < 8; k++) {
    int i = k * 256 + tid;
    float qx = xb[i * 3 + 0], qy = xb[i * 3 + 1], qz = xb[i * 3 + 2];
    sx[k * CH + tid] = qx;
    sy[k * CH + tid] = qy;
    sz[k * CH + tid] = qz;
    sh[k * CH + tid] = 0.5f * (qx * qx + qy * qy + qz * qz);
  }
  __syncthreads();
  int row = blockIdx.x * 32 + (tid >> 3);
  int sub = tid & 7;
  float px = sx[(row >> 8) * CH + (row & 255)];
  float py = sy[(row >> 8) * CH + (row & 255)];
  float pz = sz[(row >> 8) * CH + (row & 255)];
  float nn[6];
#pragma unroll
  for (int j = 0; j < 6; j++) nn[j] = 3.4e38f;
  const float4* cx = (const float4*)(sx + sub * CH);
  const float4* cy = (const float4*)(sy + sub * CH);
  const float4* cz = (const float4*)(sz + sub * CH);
  const float4* chq = (const float4*)(sh + sub * CH);
  for (int j = 0; j < 64; j++) {
    float4 qx = cx[j], qy = cy[j], qz = cz[j], qh = chq[j];
    ins6(nn, fmaf(-px, qx.x, fmaf(-py, qy.x, fmaf(-pz, qz.x, qh.x))));
    ins6(nn, fmaf(-px, qx.y, fmaf(-py, qy.y, fmaf(-pz, qz.y, qh.y))));
    ins6(nn, fmaf(-px, qx.z, fmaf(-py, qy.z, fmaf(-pz, qz.z, qh.z))));
    ins6(nn, fmaf(-px, qx.w, fmaf(-py, qy.w, fmaf(-pz, qz.w, qh.w))));
  }
  // butterfly merge across the 8 subthreads: snapshot partner's list, then insert.
#pragma unroll
  for (int m = 1; m <= 4; m <<= 1) {
    float other[6];
#pragma unroll
    for (int k = 0; k < 6; k++) other[k] = __shfl_xor(nn[k], m);
#pragma unroll
    for (int k = 0; k < 6; k++) ins6(nn, other[k]);
  }
  if (sub == 0) {
    float p2 = px * px + py * py + pz * pz;
    // ascending r: nn[0] is the self; d2_i = max(0, p2 + 2*nn[i])
    float dm = 0.f;
#pragma unroll
    for (int i = 1; i < 6; i++) dm += sqrtf(fmaxf(fmaf(2.f, nn[i], p2), 0.f));
    dm *= 0.2f;
    float curv = 1.0f / (1e-8f + dm);
    size_t o = ((size_t)b * NPTS + row) * 4;
    feat[o + 0] = px;
    feat[o + 1] = py;
    feat[o + 2] = pz;
    feat[o + 3] = curv;
  }
}

// ---------------- layer1 fused: z1bf = feat @ W1^T + b1 (bf16), + BN1 stats partials ----------------
__global__ __launch_bounds__(256) void gemm1s_kernel(const float* __restrict__ feat,
                                                     const float* __restrict__ w,
                                                     const float* __restrict__ bias,
                                                     unsigned short* __restrict__ z1bf,
                                                     float* __restrict__ part) {
  __shared__ float wT[4 * 64];
  int tid = threadIdx.x;
  { int k = tid >> 6, c = tid & 63; wT[k * 64 + c] = w[c * 4 + k]; }
  __syncthreads();
  int col = tid & 63, rg = tid >> 6;
  int row0 = blockIdx.x * 256;
  float w0 = wT[col], w1 = wT[64 + col], w2v = wT[128 + col], w3 = wT[192 + col];
  float bb = bias[col];
  float s = 0.f, q = 0.f;
  for (int i = 0; i < 64; i++) {
    int row = row0 + i * 4 + rg;
    const float4 f = *(const float4*)(feat + (size_t)row * 4);
    float acc = bb + f.x * w0 + f.y * w1 + f.z * w2v + f.w * w3;
    s += acc;
    q += acc * acc;
    z1bf[(size_t)row * 64 + col] = f2bf(acc);
  }
  __shared__ float ls[256], lq[256];
  ls[tid] = s; lq[tid] = q;
  __syncthreads();
  if (tid < 64) {
    float ss = 0.f, qq = 0.f;
#pragma unroll
    for (int i = 0; i < 4; i++) { ss += ls[i * 64 + tid]; qq += lq[i * 64 + tid]; }
    part[((size_t)blockIdx.x * 64 + tid) * 2 + 0] = ss;
    part[((size_t)blockIdx.x * 64 + tid) * 2 + 1] = qq;
  }
}

// ---------------- generic BN finalize from P partials ----------------
template <int C, int P>
__global__ __launch_bounds__(256) void bnfinP_kernel(const float* __restrict__ part,
                                                     const float* __restrict__ g,
                                                     const float* __restrict__ be,
                                                     float* __restrict__ scale,
                                                     float* __restrict__ shift) {
  int c = blockIdx.x, tid = threadIdx.x;
  float s = 0.f, q = 0.f;
  for (int i = tid; i < P; i += 256) {
    s += part[((size_t)i * C + c) * 2 + 0];
    q += part[((size_t)i * C + c) * 2 + 1];
  }
  __shared__ float ls[256], lq[256];
  ls[tid] = s; lq[tid] = q;
  __syncthreads();
  for (int off = 128; off > 0; off >>= 1) {
    if (tid < off) { ls[tid] += ls[tid + off]; lq[tid] += lq[tid + off]; }
    __syncthreads();
  }
  if (tid == 0) {
    float m = ls[0] * (1.0f / 65536.0f);
    float v = lq[0] * (1.0f / 65536.0f) - m * m;
    float a = g[c] / sqrtf(v + EPS_BN);
    scale[c] = a;
    shift[c] = be[c] - m * a;
  }
}

// ---------------- layer2 fused: relu(bn1(z1bf)) @ W2^T + b2 -> z2bf (bf16) + BN2 stats ----------------
__global__ __launch_bounds__(256) void gemm2_kernel(const unsigned short* __restrict__ z1bf,
                                                    const float* __restrict__ s1,
                                                    const float* __restrict__ h1,
                                                    const float* __restrict__ w2,
                                                    const float* __restrict__ bias2,
                                                    unsigned short* __restrict__ z2bf,
                                                    float* __restrict__ part2) {
  __shared__ float As[64 * 36];   // [k][r], r stride 36 (16B aligned fragments)
  __shared__ float Bs[64 * 132];  // [k][c]
  __shared__ float scr[128 * 9];
  int tid = threadIdx.x;
  int row0 = blockIdx.x * 32;
  {
    int k = tid & 63, r0 = (tid >> 6) * 8;
    float sk = s1[k], hk = h1[k];
#pragma unroll
    for (int u = 0; u < 8; u++) {
      int r = r0 + u;
      float f = bf2f(z1bf[(size_t)(row0 + r) * 64 + k]);
      As[k * 36 + r] = fmaxf(f * sk + hk, 0.f);
    }
  }
#pragma unroll
  for (int i = 0; i < 32; i++) {
    int idx = tid + i * 256;
    int c = idx >> 6, k = idx & 63;
    Bs[k * 132 + c] = w2[(size_t)c * 64 + k];
  }
  __syncthreads();
  int tr = tid & 7, tc = tid >> 3;  // rows tr*4+j (0..31), cols tc*4+l (0..127)
  float acc[4][4] = {};
  for (int k = 0; k < 64; k++) {
    float4 a = *(const float4*)(As + k * 36 + tr * 4);
    float4 b = *(const float4*)(Bs + k * 132 + tc * 4);
    float av[4] = {a.x, a.y, a.z, a.w};
    float bv[4] = {b.x, b.y, b.z, b.w};
#pragma unroll
    for (int j = 0; j < 4; j++)
#pragma unroll
      for (int l = 0; l < 4; l++) acc[j][l] += av[j] * bv[l];
  }
  float bb[4];
#pragma unroll
  for (int l = 0; l < 4; l++) bb[l] = bias2[tc * 4 + l];
#pragma unroll
  for (int j = 0; j < 4; j++)
#pragma unroll
    for (int l = 0; l < 4; l++) acc[j][l] += bb[l];
  // z2 bf16 write
#pragma unroll
  for (int j = 0; j < 4; j++) {
    int row = row0 + tr * 4 + j;
    u16x4 o;
#pragma unroll
    for (int l = 0; l < 4; l++) o[l] = f2bf(acc[j][l]);
    *(u16x4*)(z2bf + (size_t)row * 128 + tc * 4) = o;
  }
  // col stats over this block's 32 rows
#pragma unroll
  for (int l = 0; l < 4; l++)
    scr[(tc * 4 + l) * 9 + tr] = acc[0][l] + acc[1][l] + acc[2][l] + acc[3][l];
  __syncthreads();
  if (tid < 128) {
    float s = 0.f;
#pragma unroll
    for (int i = 0; i < 8; i++) s += scr[tid * 9 + i];
    part2[((size_t)blockIdx.x * 128 + tid) * 2 + 0] = s;
  }
  __syncthreads();
#pragma unroll
  for (int l = 0; l < 4; l++)
    scr[(tc * 4 + l) * 9 + tr] = acc[0][l] * acc[0][l] + acc[1][l] * acc[1][l] +
                                 acc[2][l] * acc[2][l] + acc[3][l] * acc[3][l];
  __syncthreads();
  if (tid < 128) {
    float q = 0.f;
#pragma unroll
    for (int i = 0; i < 8; i++) q += scr[tid * 9 + i];
    part2[((size_t)blockIdx.x * 128 + tid) * 2 + 1] = q;
  }
}

// ---------------- bn2+relu -> bf16: abf = relu(bn2(z2bf)) ----------------
__global__ __launch_bounds__(256) void bnrelu_bf16_kernel(const unsigned short* __restrict__ z2bf,
                                                          const float* __restrict__ s2,
                                                          const float* __restrict__ h2,
                                                          unsigned short* __restrict__ abf) {
  __shared__ float ss[128], hh[128];
  int tid = threadIdx.x;
  if (tid < 128) { ss[tid] = s2[tid]; hh[tid] = h2[tid]; }
  __syncthreads();
  int g = blockIdx.x * 256 + tid;  // 1048576 groups of 8
  int c0 = (g & 15) * 8;
  s16x8 v = *(const s16x8*)(z2bf + (size_t)g * 8);
  s16x8 o;
#pragma unroll
  for (int j = 0; j < 8; j++) {
    float f = bf2f((unsigned short)v[j]);
    float val = fmaxf(f * ss[c0 + j] + hh[c0 + j], 0.f);
    o[j] = (short)f2bf(val);
  }
  *(s16x8*)(abf + (size_t)g * 8) = o;
}

// ---------------- w3 -> bf16 ----------------
__global__ __launch_bounds__(256) void wconv_kernel(const float* __restrict__ w,
                                                    unsigned short* __restrict__ wbf) {
  int g = blockIdx.x * 256 + threadIdx.x;
  const float4 v = ((const float4*)w)[g];
  unsigned short o0 = f2bf(v.x), o1 = f2bf(v.y), o2 = f2bf(v.z), o3 = f2bf(v.w);
  unsigned short* d = wbf + (size_t)g * 4;
  d[0] = o0; d[1] = o1; d[2] = o2; d[3] = o3;
}

// ---------------- layer3 MFMA, XCD-chunked grid: abf @ wbf^T + b3 -> col stats ----------------
__global__ __launch_bounds__(256) void gemm3_mfma_kernel(const unsigned short* __restrict__ abf,
                                                         const unsigned short* __restrict__ wbf,
                                                         const float* __restrict__ bias3,
                                                         float* __restrict__ pS,
                                                         float* __restrict__ pQ,
                                                         float* __restrict__ pMx,
                                                         float* __restrict__ pMn) {
  __shared__ char lds[65536];
  int tid = threadIdx.x;
  int w = tid >> 6, lane = tid & 63;
  // XCD-chunked mapping: each XCD owns a contiguous 64-row-block range.
  int bid = blockIdx.x;
  int xcd = bid & 7, j = bid >> 3;
  int rblk = xcd * 64 + (j & 63);
  int cblk = j >> 6;
  int row0 = rblk * 128, col0 = cblk * 128;

#pragma unroll
  for (int i = 0; i < 8; i++) {
    int ldsoff = w * 8192 + i * 1024;
    int lin = ldsoff + lane * 16;
    int row = lin >> 8;
    int gc = (lin >> 4) & 15;
    int gcl = gc ^ (row & 7);
    gload_lds16(abf + (size_t)(row0 + row) * 128 + gcl * 8, &lds[ldsoff]);
  }
#pragma unroll
  for (int i = 0; i < 8; i++) {
    int ldsoff = w * 8192 + i * 1024;
    int lin = ldsoff + lane * 16;
    int row = lin >> 8;
    int gc = (lin >> 4) & 15;
    int gcl = gc ^ (row & 7);
    gload_lds16(wbf + (size_t)(col0 + row) * 128 + gcl * 8, &lds[32768 + ldsoff]);
  }
  __syncthreads();

  int wm = w >> 1, wn = w & 1;
  int lrow = lane & 15, lg = lane >> 4;
  int sw = (lrow & 7) << 4;
  f32x4 acc[4][4] = {};
#pragma unroll
  for (int kstep = 0; kstep < 4; kstep++) {
    s16x8 a[4], b[4];
#pragma unroll
    for (int m = 0; m < 4; m++) {
      int row = wm * 64 + m * 16 + lrow;
      int byte = (row * 256 + kstep * 64 + lg * 16) ^ sw;
      a[m] = *(const s16x8*)(lds + byte);
    }
#pragma unroll
    for (int n = 0; n < 4; n++) {
      int col = wn * 64 + n * 16 + lrow;
      int byte = 32768 + ((col * 256 + kstep * 64 + lg * 16) ^ sw);
      b[n] = *(const s16x8*)(lds + byte);
    }
#pragma unroll
    for (int m = 0; m < 4; m++)
#pragma unroll
      for (int n = 0; n < 4; n++)
        acc[m][n] = __builtin_amdgcn_mfma_f32_16x16x32_bf16(a[m], b[n], acc[m][n], 0, 0, 0);
  }
  __syncthreads();

  float* sS = (float*)lds;
  float* sQ = sS + 256;
  float* sMx = sQ + 256;
  float* sMn = sMx + 256;
#pragma unroll
  for (int n = 0; n < 4; n++) {
    float bb = bias3[col0 + wn * 64 + n * 16 + lrow];
    float s = 0.f, q = 0.f, mx = -3.4e38f, mn = 3.4e38f;
#pragma unroll
    for (int m = 0; m < 4; m++)
#pragma unroll
      for (int r = 0; r < 4; r++) {
        float v = acc[m][n][r] + bb;
        s += v;
        q += v * v;
        mx = fmaxf(mx, v);
        mn = fminf(mn, v);
      }
    s += __shfl_xor(s, 16); s += __shfl_xor(s, 32);
    q += __shfl_xor(q, 16); q += __shfl_xor(q, 32);
    mx = fmaxf(mx, __shfl_xor(mx, 16)); mx = fmaxf(mx, __shfl_xor(mx, 32));
    mn = fminf(mn, __shfl_xor(mn, 16)); mn = fminf(mn, __shfl_xor(mn, 32));
    if (lane < 16) {
      int cidx = wn * 64 + n * 16 + lane;
      sS[wm * 128 + cidx] = s;
      sQ[wm * 128 + cidx] = q;
      sMx[wm * 128 + cidx] = mx;
      sMn[wm * 128 + cidx] = mn;
    }
  }
  __syncthreads();
  if (tid < 128) {
    size_t o = (size_t)rblk * 1024 + col0 + tid;
    pS[o] = sS[tid] + sS[128 + tid];
    pQ[o] = sQ[tid] + sQ[128 + tid];
    pMx[o] = fmaxf(sMx[tid], sMx[128 + tid]);
    pMn[o] = fminf(sMn[tid], sMn[128 + tid]);
  }
}

// ---------------- bn3 finalize + masked max-pool ----------------
__global__ __launch_bounds__(256) void bn3fin_pool_kernel(const float* __restrict__ pS,
                                                          const float* __restrict__ pQ,
                                                          const float* __restrict__ pMx,
                                                          const float* __restrict__ pMn,
                                                          const float* __restrict__ g,
                                                          const float* __restrict__ be,
                                                          float* __restrict__ pooled) {
  int tid = threadIdx.x;
  int chl = tid & 15, grp = tid >> 4;
  int c = blockIdx.x * 16 + chl;
  float s = 0.f, q = 0.f;
  for (int i = grp; i < 512; i += 16) {
    s += pS[(size_t)i * 1024 + c];
    q += pQ[(size_t)i * 1024 + c];
  }
  __shared__ float ls[256], lq[256], sa[16], sc[16];
  ls[chl * 16 + grp] = s;
  lq[chl * 16 + grp] = q;
  __syncthreads();
  if (tid < 16) {
    float ss = 0.f, qq = 0.f;
#pragma unroll
    for (int i = 0; i < 16; i++) { ss += ls[tid * 16 + i]; qq += lq[tid * 16 + i]; }
    float m = ss * (1.0f / 65536.0f);
    float v = qq * (1.0f / 65536.0f) - m * m;
    float a = g[blockIdx.x * 16 + tid] / sqrtf(v + EPS_BN);
    sa[tid] = a;
    sc[tid] = be[blockIdx.x * 16 + tid] - m * a;
  }
  __syncthreads();
  for (int idx = tid; idx < 512; idx += 256) {
    int b = idx >> 4, l = idx & 15;
    int cc = blockIdx.x * 16 + l;
    float mx = -3.4e38f, mn = 3.4e38f;
    for (int i = 0; i < 16; i++) {
      mx = fmaxf(mx, pMx[(size_t)(b * 16 + i) * 1024 + cc]);
      mn = fminf(mn, pMn[(size_t)(b * 16 + i) * 1024 + cc]);
    }
    float a = sa[l];
    float v = (a > 0.f) ? (a * mx + sc[l]) : (a * mn + sc[l]);
    pooled[(size_t)b * 1024 + cc] = fmaxf(v, 0.f);
  }
}

// ---------------- fc1 ----------------
__global__ __launch_bounds__(256) void fc1_kernel(const float* __restrict__ pooled,
                                                  const float* __restrict__ w,
                                                  const float* __restrict__ bias,
                                                  float* __restrict__ zf1) {
  int g = blockIdx.x * 256 + threadIdx.x;
  int b = g >> 9, o = g & 511;
  const float4* pr = (const float4*)(pooled + (size_t)b * 1024);
  const float4* wr = (const float4*)(w + (size_t)o * 1024);
  float acc = 0.f;
  for (int k = 0; k < 256; k++) {
    float4 p = pr[k], q = wr[k];
    acc += p.x * q.x + p.y * q.y + p.z * q.z + p.w * q.w;
  }
  zf1[g] = acc + bias[o];
}

__global__ __launch_bounds__(256) void statsF_kernel(const float* __restrict__ z,
                                                     const float* __restrict__ g,
                                                     const float* __restrict__ be, int C,
                                                     float* __restrict__ scale,
                                                     float* __restrict__ shift) {
  int c = blockIdx.x * 256 + threadIdx.x;
  if (c >= C) return;
  float s = 0.f, q = 0.f;
  for (int b = 0; b < 32; b++) {
    float v = z[(size_t)b * C + c];
    s += v;
    q += v * v;
  }
  float m = s * (1.0f / 32.0f);
  float v = q * (1.0f / 32.0f) - m * m;
  float a = g[c] / sqrtf(v + EPS_BN);
  scale[c] = a;
  shift[c] = be[c] - m * a;
}

__global__ __launch_bounds__(256) void fc2_kernel(const float* __restrict__ zf1,
                                                  const float* __restrict__ sf1,
                                                  const float* __restrict__ hf1,
                                                  const float* __restrict__ w,
                                                  const float* __restrict__ bias,
                                                  float* __restrict__ zf2) {
  int g = blockIdx.x * 256 + threadIdx.x;
  int b = g >> 8, o = g & 255;
  const float* zr = zf1 + (size_t)b * 512;
  const float* wr = w + (size_t)o * 512;
  float acc = 0.f;
  for (int k = 0; k < 512; k++) {
    float v = fmaxf(zr[k] * sf1[k] + hf1[k], 0.f);
    acc += v * wr[k];
  }
  zf2[g] = acc + bias[o];
}

__global__ __launch_bounds__(64) void head_kernel(const float* __restrict__ zf2,
                                                  const float* __restrict__ sf2,
                                                  const float* __restrict__ hf2,
                                                  const float* __restrict__ w,
                                                  const float* __restrict__ bias,
                                                  float* __restrict__ out) {
  int b = blockIdx.x, t = threadIdx.x;
  __shared__ float lg[40];
  __shared__ float red[2];
  if (t < 40) {
    const float* zr = zf2 + (size_t)b * 256;
    const float* wr = w + (size_t)t * 256;
    float acc = bias[t];
    for (int k = 0; k < 256; k++) {
      float v = fmaxf(zr[k] * sf2[k] + hf2[k], 0.f);
      acc += v * wr[k];
    }
    lg[t] = acc;
  }
  __syncthreads();
  if (t == 0) {
    float mx = -3.4e38f;
    for (int i = 0; i < 40; i++) mx = fmaxf(mx, lg[i]);
    float s = 0.f;
    for (int i = 0; i < 40; i++) s += expf(lg[i] - mx);
    red[0] = mx;
    red[1] = logf(s);
  }
  __syncthreads();
  if (t < 40) out[(size_t)b * 40 + t] = lg[t] - red[0] - red[1];
}

extern "C" void kernel_launch(void* const* d_in, const int* in_sizes, int n_in,
                              void* d_out, int out_size, void* d_ws, size_t ws_size,
                              hipStream_t stream) {
  const float* x    = (const float*)d_in[0];
  const float* c1w  = (const float*)d_in[1];
  const float* c1b  = (const float*)d_in[2];
  const float* g1   = (const float*)d_in[3];
  const float* be1  = (const float*)d_in[4];
  const float* c2w  = (const float*)d_in[5];
  const float* c2b  = (const float*)d_in[6];
  const float* g2   = (const float*)d_in[7];
  const float* be2  = (const float*)d_in[8];
  const float* c3w  = (const float*)d_in[9];
  const float* c3b  = (const float*)d_in[10];
  const float* g3   = (const float*)d_in[11];
  const float* be3  = (const float*)d_in[12];
  const float* f1w  = (const float*)d_in[13];
  const float* f1b  = (const float*)d_in[14];
  const float* gf1  = (const float*)d_in[15];
  const float* bef1 = (const float*)d_in[16];
  const float* f2w  = (const float*)d_in[17];
  const float* f2b  = (const float*)d_in[18];
  const float* gf2  = (const float*)d_in[19];
  const float* bef2 = (const float*)d_in[20];
  const float* ow   = (const float*)d_in[21];
  const float* ob   = (const float*)d_in[22];
  float* out = (float*)d_out;

  float* W = (float*)d_ws;
  float* feat   = W;                   // 262144
  float* pS     = feat + 262144;       // 524288
  float* pQ     = pS + 524288;
  float* pMx    = pQ + 524288;
  float* pMn    = pMx + 524288;
  float* part   = pMn + 524288;        // 32768 (BN1 partials, 256x64x2)
  float* part2  = part + 32768;        // 524288 (BN2 partials, 2048x128x2)
  float* pooled = part2 + 524288;      // 32768
  float* zf1    = pooled + 32768;      // 16384
  float* zf2    = zf1 + 16384;         // 8192
  float* s1     = zf2 + 8192;          // 64
  float* h1     = s1 + 64;
  float* s2     = h1 + 64;             // 128
  float* h2     = s2 + 128;
  float* sf1    = h2 + 128;            // 512
  float* hf1    = sf1 + 512;
  float* sf2    = hf1 + 512;           // 256
  float* hf2    = sf2 + 256;
  unsigned short* wbf  = (unsigned short*)(hf2 + 256);   // 131072 shorts
  unsigned short* z1bf = wbf + 131072;                   // 65536*64
  unsigned short* z2bf = z1bf + (size_t)BP * 64;         // 65536*128
  unsigned short* abf  = z2bf + (size_t)BP * 128;        // 65536*128

  wconv_kernel<<<128, 256, 0, stream>>>(c3w, wbf);
  curv_kernel<<<dim3(64, 32), 256, 0, stream>>>(x, feat);
  gemm1s_kernel<<<256, 256, 0, stream>>>(feat, c1w, c1b, z1bf, part);
  bnfinP_kernel<64, 256><<<64, 256, 0, stream>>>(part, g1, be1, s1, h1);
  gemm2_kernel<<<2048, 256, 0, stream>>>(z1bf, s1, h1, c2w, c2b, z2bf, part2);
  bnfinP_kernel<128, 2048><<<128, 256, 0, stream>>>(part2, g2, be2, s2, h2);
  bnrelu_bf16_kernel<<<4096, 256, 0, stream>>>(z2bf, s2, h2, abf);
  gemm3_mfma_kernel<<<4096, 256, 0, stream>>>(abf, wbf, c3b, pS, pQ, pMx, pMn);
  bn3fin_pool_kernel<<<64, 256, 0, stream>>>(pS, pQ, pMx, pMn, g3, be3, pooled);
  fc1_kernel<<<64, 256, 0, stream>>>(pooled, f1w, f1b, zf1);
  statsF_kernel<<<2, 256, 0, stream>>>(zf1, gf1, bef1, 512, sf1, hf1);
  fc2_kernel<<<32, 256, 0, stream>>>(zf1, sf1, hf1, f2w, f2b, zf2);
  statsF_kernel<<<1, 256, 0, stream>>>(zf2, gf2, bef2, 256, sf2, hf2);
  head_kernel<<<32, 64, 0, stream>>>(zf2, sf2, hf2, ow, ob, out);
}

// Round 8
// 161.650 us; speedup vs baseline: 4.8885x; 1.3286x over previous
//
#include <hip/hip_runtime.h>
#include <math.h>

#define EPS_BN 1e-5f

constexpr int BATCH = 32;
constexpr int NPTS  = 2048;
constexpr int BP    = BATCH * NPTS;   // 65536

using s16x8 = __attribute__((ext_vector_type(8))) short;
using u16x4 = __attribute__((ext_vector_type(4))) unsigned short;
using f32x4 = __attribute__((ext_vector_type(4))) float;

static __device__ __forceinline__ unsigned short f2bf(float f) {
  union { float f; unsigned u; } x{f};
  unsigned r = x.u + 0x7fffu + ((x.u >> 16) & 1u);  // RNE
  return (unsigned short)(r >> 16);
}
static __device__ __forceinline__ float bf2f(unsigned short s) {
  union { unsigned u; float f; } x;
  x.u = ((unsigned)s) << 16;
  return x.f;
}

static __device__ __forceinline__ void gload_lds16(const void* g, void* l) {
  __builtin_amdgcn_global_load_lds((const __attribute__((address_space(1))) void*)g,
                                   (__attribute__((address_space(3))) void*)l, 16, 0, 0);
}

static __device__ __forceinline__ float wave_reduce_add(float v) {
#pragma unroll
  for (int off = 32; off > 0; off >>= 1) v += __shfl_xor(v, off);
  return v;
}

// keep-6-smallest, ASCENDING list, depth-1 branchless insert (1 min + 5 med3).
static __device__ __forceinline__ void ins6(float (&nn)[6], float c) {
  float b0 = fminf(nn[0], c);
  float b1 = __builtin_amdgcn_fmed3f(c, nn[1], nn[0]);
  float b2 = __builtin_amdgcn_fmed3f(c, nn[2], nn[1]);
  float b3 = __builtin_amdgcn_fmed3f(c, nn[3], nn[2]);
  float b4 = __builtin_amdgcn_fmed3f(c, nn[4], nn[3]);
  float b5 = __builtin_amdgcn_fmed3f(c, nn[5], nn[4]);
  nn[0] = b0; nn[1] = b1; nn[2] = b2; nn[3] = b3; nn[4] = b4; nn[5] = b5;
}

// ---------------- curvature: rank by r = 0.5|q|^2 - p.q  (d2 = |p|^2 + 2r) ----------------
constexpr int CH = 260;  // padded chunk stride (floats)
__global__ __launch_bounds__(256) void curv_kernel(const float* __restrict__ x,
                                                   float* __restrict__ feat) {
  __shared__ float sx[8 * CH], sy[8 * CH], sz[8 * CH], sh[8 * CH];
  int b = blockIdx.y;
  const float* xb = x + (size_t)b * NPTS * 3;
  int tid = threadIdx.x;
#pragma unroll
  for (int k = 0; k < 8; k++) {
    int i = k * 256 + tid;
    float qx = xb[i * 3 + 0], qy = xb[i * 3 + 1], qz = xb[i * 3 + 2];
    sx[k * CH + tid] = qx;
    sy[k * CH + tid] = qy;
    sz[k * CH + tid] = qz;
    sh[k * CH + tid] = 0.5f * (qx * qx + qy * qy + qz * qz);
  }
  __syncthreads();
  int row = blockIdx.x * 32 + (tid >> 3);
  int sub = tid & 7;
  float px = sx[(row >> 8) * CH + (row & 255)];
  float py = sy[(row >> 8) * CH + (row & 255)];
  float pz = sz[(row >> 8) * CH + (row & 255)];
  float nn[6];
#pragma unroll
  for (int j = 0; j < 6; j++) nn[j] = 3.4e38f;
  const float4* cx = (const float4*)(sx + sub * CH);
  const float4* cy = (const float4*)(sy + sub * CH);
  const float4* cz = (const float4*)(sz + sub * CH);
  const float4* chq = (const float4*)(sh + sub * CH);
  for (int j = 0; j < 64; j++) {
    float4 qx = cx[j], qy = cy[j], qz = cz[j], qh = chq[j];
    ins6(nn, fmaf(-px, qx.x, fmaf(-py, qy.x, fmaf(-pz, qz.x, qh.x))));
    ins6(nn, fmaf(-px, qx.y, fmaf(-py, qy.y, fmaf(-pz, qz.y, qh.y))));
    ins6(nn, fmaf(-px, qx.z, fmaf(-py, qy.z, fmaf(-pz, qz.z, qh.z))));
    ins6(nn, fmaf(-px, qx.w, fmaf(-py, qy.w, fmaf(-pz, qz.w, qh.w))));
  }
#pragma unroll
  for (int m = 1; m <= 4; m <<= 1) {
    float other[6];
#pragma unroll
    for (int k = 0; k < 6; k++) other[k] = __shfl_xor(nn[k], m);
#pragma unroll
    for (int k = 0; k < 6; k++) ins6(nn, other[k]);
  }
  if (sub == 0) {
    float p2 = px * px + py * py + pz * pz;
    float dm = 0.f;
#pragma unroll
    for (int i = 1; i < 6; i++) dm += sqrtf(fmaxf(fmaf(2.f, nn[i], p2), 0.f));
    dm *= 0.2f;
    float curv = 1.0f / (1e-8f + dm);
    size_t o = ((size_t)b * NPTS + row) * 4;
    feat[o + 0] = px;
    feat[o + 1] = py;
    feat[o + 2] = pz;
    feat[o + 3] = curv;
  }
}

// ---------------- layer1 fused: z1bf = feat @ W1^T + b1 (bf16), + BN1 stats partials ----------------
__global__ __launch_bounds__(256) void gemm1s_kernel(const float* __restrict__ feat,
                                                     const float* __restrict__ w,
                                                     const float* __restrict__ bias,
                                                     unsigned short* __restrict__ z1bf,
                                                     float* __restrict__ part) {
  __shared__ float wT[4 * 64];
  int tid = threadIdx.x;
  { int k = tid >> 6, c = tid & 63; wT[k * 64 + c] = w[c * 4 + k]; }
  __syncthreads();
  int col = tid & 63, rg = tid >> 6;
  int row0 = blockIdx.x * 256;
  float w0 = wT[col], w1 = wT[64 + col], w2v = wT[128 + col], w3 = wT[192 + col];
  float bb = bias[col];
  float s = 0.f, q = 0.f;
  for (int i = 0; i < 64; i++) {
    int row = row0 + i * 4 + rg;
    const float4 f = *(const float4*)(feat + (size_t)row * 4);
    float acc = bb + f.x * w0 + f.y * w1 + f.z * w2v + f.w * w3;
    s += acc;
    q += acc * acc;
    z1bf[(size_t)row * 64 + col] = f2bf(acc);
  }
  __shared__ float ls[256], lq[256];
  ls[tid] = s; lq[tid] = q;
  __syncthreads();
  if (tid < 64) {
    float ss = 0.f, qq = 0.f;
#pragma unroll
    for (int i = 0; i < 4; i++) { ss += ls[i * 64 + tid]; qq += lq[i * 64 + tid]; }
    part[((size_t)blockIdx.x * 64 + tid) * 2 + 0] = ss;
    part[((size_t)blockIdx.x * 64 + tid) * 2 + 1] = qq;
  }
}

// ---------------- generic BN finalize from P partials ----------------
template <int C, int P>
__global__ __launch_bounds__(256) void bnfinP_kernel(const float* __restrict__ part,
                                                     const float* __restrict__ g,
                                                     const float* __restrict__ be,
                                                     float* __restrict__ scale,
                                                     float* __restrict__ shift) {
  int c = blockIdx.x, tid = threadIdx.x;
  float s = 0.f, q = 0.f;
  for (int i = tid; i < P; i += 256) {
    s += part[((size_t)i * C + c) * 2 + 0];
    q += part[((size_t)i * C + c) * 2 + 1];
  }
  __shared__ float ls[256], lq[256];
  ls[tid] = s; lq[tid] = q;
  __syncthreads();
  for (int off = 128; off > 0; off >>= 1) {
    if (tid < off) { ls[tid] += ls[tid + off]; lq[tid] += lq[tid + off]; }
    __syncthreads();
  }
  if (tid == 0) {
    float m = ls[0] * (1.0f / 65536.0f);
    float v = lq[0] * (1.0f / 65536.0f) - m * m;
    float a = g[c] / sqrtf(v + EPS_BN);
    scale[c] = a;
    shift[c] = be[c] - m * a;
  }
}

// ---------------- layer2 fused: relu(bn1(z1bf)) @ W2^T + b2 -> z2bf (bf16) + BN2 stats ----------------
__global__ __launch_bounds__(256) void gemm2_kernel(const unsigned short* __restrict__ z1bf,
                                                    const float* __restrict__ s1,
                                                    const float* __restrict__ h1,
                                                    const float* __restrict__ w2,
                                                    const float* __restrict__ bias2,
                                                    unsigned short* __restrict__ z2bf,
                                                    float* __restrict__ part2) {
  __shared__ float As[64 * 36];   // [k][r]
  __shared__ float Bs[64 * 132];  // [k][c]
  __shared__ float scr[128 * 9];
  int tid = threadIdx.x;
  int row0 = blockIdx.x * 32;
  {
    int k = tid & 63, r0 = (tid >> 6) * 8;
    float sk = s1[k], hk = h1[k];
#pragma unroll
    for (int u = 0; u < 8; u++) {
      int r = r0 + u;
      float f = bf2f(z1bf[(size_t)(row0 + r) * 64 + k]);
      As[k * 36 + r] = fmaxf(f * sk + hk, 0.f);
    }
  }
#pragma unroll
  for (int i = 0; i < 32; i++) {
    int idx = tid + i * 256;
    int c = idx >> 6, k = idx & 63;
    Bs[k * 132 + c] = w2[(size_t)c * 64 + k];
  }
  __syncthreads();
  int tr = tid & 7, tc = tid >> 3;
  float acc[4][4] = {};
  for (int k = 0; k < 64; k++) {
    float4 a = *(const float4*)(As + k * 36 + tr * 4);
    float4 b = *(const float4*)(Bs + k * 132 + tc * 4);
    float av[4] = {a.x, a.y, a.z, a.w};
    float bv[4] = {b.x, b.y, b.z, b.w};
#pragma unroll
    for (int j = 0; j < 4; j++)
#pragma unroll
      for (int l = 0; l < 4; l++) acc[j][l] += av[j] * bv[l];
  }
  float bb[4];
#pragma unroll
  for (int l = 0; l < 4; l++) bb[l] = bias2[tc * 4 + l];
#pragma unroll
  for (int j = 0; j < 4; j++)
#pragma unroll
    for (int l = 0; l < 4; l++) acc[j][l] += bb[l];
#pragma unroll
  for (int j = 0; j < 4; j++) {
    int row = row0 + tr * 4 + j;
    u16x4 o;
#pragma unroll
    for (int l = 0; l < 4; l++) o[l] = f2bf(acc[j][l]);
    *(u16x4*)(z2bf + (size_t)row * 128 + tc * 4) = o;
  }
#pragma unroll
  for (int l = 0; l < 4; l++)
    scr[(tc * 4 + l) * 9 + tr] = acc[0][l] + acc[1][l] + acc[2][l] + acc[3][l];
  __syncthreads();
  if (tid < 128) {
    float s = 0.f;
#pragma unroll
    for (int i = 0; i < 8; i++) s += scr[tid * 9 + i];
    part2[((size_t)blockIdx.x * 128 + tid) * 2 + 0] = s;
  }
  __syncthreads();
#pragma unroll
  for (int l = 0; l < 4; l++)
    scr[(tc * 4 + l) * 9 + tr] = acc[0][l] * acc[0][l] + acc[1][l] * acc[1][l] +
                                 acc[2][l] * acc[2][l] + acc[3][l] * acc[3][l];
  __syncthreads();
  if (tid < 128) {
    float q = 0.f;
#pragma unroll
    for (int i = 0; i < 8; i++) q += scr[tid * 9 + i];
    part2[((size_t)blockIdx.x * 128 + tid) * 2 + 1] = q;
  }
}

// ---------------- bn2+relu -> bf16: abf = relu(bn2(z2bf)) ----------------
__global__ __launch_bounds__(256) void bnrelu_bf16_kernel(const unsigned short* __restrict__ z2bf,
                                                          const float* __restrict__ s2,
                                                          const float* __restrict__ h2,
                                                          unsigned short* __restrict__ abf) {
  __shared__ float ss[128], hh[128];
  int tid = threadIdx.x;
  if (tid < 128) { ss[tid] = s2[tid]; hh[tid] = h2[tid]; }
  __syncthreads();
  int g = blockIdx.x * 256 + tid;
  int c0 = (g & 15) * 8;
  s16x8 v = *(const s16x8*)(z2bf + (size_t)g * 8);
  s16x8 o;
#pragma unroll
  for (int j = 0; j < 8; j++) {
    float f = bf2f((unsigned short)v[j]);
    float val = fmaxf(f * ss[c0 + j] + hh[c0 + j], 0.f);
    o[j] = (short)f2bf(val);
  }
  *(s16x8*)(abf + (size_t)g * 8) = o;
}

// ---------------- w3 -> bf16 ----------------
__global__ __launch_bounds__(256) void wconv_kernel(const float* __restrict__ w,
                                                    unsigned short* __restrict__ wbf) {
  int g = blockIdx.x * 256 + threadIdx.x;
  const float4 v = ((const float4*)w)[g];
  unsigned short o0 = f2bf(v.x), o1 = f2bf(v.y), o2 = f2bf(v.z), o3 = f2bf(v.w);
  unsigned short* d = wbf + (size_t)g * 4;
  d[0] = o0; d[1] = o1; d[2] = o2; d[3] = o3;
}

// ---------------- layer3 MFMA, XCD-chunked grid ----------------
__global__ __launch_bounds__(256) void gemm3_mfma_kernel(const unsigned short* __restrict__ abf,
                                                         const unsigned short* __restrict__ wbf,
                                                         const float* __restrict__ bias3,
                                                         float* __restrict__ pS,
                                                         float* __restrict__ pQ,
                                                         float* __restrict__ pMx,
                                                         float* __restrict__ pMn) {
  __shared__ char lds[65536];
  int tid = threadIdx.x;
  int w = tid >> 6, lane = tid & 63;
  int bid = blockIdx.x;
  int xcd = bid & 7, j = bid >> 3;
  int rblk = xcd * 64 + (j & 63);
  int cblk = j >> 6;
  int row0 = rblk * 128, col0 = cblk * 128;

#pragma unroll
  for (int i = 0; i < 8; i++) {
    int ldsoff = w * 8192 + i * 1024;
    int lin = ldsoff + lane * 16;
    int row = lin >> 8;
    int gc = (lin >> 4) & 15;
    int gcl = gc ^ (row & 7);
    gload_lds16(abf + (size_t)(row0 + row) * 128 + gcl * 8, &lds[ldsoff]);
  }
#pragma unroll
  for (int i = 0; i < 8; i++) {
    int ldsoff = w * 8192 + i * 1024;
    int lin = ldsoff + lane * 16;
    int row = lin >> 8;
    int gc = (lin >> 4) & 15;
    int gcl = gc ^ (row & 7);
    gload_lds16(wbf + (size_t)(col0 + row) * 128 + gcl * 8, &lds[32768 + ldsoff]);
  }
  __syncthreads();

  int wm = w >> 1, wn = w & 1;
  int lrow = lane & 15, lg = lane >> 4;
  int sw = (lrow & 7) << 4;
  f32x4 acc[4][4] = {};
#pragma unroll
  for (int kstep = 0; kstep < 4; kstep++) {
    s16x8 a[4], b[4];
#pragma unroll
    for (int m = 0; m < 4; m++) {
      int row = wm * 64 + m * 16 + lrow;
      int byte = (row * 256 + kstep * 64 + lg * 16) ^ sw;
      a[m] = *(const s16x8*)(lds + byte);
    }
#pragma unroll
    for (int n = 0; n < 4; n++) {
      int col = wn * 64 + n * 16 + lrow;
      int byte = 32768 + ((col * 256 + kstep * 64 + lg * 16) ^ sw);
      b[n] = *(const s16x8*)(lds + byte);
    }
#pragma unroll
    for (int m = 0; m < 4; m++)
#pragma unroll
      for (int n = 0; n < 4; n++)
        acc[m][n] = __builtin_amdgcn_mfma_f32_16x16x32_bf16(a[m], b[n], acc[m][n], 0, 0, 0);
  }
  __syncthreads();

  float* sS = (float*)lds;
  float* sQ = sS + 256;
  float* sMx = sQ + 256;
  float* sMn = sMx + 256;
#pragma unroll
  for (int n = 0; n < 4; n++) {
    float bb = bias3[col0 + wn * 64 + n * 16 + lrow];
    float s = 0.f, q = 0.f, mx = -3.4e38f, mn = 3.4e38f;
#pragma unroll
    for (int m = 0; m < 4; m++)
#pragma unroll
      for (int r = 0; r < 4; r++) {
        float v = acc[m][n][r] + bb;
        s += v;
        q += v * v;
        mx = fmaxf(mx, v);
        mn = fminf(mn, v);
      }
    s += __shfl_xor(s, 16); s += __shfl_xor(s, 32);
    q += __shfl_xor(q, 16); q += __shfl_xor(q, 32);
    mx = fmaxf(mx, __shfl_xor(mx, 16)); mx = fmaxf(mx, __shfl_xor(mx, 32));
    mn = fminf(mn, __shfl_xor(mn, 16)); mn = fminf(mn, __shfl_xor(mn, 32));
    if (lane < 16) {
      int cidx = wn * 64 + n * 16 + lane;
      sS[wm * 128 + cidx] = s;
      sQ[wm * 128 + cidx] = q;
      sMx[wm * 128 + cidx] = mx;
      sMn[wm * 128 + cidx] = mn;
    }
  }
  __syncthreads();
  if (tid < 128) {
    size_t o = (size_t)rblk * 1024 + col0 + tid;
    pS[o] = sS[tid] + sS[128 + tid];
    pQ[o] = sQ[tid] + sQ[128 + tid];
    pMx[o] = fmaxf(sMx[tid], sMx[128 + tid]);
    pMn[o] = fminf(sMn[tid], sMn[128 + tid]);
  }
}

// ---------------- bn3 finalize + masked max-pool ----------------
__global__ __launch_bounds__(256) void bn3fin_pool_kernel(const float* __restrict__ pS,
                                                          const float* __restrict__ pQ,
                                                          const float* __restrict__ pMx,
                                                          const float* __restrict__ pMn,
                                                          const float* __restrict__ g,
                                                          const float* __restrict__ be,
                                                          float* __restrict__ pooled) {
  int tid = threadIdx.x;
  int chl = tid & 15, grp = tid >> 4;
  int c = blockIdx.x * 16 + chl;
  float s = 0.f, q = 0.f;
  for (int i = grp; i < 512; i += 16) {
    s += pS[(size_t)i * 1024 + c];
    q += pQ[(size_t)i * 1024 + c];
  }
  __shared__ float ls[256], lq[256], sa[16], sc[16];
  ls[chl * 16 + grp] = s;
  lq[chl * 16 + grp] = q;
  __syncthreads();
  if (tid < 16) {
    float ss = 0.f, qq = 0.f;
#pragma unroll
    for (int i = 0; i < 16; i++) { ss += ls[tid * 16 + i]; qq += lq[tid * 16 + i]; }
    float m = ss * (1.0f / 65536.0f);
    float v = qq * (1.0f / 65536.0f) - m * m;
    float a = g[blockIdx.x * 16 + tid] / sqrtf(v + EPS_BN);
    sa[tid] = a;
    sc[tid] = be[blockIdx.x * 16 + tid] - m * a;
  }
  __syncthreads();
  for (int idx = tid; idx < 512; idx += 256) {
    int b = idx >> 4, l = idx & 15;
    int cc = blockIdx.x * 16 + l;
    float mx = -3.4e38f, mn = 3.4e38f;
    for (int i = 0; i < 16; i++) {
      mx = fmaxf(mx, pMx[(size_t)(b * 16 + i) * 1024 + cc]);
      mn = fminf(mn, pMn[(size_t)(b * 16 + i) * 1024 + cc]);
    }
    float a = sa[l];
    float v = (a > 0.f) ? (a * mx + sc[l]) : (a * mn + sc[l]);
    pooled[(size_t)b * 1024 + cc] = fmaxf(v, 0.f);
  }
}

// ---------------- fc1: wave-per-output  pooled[32,1024] @ [1024,512]^T + b ----------------
__global__ __launch_bounds__(256) void fc1_kernel(const float* __restrict__ pooled,
                                                  const float* __restrict__ w,
                                                  const float* __restrict__ bias,
                                                  float* __restrict__ zf1) {
  int gw = blockIdx.x * 4 + (threadIdx.x >> 6);  // 16384 waves
  int lane = threadIdx.x & 63;
  int b = gw >> 9, o = gw & 511;
  const float4* pr = (const float4*)(pooled + (size_t)b * 1024);
  const float4* wr = (const float4*)(w + (size_t)o * 1024);
  float acc = 0.f;
#pragma unroll
  for (int i = 0; i < 4; i++) {
    int k = lane + i * 64;
    float4 p = pr[k], q = wr[k];
    acc += p.x * q.x + p.y * q.y + p.z * q.z + p.w * q.w;
  }
  acc = wave_reduce_add(acc);
  if (lane == 0) zf1[gw] = acc + bias[o];
}

__global__ __launch_bounds__(256) void statsF_kernel(const float* __restrict__ z,
                                                     const float* __restrict__ g,
                                                     const float* __restrict__ be, int C,
                                                     float* __restrict__ scale,
                                                     float* __restrict__ shift) {
  int c = blockIdx.x * 256 + threadIdx.x;
  if (c >= C) return;
  float s = 0.f, q = 0.f;
  for (int b = 0; b < 32; b++) {
    float v = z[(size_t)b * C + c];
    s += v;
    q += v * v;
  }
  float m = s * (1.0f / 32.0f);
  float v = q * (1.0f / 32.0f) - m * m;
  float a = g[c] / sqrtf(v + EPS_BN);
  scale[c] = a;
  shift[c] = be[c] - m * a;
}

// ---------------- fc2: wave-per-output  relu(bn(zf1))[32,512] @ [512,256]^T + b ----------------
__global__ __launch_bounds__(256) void fc2_kernel(const float* __restrict__ zf1,
                                                  const float* __restrict__ sf1,
                                                  const float* __restrict__ hf1,
                                                  const float* __restrict__ w,
                                                  const float* __restrict__ bias,
                                                  float* __restrict__ zf2) {
  int gw = blockIdx.x * 4 + (threadIdx.x >> 6);  // 8192 waves
  int lane = threadIdx.x & 63;
  int b = gw >> 8, o = gw & 255;
  const float4* zr = (const float4*)(zf1 + (size_t)b * 512);
  const float4* sr = (const float4*)sf1;
  const float4* hr = (const float4*)hf1;
  const float4* wr = (const float4*)(w + (size_t)o * 512);
  float acc = 0.f;
#pragma unroll
  for (int i = 0; i < 2; i++) {
    int k = lane + i * 64;
    float4 z = zr[k], s = sr[k], h = hr[k], q = wr[k];
    float v0 = fmaxf(z.x * s.x + h.x, 0.f);
    float v1 = fmaxf(z.y * s.y + h.y, 0.f);
    float v2 = fmaxf(z.z * s.z + h.z, 0.f);
    float v3 = fmaxf(z.w * s.w + h.w, 0.f);
    acc += v0 * q.x + v1 * q.y + v2 * q.z + v3 * q.w;
  }
  acc = wave_reduce_add(acc);
  if (lane == 0) zf2[gw] = acc + bias[o];
}

// ---------------- head: block per batch row; 4 waves x 10 lane-parallel dots ----------------
__global__ __launch_bounds__(256) void head_kernel(const float* __restrict__ zf2,
                                                   const float* __restrict__ sf2,
                                                   const float* __restrict__ hf2,
                                                   const float* __restrict__ w,
                                                   const float* __restrict__ bias,
                                                   float* __restrict__ out) {
  int b = blockIdx.x, tid = threadIdx.x;
  int wv = tid >> 6, lane = tid & 63;
  __shared__ float lg[40];
  __shared__ float red[2];
  float4 z = ((const float4*)(zf2 + (size_t)b * 256))[lane];
  float4 s = ((const float4*)sf2)[lane];
  float4 h = ((const float4*)hf2)[lane];
  float v0 = fmaxf(z.x * s.x + h.x, 0.f);
  float v1 = fmaxf(z.y * s.y + h.y, 0.f);
  float v2 = fmaxf(z.z * s.z + h.z, 0.f);
  float v3 = fmaxf(z.w * s.w + h.w, 0.f);
  for (int r = 0; r < 10; r++) {
    int o = wv * 10 + r;
    float4 q = ((const float4*)(w + (size_t)o * 256))[lane];
    float a = v0 * q.x + v1 * q.y + v2 * q.z + v3 * q.w;
    a = wave_reduce_add(a);
    if (lane == 0) lg[o] = a + bias[o];
  }
  __syncthreads();
  if (tid == 0) {
    float mx = -3.4e38f;
    for (int i = 0; i < 40; i++) mx = fmaxf(mx, lg[i]);
    float sum = 0.f;
    for (int i = 0; i < 40; i++) sum += expf(lg[i] - mx);
    red[0] = mx;
    red[1] = logf(sum);
  }
  __syncthreads();
  if (tid < 40) out[(size_t)b * 40 + tid] = lg[tid] - red[0] - red[1];
}

extern "C" void kernel_launch(void* const* d_in, const int* in_sizes, int n_in,
                              void* d_out, int out_size, void* d_ws, size_t ws_size,
                              hipStream_t stream) {
  const float* x    = (const float*)d_in[0];
  const float* c1w  = (const float*)d_in[1];
  const float* c1b  = (const float*)d_in[2];
  const float* g1   = (const float*)d_in[3];
  const float* be1  = (const float*)d_in[4];
  const float* c2w  = (const float*)d_in[5];
  const float* c2b  = (const float*)d_in[6];
  const float* g2   = (const float*)d_in[7];
  const float* be2  = (const float*)d_in[8];
  const float* c3w  = (const float*)d_in[9];
  const float* c3b  = (const float*)d_in[10];
  const float* g3   = (const float*)d_in[11];
  const float* be3  = (const float*)d_in[12];
  const float* f1w  = (const float*)d_in[13];
  const float* f1b  = (const float*)d_in[14];
  const float* gf1  = (const float*)d_in[15];
  const float* bef1 = (const float*)d_in[16];
  const float* f2w  = (const float*)d_in[17];
  const float* f2b  = (const float*)d_in[18];
  const float* gf2  = (const float*)d_in[19];
  const float* bef2 = (const float*)d_in[20];
  const float* ow   = (const float*)d_in[21];
  const float* ob   = (const float*)d_in[22];
  float* out = (float*)d_out;

  float* W = (float*)d_ws;
  float* feat   = W;                   // 262144
  float* pS     = feat + 262144;       // 524288
  float* pQ     = pS + 524288;
  float* pMx    = pQ + 524288;
  float* pMn    = pMx + 524288;
  float* part   = pMn + 524288;        // 32768
  float* part2  = part + 32768;        // 524288
  float* pooled = part2 + 524288;      // 32768
  float* zf1    = pooled + 32768;      // 16384
  float* zf2    = zf1 + 16384;         // 8192
  float* s1     = zf2 + 8192;          // 64
  float* h1     = s1 + 64;
  float* s2     = h1 + 64;             // 128
  float* h2     = s2 + 128;
  float* sf1    = h2 + 128;            // 512
  float* hf1    = sf1 + 512;
  float* sf2    = hf1 + 512;           // 256
  float* hf2    = sf2 + 256;
  unsigned short* wbf  = (unsigned short*)(hf2 + 256);   // 131072 shorts
  unsigned short* z1bf = wbf + 131072;                   // 65536*64
  unsigned short* z2bf = z1bf + (size_t)BP * 64;         // 65536*128
  unsigned short* abf  = z2bf + (size_t)BP * 128;        // 65536*128

  wconv_kernel<<<128, 256, 0, stream>>>(c3w, wbf);
  curv_kernel<<<dim3(64, 32), 256, 0, stream>>>(x, feat);
  gemm1s_kernel<<<256, 256, 0, stream>>>(feat, c1w, c1b, z1bf, part);
  bnfinP_kernel<64, 256><<<64, 256, 0, stream>>>(part, g1, be1, s1, h1);
  gemm2_kernel<<<2048, 256, 0, stream>>>(z1bf, s1, h1, c2w, c2b, z2bf, part2);
  bnfinP_kernel<128, 2048><<<128, 256, 0, stream>>>(part2, g2, be2, s2, h2);
  bnrelu_bf16_kernel<<<4096, 256, 0, stream>>>(z2bf, s2, h2, abf);
  gemm3_mfma_kernel<<<4096, 256, 0, stream>>>(abf, wbf, c3b, pS, pQ, pMx, pMn);
  bn3fin_pool_kernel<<<64, 256, 0, stream>>>(pS, pQ, pMx, pMn, g3, be3, pooled);
  fc1_kernel<<<4096, 256, 0, stream>>>(pooled, f1w, f1b, zf1);
  statsF_kernel<<<2, 256, 0, stream>>>(zf1, gf1, bef1, 512, sf1, hf1);
  fc2_kernel<<<2048, 256, 0, stream>>>(zf1, sf1, hf1, f2w, f2b, zf2);
  statsF_kernel<<<1, 256, 0, stream>>>(zf2, gf2, bef2, 256, sf2, hf2);
  head_kernel<<<32, 256, 0, stream>>>(zf2, sf2, hf2, ow, ob, out);
}

// Round 9
// 145.018 us; speedup vs baseline: 5.4491x; 1.1147x over previous
//
#include <hip/hip_runtime.h>
#include <hip/hip_bf16.h>
#include <math.h>

#define EPS_BN 1e-5f

constexpr int BATCH = 32;
constexpr int NPTS  = 2048;
constexpr int BP    = BATCH * NPTS;   // 65536

using s16x8 = __attribute__((ext_vector_type(8))) short;
using u32x4 = __attribute__((ext_vector_type(4))) unsigned;
using f32x4 = __attribute__((ext_vector_type(4))) float;

static __device__ __forceinline__ unsigned short f2bf(float f) {
  union { float f; unsigned u; } x{f};
  unsigned r = x.u + 0x7fffu + ((x.u >> 16) & 1u);  // RNE
  return (unsigned short)(r >> 16);
}
static __device__ __forceinline__ float bf2f(unsigned short s) {
  union { unsigned u; float f; } x;
  x.u = ((unsigned)s) << 16;
  return x.f;
}
static __device__ __forceinline__ unsigned pk2bf(float lo, float hi) {
  __hip_bfloat162 t = __float22bfloat162_rn(float2{lo, hi});
  unsigned r;
  __builtin_memcpy(&r, &t, 4);
  return r;
}

static __device__ __forceinline__ void gload_lds16(const void* g, void* l) {
  __builtin_amdgcn_global_load_lds((const __attribute__((address_space(1))) void*)g,
                                   (__attribute__((address_space(3))) void*)l, 16, 0, 0);
}

static __device__ __forceinline__ float wave_reduce_add(float v) {
#pragma unroll
  for (int off = 32; off > 0; off >>= 1) v += __shfl_xor(v, off);
  return v;
}

// keep-6-smallest, ASCENDING list, depth-1 branchless insert (1 min + 5 med3).
static __device__ __forceinline__ void ins6(float (&nn)[6], float c) {
  float b0 = fminf(nn[0], c);
  float b1 = __builtin_amdgcn_fmed3f(c, nn[1], nn[0]);
  float b2 = __builtin_amdgcn_fmed3f(c, nn[2], nn[1]);
  float b3 = __builtin_amdgcn_fmed3f(c, nn[3], nn[2]);
  float b4 = __builtin_amdgcn_fmed3f(c, nn[4], nn[3]);
  float b5 = __builtin_amdgcn_fmed3f(c, nn[5], nn[4]);
  nn[0] = b0; nn[1] = b1; nn[2] = b2; nn[3] = b3; nn[4] = b4; nn[5] = b5;
}

// ---------------- curvature: rank by r = 0.5|q|^2 - p.q  (d2 = |p|^2 + 2r) ----------------
constexpr int CH = 260;
__global__ __launch_bounds__(256) void curv_kernel(const float* __restrict__ x,
                                                   float* __restrict__ feat) {
  __shared__ float sx[8 * CH], sy[8 * CH], sz[8 * CH], sh[8 * CH];
  int b = blockIdx.y;
  const float* xb = x + (size_t)b * NPTS * 3;
  int tid = threadIdx.x;
#pragma unroll
  for (int k = 0; k < 8; k++) {
    int i = k * 256 + tid;
    float qx = xb[i * 3 + 0], qy = xb[i * 3 + 1], qz = xb[i * 3 + 2];
    sx[k * CH + tid] = qx;
    sy[k * CH + tid] = qy;
    sz[k * CH + tid] = qz;
    sh[k * CH + tid] = 0.5f * (qx * qx + qy * qy + qz * qz);
  }
  __syncthreads();
  int row = blockIdx.x * 32 + (tid >> 3);
  int sub = tid & 7;
  float px = sx[(row >> 8) * CH + (row & 255)];
  float py = sy[(row >> 8) * CH + (row & 255)];
  float pz = sz[(row >> 8) * CH + (row & 255)];
  float nn[6];
#pragma unroll
  for (int j = 0; j < 6; j++) nn[j] = 3.4e38f;
  const float4* cx = (const float4*)(sx + sub * CH);
  const float4* cy = (const float4*)(sy + sub * CH);
  const float4* cz = (const float4*)(sz + sub * CH);
  const float4* chq = (const float4*)(sh + sub * CH);
  for (int j = 0; j < 64; j++) {
    float4 qx = cx[j], qy = cy[j], qz = cz[j], qh = chq[j];
    ins6(nn, fmaf(-px, qx.x, fmaf(-py, qy.x, fmaf(-pz, qz.x, qh.x))));
    ins6(nn, fmaf(-px, qx.y, fmaf(-py, qy.y, fmaf(-pz, qz.y, qh.y))));
    ins6(nn, fmaf(-px, qx.z, fmaf(-py, qy.z, fmaf(-pz, qz.z, qh.z))));
    ins6(nn, fmaf(-px, qx.w, fmaf(-py, qy.w, fmaf(-pz, qz.w, qh.w))));
  }
#pragma unroll
  for (int m = 1; m <= 4; m <<= 1) {
    float other[6];
#pragma unroll
    for (int k = 0; k < 6; k++) other[k] = __shfl_xor(nn[k], m);
#pragma unroll
    for (int k = 0; k < 6; k++) ins6(nn, other[k]);
  }
  if (sub == 0) {
    float p2 = px * px + py * py + pz * pz;
    float dm = 0.f;
#pragma unroll
    for (int i = 1; i < 6; i++) dm += sqrtf(fmaxf(fmaf(2.f, nn[i], p2), 0.f));
    dm *= 0.2f;
    float curv = 1.0f / (1e-8f + dm);
    size_t o = ((size_t)b * NPTS + row) * 4;
    feat[o + 0] = px;
    feat[o + 1] = py;
    feat[o + 2] = pz;
    feat[o + 3] = curv;
  }
}

// ---------------- layer1 fused: z1bf = feat @ W1^T + b1 (bf16), + BN1 stats partials ----------------
__global__ __launch_bounds__(256) void gemm1s_kernel(const float* __restrict__ feat,
                                                     const float* __restrict__ w,
                                                     const float* __restrict__ bias,
                                                     unsigned short* __restrict__ z1bf,
                                                     float* __restrict__ part) {
  __shared__ float wT[4 * 64];
  int tid = threadIdx.x;
  { int k = tid >> 6, c = tid & 63; wT[k * 64 + c] = w[c * 4 + k]; }
  __syncthreads();
  int col = tid & 63, rg = tid >> 6;
  int row0 = blockIdx.x * 256;
  float w0 = wT[col], w1 = wT[64 + col], w2v = wT[128 + col], w3 = wT[192 + col];
  float bb = bias[col];
  float s = 0.f, q = 0.f;
  for (int i = 0; i < 64; i++) {
    int row = row0 + i * 4 + rg;
    const float4 f = *(const float4*)(feat + (size_t)row * 4);
    float acc = bb + f.x * w0 + f.y * w1 + f.z * w2v + f.w * w3;
    s += acc;
    q += acc * acc;
    z1bf[(size_t)row * 64 + col] = f2bf(acc);
  }
  __shared__ float ls[256], lq[256];
  ls[tid] = s; lq[tid] = q;
  __syncthreads();
  if (tid < 64) {
    float ss = 0.f, qq = 0.f;
#pragma unroll
    for (int i = 0; i < 4; i++) { ss += ls[i * 64 + tid]; qq += lq[i * 64 + tid]; }
    part[((size_t)blockIdx.x * 64 + tid) * 2 + 0] = ss;
    part[((size_t)blockIdx.x * 64 + tid) * 2 + 1] = qq;
  }
}

// ---------------- generic BN finalize from P partials ----------------
template <int C, int P>
__global__ __launch_bounds__(256) void bnfinP_kernel(const float* __restrict__ part,
                                                     const float* __restrict__ g,
                                                     const float* __restrict__ be,
                                                     float* __restrict__ scale,
                                                     float* __restrict__ shift) {
  int c = blockIdx.x, tid = threadIdx.x;
  float s = 0.f, q = 0.f;
  for (int i = tid; i < P; i += 256) {
    s += part[((size_t)i * C + c) * 2 + 0];
    q += part[((size_t)i * C + c) * 2 + 1];
  }
  __shared__ float ls[256], lq[256];
  ls[tid] = s; lq[tid] = q;
  __syncthreads();
  for (int off = 128; off > 0; off >>= 1) {
    if (tid < off) { ls[tid] += ls[tid + off]; lq[tid] += lq[tid + off]; }
    __syncthreads();
  }
  if (tid == 0) {
    float m = ls[0] * (1.0f / 65536.0f);
    float v = lq[0] * (1.0f / 65536.0f) - m * m;
    float a = g[c] / sqrtf(v + EPS_BN);
    scale[c] = a;
    shift[c] = be[c] - m * a;
  }
}

// ---------------- layer2 MFMA: relu(bn1(z1bf)) @ W2^T + b2 -> z2bf + BN2 stats ----------------
// A: [128 rows][64 k] bf16 (transform in staging), B: w2 [128 c][64 k] -> bf16 in staging.
__global__ __launch_bounds__(256) void gemm2_mfma_kernel(const unsigned short* __restrict__ z1bf,
                                                         const float* __restrict__ s1,
                                                         const float* __restrict__ h1,
                                                         const float* __restrict__ w2,
                                                         const float* __restrict__ bias2,
                                                         unsigned short* __restrict__ z2bf,
                                                         float* __restrict__ part2) {
  __shared__ char lds[33280];  // A @0 (16KB), B @16384 (16KB), s1h1 @32768 (512B)
  float* ls1 = (float*)(lds + 32768);
  float* lh1 = ls1 + 64;
  int tid = threadIdx.x;
  int row0 = blockIdx.x * 128;
  if (tid < 64) { ls1[tid] = s1[tid]; lh1[tid] = h1[tid]; }

  // issue global loads
  s16x8 araw[4];
  float4 b0[4], b1[4];
#pragma unroll
  for (int i = 0; i < 4; i++) {
    int L = tid + 256 * i;  // 16B chunk id, 0..1023
    araw[i] = *(const s16x8*)(z1bf + (size_t)row0 * 64 + (size_t)L * 8);
    int crow = L >> 3, k0 = (L & 7) * 8;
    b0[i] = *(const float4*)(w2 + (size_t)crow * 64 + k0);
    b1[i] = *(const float4*)(w2 + (size_t)crow * 64 + k0 + 4);
  }
  __syncthreads();  // ls1/lh1 ready

  // transform + swizzled LDS writes
#pragma unroll
  for (int i = 0; i < 4; i++) {
    int L = tid + 256 * i;
    int row = L >> 3, grp = L & 7, k0 = grp * 8;
    float4 sA = *(const float4*)(ls1 + k0);
    float4 sB = *(const float4*)(ls1 + k0 + 4);
    float4 hA = *(const float4*)(lh1 + k0);
    float4 hB = *(const float4*)(lh1 + k0 + 4);
    float v0 = fmaxf(bf2f((unsigned short)araw[i][0]) * sA.x + hA.x, 0.f);
    float v1 = fmaxf(bf2f((unsigned short)araw[i][1]) * sA.y + hA.y, 0.f);
    float v2 = fmaxf(bf2f((unsigned short)araw[i][2]) * sA.z + hA.z, 0.f);
    float v3 = fmaxf(bf2f((unsigned short)araw[i][3]) * sA.w + hA.w, 0.f);
    float v4 = fmaxf(bf2f((unsigned short)araw[i][4]) * sB.x + hB.x, 0.f);
    float v5 = fmaxf(bf2f((unsigned short)araw[i][5]) * sB.y + hB.y, 0.f);
    float v6 = fmaxf(bf2f((unsigned short)araw[i][6]) * sB.z + hB.z, 0.f);
    float v7 = fmaxf(bf2f((unsigned short)araw[i][7]) * sB.w + hB.w, 0.f);
    u32x4 pa = {pk2bf(v0, v1), pk2bf(v2, v3), pk2bf(v4, v5), pk2bf(v6, v7)};
    *(u32x4*)(lds + row * 128 + ((grp ^ (row & 7)) << 4)) = pa;
    u32x4 pb = {pk2bf(b0[i].x, b0[i].y), pk2bf(b0[i].z, b0[i].w),
                pk2bf(b1[i].x, b1[i].y), pk2bf(b1[i].z, b1[i].w)};
    *(u32x4*)(lds + 16384 + row * 128 + ((grp ^ (row & 7)) << 4)) = pb;
  }
  __syncthreads();

  int w = tid >> 6, lane = tid & 63;
  int wm = w >> 1, wn = w & 1;
  int lrow = lane & 15, lg = lane >> 4;
  int sw = (lrow & 7) << 4;
  f32x4 acc[4][4] = {};
#pragma unroll
  for (int kstep = 0; kstep < 2; kstep++) {
    s16x8 a[4], bfr[4];
#pragma unroll
    for (int m = 0; m < 4; m++) {
      int row = wm * 64 + m * 16 + lrow;
      int byte = row * 128 + ((kstep * 64 + lg * 16) ^ sw);
      a[m] = *(const s16x8*)(lds + byte);
    }
#pragma unroll
    for (int n = 0; n < 4; n++) {
      int col = wn * 64 + n * 16 + lrow;
      int byte = 16384 + col * 128 + ((kstep * 64 + lg * 16) ^ sw);
      bfr[n] = *(const s16x8*)(lds + byte);
    }
#pragma unroll
    for (int m = 0; m < 4; m++)
#pragma unroll
      for (int n = 0; n < 4; n++)
        acc[m][n] = __builtin_amdgcn_mfma_f32_16x16x32_bf16(a[m], bfr[n], acc[m][n], 0, 0, 0);
  }
  __syncthreads();  // LDS free for stats

  float* sS = (float*)lds;   // [2][128]
  float* sQ = sS + 256;
#pragma unroll
  for (int n = 0; n < 4; n++) {
    int col = wn * 64 + n * 16 + lrow;
    float bb = bias2[col];
    float s = 0.f, q = 0.f;
#pragma unroll
    for (int m = 0; m < 4; m++) {
#pragma unroll
      for (int r = 0; r < 4; r++) {
        float v = acc[m][n][r] + bb;
        s += v;
        q += v * v;
        int row = row0 + wm * 64 + m * 16 + lg * 4 + r;
        z2bf[(size_t)row * 128 + col] = f2bf(v);
      }
    }
    s += __shfl_xor(s, 16); s += __shfl_xor(s, 32);
    q += __shfl_xor(q, 16); q += __shfl_xor(q, 32);
    if (lane < 16) {
      int cidx = wn * 64 + n * 16 + lane;
      sS[wm * 128 + cidx] = s;
      sQ[wm * 128 + cidx] = q;
    }
  }
  __syncthreads();
  if (tid < 128) {
    part2[((size_t)blockIdx.x * 128 + tid) * 2 + 0] = sS[tid] + sS[128 + tid];
    part2[((size_t)blockIdx.x * 128 + tid) * 2 + 1] = sQ[tid] + sQ[128 + tid];
  }
}

// ---------------- bn2+relu -> bf16: abf = relu(bn2(z2bf)) ----------------
__global__ __launch_bounds__(256) void bnrelu_bf16_kernel(const unsigned short* __restrict__ z2bf,
                                                          const float* __restrict__ s2,
                                                          const float* __restrict__ h2,
                                                          unsigned short* __restrict__ abf) {
  __shared__ float ss[128], hh[128];
  int tid = threadIdx.x;
  if (tid < 128) { ss[tid] = s2[tid]; hh[tid] = h2[tid]; }
  __syncthreads();
  int g = blockIdx.x * 256 + tid;
  int c0 = (g & 15) * 8;
  s16x8 v = *(const s16x8*)(z2bf + (size_t)g * 8);
  s16x8 o;
#pragma unroll
  for (int j = 0; j < 8; j++) {
    float f = bf2f((unsigned short)v[j]);
    float val = fmaxf(f * ss[c0 + j] + hh[c0 + j], 0.f);
    o[j] = (short)f2bf(val);
  }
  *(s16x8*)(abf + (size_t)g * 8) = o;
}

// ---------------- w3 -> bf16 ----------------
__global__ __launch_bounds__(256) void wconv_kernel(const float* __restrict__ w,
                                                    unsigned short* __restrict__ wbf) {
  int g = blockIdx.x * 256 + threadIdx.x;
  const float4 v = ((const float4*)w)[g];
  unsigned short o0 = f2bf(v.x), o1 = f2bf(v.y), o2 = f2bf(v.z), o3 = f2bf(v.w);
  unsigned short* d = wbf + (size_t)g * 4;
  d[0] = o0; d[1] = o1; d[2] = o2; d[3] = o3;
}

// ---------------- layer3 MFMA, XCD-chunked grid ----------------
__global__ __launch_bounds__(256) void gemm3_mfma_kernel(const unsigned short* __restrict__ abf,
                                                         const unsigned short* __restrict__ wbf,
                                                         const float* __restrict__ bias3,
                                                         float* __restrict__ pS,
                                                         float* __restrict__ pQ,
                                                         float* __restrict__ pMx,
                                                         float* __restrict__ pMn) {
  __shared__ char lds[65536];
  int tid = threadIdx.x;
  int w = tid >> 6, lane = tid & 63;
  int bid = blockIdx.x;
  int xcd = bid & 7, j = bid >> 3;
  int rblk = xcd * 64 + (j & 63);
  int cblk = j >> 6;
  int row0 = rblk * 128, col0 = cblk * 128;

#pragma unroll
  for (int i = 0; i < 8; i++) {
    int ldsoff = w * 8192 + i * 1024;
    int lin = ldsoff + lane * 16;
    int row = lin >> 8;
    int gc = (lin >> 4) & 15;
    int gcl = gc ^ (row & 7);
    gload_lds16(abf + (size_t)(row0 + row) * 128 + gcl * 8, &lds[ldsoff]);
  }
#pragma unroll
  for (int i = 0; i < 8; i++) {
    int ldsoff = w * 8192 + i * 1024;
    int lin = ldsoff + lane * 16;
    int row = lin >> 8;
    int gc = (lin >> 4) & 15;
    int gcl = gc ^ (row & 7);
    gload_lds16(wbf + (size_t)(col0 + row) * 128 + gcl * 8, &lds[32768 + ldsoff]);
  }
  __syncthreads();

  int wm = w >> 1, wn = w & 1;
  int lrow = lane & 15, lg = lane >> 4;
  int sw = (lrow & 7) << 4;
  f32x4 acc[4][4] = {};
#pragma unroll
  for (int kstep = 0; kstep < 4; kstep++) {
    s16x8 a[4], b[4];
#pragma unroll
    for (int m = 0; m < 4; m++) {
      int row = wm * 64 + m * 16 + lrow;
      int byte = (row * 256 + kstep * 64 + lg * 16) ^ sw;
      a[m] = *(const s16x8*)(lds + byte);
    }
#pragma unroll
    for (int n = 0; n < 4; n++) {
      int col = wn * 64 + n * 16 + lrow;
      int byte = 32768 + ((col * 256 + kstep * 64 + lg * 16) ^ sw);
      b[n] = *(const s16x8*)(lds + byte);
    }
#pragma unroll
    for (int m = 0; m < 4; m++)
#pragma unroll
      for (int n = 0; n < 4; n++)
        acc[m][n] = __builtin_amdgcn_mfma_f32_16x16x32_bf16(a[m], b[n], acc[m][n], 0, 0, 0);
  }
  __syncthreads();

  float* sS = (float*)lds;
  float* sQ = sS + 256;
  float* sMx = sQ + 256;
  float* sMn = sMx + 256;
#pragma unroll
  for (int n = 0; n < 4; n++) {
    float bb = bias3[col0 + wn * 64 + n * 16 + lrow];
    float s = 0.f, q = 0.f, mx = -3.4e38f, mn = 3.4e38f;
#pragma unroll
    for (int m = 0; m < 4; m++)
#pragma unroll
      for (int r = 0; r < 4; r++) {
        float v = acc[m][n][r] + bb;
        s += v;
        q += v * v;
        mx = fmaxf(mx, v);
        mn = fminf(mn, v);
      }
    s += __shfl_xor(s, 16); s += __shfl_xor(s, 32);
    q += __shfl_xor(q, 16); q += __shfl_xor(q, 32);
    mx = fmaxf(mx, __shfl_xor(mx, 16)); mx = fmaxf(mx, __shfl_xor(mx, 32));
    mn = fminf(mn, __shfl_xor(mn, 16)); mn = fminf(mn, __shfl_xor(mn, 32));
    if (lane < 16) {
      int cidx = wn * 64 + n * 16 + lane;
      sS[wm * 128 + cidx] = s;
      sQ[wm * 128 + cidx] = q;
      sMx[wm * 128 + cidx] = mx;
      sMn[wm * 128 + cidx] = mn;
    }
  }
  __syncthreads();
  if (tid < 128) {
    size_t o = (size_t)rblk * 1024 + col0 + tid;
    pS[o] = sS[tid] + sS[128 + tid];
    pQ[o] = sQ[tid] + sQ[128 + tid];
    pMx[o] = fmaxf(sMx[tid], sMx[128 + tid]);
    pMn[o] = fminf(sMn[tid], sMn[128 + tid]);
  }
}

// ---------------- bn3 finalize + masked max-pool ----------------
__global__ __launch_bounds__(256) void bn3fin_pool_kernel(const float* __restrict__ pS,
                                                          const float* __restrict__ pQ,
                                                          const float* __restrict__ pMx,
                                                          const float* __restrict__ pMn,
                                                          const float* __restrict__ g,
                                                          const float* __restrict__ be,
                                                          float* __restrict__ pooled) {
  int tid = threadIdx.x;
  int chl = tid & 15, grp = tid >> 4;
  int c = blockIdx.x * 16 + chl;
  float s = 0.f, q = 0.f;
  for (int i = grp; i < 512; i += 16) {
    s += pS[(size_t)i * 1024 + c];
    q += pQ[(size_t)i * 1024 + c];
  }
  __shared__ float ls[256], lq[256], sa[16], sc[16];
  ls[chl * 16 + grp] = s;
  lq[chl * 16 + grp] = q;
  __syncthreads();
  if (tid < 16) {
    float ss = 0.f, qq = 0.f;
#pragma unroll
    for (int i = 0; i < 16; i++) { ss += ls[tid * 16 + i]; qq += lq[tid * 16 + i]; }
    float m = ss * (1.0f / 65536.0f);
    float v = qq * (1.0f / 65536.0f) - m * m;
    float a = g[blockIdx.x * 16 + tid] / sqrtf(v + EPS_BN);
    sa[tid] = a;
    sc[tid] = be[blockIdx.x * 16 + tid] - m * a;
  }
  __syncthreads();
  for (int idx = tid; idx < 512; idx += 256) {
    int b = idx >> 4, l = idx & 15;
    int cc = blockIdx.x * 16 + l;
    float mx = -3.4e38f, mn = 3.4e38f;
    for (int i = 0; i < 16; i++) {
      mx = fmaxf(mx, pMx[(size_t)(b * 16 + i) * 1024 + cc]);
      mn = fminf(mn, pMn[(size_t)(b * 16 + i) * 1024 + cc]);
    }
    float a = sa[l];
    float v = (a > 0.f) ? (a * mx + sc[l]) : (a * mn + sc[l]);
    pooled[(size_t)b * 1024 + cc] = fmaxf(v, 0.f);
  }
}

// ---------------- fc1: wave-per-output ----------------
__global__ __launch_bounds__(256) void fc1_kernel(const float* __restrict__ pooled,
                                                  const float* __restrict__ w,
                                                  const float* __restrict__ bias,
                                                  float* __restrict__ zf1) {
  int gw = blockIdx.x * 4 + (threadIdx.x >> 6);
  int lane = threadIdx.x & 63;
  int b = gw >> 9, o = gw & 511;
  const float4* pr = (const float4*)(pooled + (size_t)b * 1024);
  const float4* wr = (const float4*)(w + (size_t)o * 1024);
  float acc = 0.f;
#pragma unroll
  for (int i = 0; i < 4; i++) {
    int k = lane + i * 64;
    float4 p = pr[k], q = wr[k];
    acc += p.x * q.x + p.y * q.y + p.z * q.z + p.w * q.w;
  }
  acc = wave_reduce_add(acc);
  if (lane == 0) zf1[gw] = acc + bias[o];
}

__global__ __launch_bounds__(256) void statsF_kernel(const float* __restrict__ z,
                                                     const float* __restrict__ g,
                                                     const float* __restrict__ be, int C,
                                                     float* __restrict__ scale,
                                                     float* __restrict__ shift) {
  int c = blockIdx.x * 256 + threadIdx.x;
  if (c >= C) return;
  float s = 0.f, q = 0.f;
  for (int b = 0; b < 32; b++) {
    float v = z[(size_t)b * C + c];
    s += v;
    q += v * v;
  }
  float m = s * (1.0f / 32.0f);
  float v = q * (1.0f / 32.0f) - m * m;
  float a = g[c] / sqrtf(v + EPS_BN);
  scale[c] = a;
  shift[c] = be[c] - m * a;
}

// ---------------- fc2: wave-per-output ----------------
__global__ __launch_bounds__(256) void fc2_kernel(const float* __restrict__ zf1,
                                                  const float* __restrict__ sf1,
                                                  const float* __restrict__ hf1,
                                                  const float* __restrict__ w,
                                                  const float* __restrict__ bias,
                                                  float* __restrict__ zf2) {
  int gw = blockIdx.x * 4 + (threadIdx.x >> 6);
  int lane = threadIdx.x & 63;
  int b = gw >> 8, o = gw & 255;
  const float4* zr = (const float4*)(zf1 + (size_t)b * 512);
  const float4* sr = (const float4*)sf1;
  const float4* hr = (const float4*)hf1;
  const float4* wr = (const float4*)(w + (size_t)o * 512);
  float acc = 0.f;
#pragma unroll
  for (int i = 0; i < 2; i++) {
    int k = lane + i * 64;
    float4 z = zr[k], s = sr[k], h = hr[k], q = wr[k];
    float v0 = fmaxf(z.x * s.x + h.x, 0.f);
    float v1 = fmaxf(z.y * s.y + h.y, 0.f);
    float v2 = fmaxf(z.z * s.z + h.z, 0.f);
    float v3 = fmaxf(z.w * s.w + h.w, 0.f);
    acc += v0 * q.x + v1 * q.y + v2 * q.z + v3 * q.w;
  }
  acc = wave_reduce_add(acc);
  if (lane == 0) zf2[gw] = acc + bias[o];
}

// ---------------- head: per-block BN-f2 stats + 4 waves x 10 dots + log_softmax ----------------
__global__ __launch_bounds__(256) void head_kernel(const float* __restrict__ zf2,
                                                   const float* __restrict__ gf2,
                                                   const float* __restrict__ bef2,
                                                   const float* __restrict__ w,
                                                   const float* __restrict__ bias,
                                                   float* __restrict__ out) {
  int b = blockIdx.x, tid = threadIdx.x;
  int wv = tid >> 6, lane = tid & 63;
  __shared__ float ssf[256], shf[256], lg[40], red[2];
  {
    float s = 0.f, q = 0.f;
    for (int bb = 0; bb < 32; bb++) {
      float v = zf2[(size_t)bb * 256 + tid];
      s += v;
      q += v * v;
    }
    float m = s * (1.0f / 32.0f);
    float var = q * (1.0f / 32.0f) - m * m;
    float a = gf2[tid] / sqrtf(var + EPS_BN);
    ssf[tid] = a;
    shf[tid] = bef2[tid] - m * a;
  }
  __syncthreads();
  float4 z = ((const float4*)(zf2 + (size_t)b * 256))[lane];
  float4 s = ((const float4*)ssf)[lane];
  float4 h = ((const float4*)shf)[lane];
  float v0 = fmaxf(z.x * s.x + h.x, 0.f);
  float v1 = fmaxf(z.y * s.y + h.y, 0.f);
  float v2 = fmaxf(z.z * s.z + h.z, 0.f);
  float v3 = fmaxf(z.w * s.w + h.w, 0.f);
  for (int r = 0; r < 10; r++) {
    int o = wv * 10 + r;
    float4 q = ((const float4*)(w + (size_t)o * 256))[lane];
    float a = v0 * q.x + v1 * q.y + v2 * q.z + v3 * q.w;
    a = wave_reduce_add(a);
    if (lane == 0) lg[o] = a + bias[o];
  }
  __syncthreads();
  if (tid == 0) {
    float mx = -3.4e38f;
    for (int i = 0; i < 40; i++) mx = fmaxf(mx, lg[i]);
    float sum = 0.f;
    for (int i = 0; i < 40; i++) sum += expf(lg[i] - mx);
    red[0] = mx;
    red[1] = logf(sum);
  }
  __syncthreads();
  if (tid < 40) out[(size_t)b * 40 + tid] = lg[tid] - red[0] - red[1];
}

extern "C" void kernel_launch(void* const* d_in, const int* in_sizes, int n_in,
                              void* d_out, int out_size, void* d_ws, size_t ws_size,
                              hipStream_t stream) {
  const float* x    = (const float*)d_in[0];
  const float* c1w  = (const float*)d_in[1];
  const float* c1b  = (const float*)d_in[2];
  const float* g1   = (const float*)d_in[3];
  const float* be1  = (const float*)d_in[4];
  const float* c2w  = (const float*)d_in[5];
  const float* c2b  = (const float*)d_in[6];
  const float* g2   = (const float*)d_in[7];
  const float* be2  = (const float*)d_in[8];
  const float* c3w  = (const float*)d_in[9];
  const float* c3b  = (const float*)d_in[10];
  const float* g3   = (const float*)d_in[11];
  const float* be3  = (const float*)d_in[12];
  const float* f1w  = (const float*)d_in[13];
  const float* f1b  = (const float*)d_in[14];
  const float* gf1  = (const float*)d_in[15];
  const float* bef1 = (const float*)d_in[16];
  const float* f2w  = (const float*)d_in[17];
  const float* f2b  = (const float*)d_in[18];
  const float* gf2  = (const float*)d_in[19];
  const float* bef2 = (const float*)d_in[20];
  const float* ow   = (const float*)d_in[21];
  const float* ob   = (const float*)d_in[22];
  float* out = (float*)d_out;

  float* W = (float*)d_ws;
  float* feat   = W;                   // 262144
  float* pS     = feat + 262144;       // 524288
  float* pQ     = pS + 524288;
  float* pMx    = pQ + 524288;
  float* pMn    = pMx + 524288;
  float* part   = pMn + 524288;        // 32768  (BN1 partials 256x64x2)
  float* part2  = part + 32768;        // 131072 (BN2 partials 512x128x2)
  float* pooled = part2 + 131072;      // 32768
  float* zf1    = pooled + 32768;      // 16384
  float* zf2    = zf1 + 16384;         // 8192
  float* s1     = zf2 + 8192;          // 64
  float* h1     = s1 + 64;
  float* s2     = h1 + 64;             // 128
  float* h2     = s2 + 128;
  float* sf1    = h2 + 128;            // 512
  float* hf1    = sf1 + 512;
  unsigned short* wbf  = (unsigned short*)(hf1 + 512);   // 131072 shorts
  unsigned short* z1bf = wbf + 131072;                   // 65536*64
  unsigned short* z2bf = z1bf + (size_t)BP * 64;         // 65536*128
  unsigned short* abf  = z2bf + (size_t)BP * 128;        // 65536*128

  wconv_kernel<<<128, 256, 0, stream>>>(c3w, wbf);
  curv_kernel<<<dim3(64, 32), 256, 0, stream>>>(x, feat);
  gemm1s_kernel<<<256, 256, 0, stream>>>(feat, c1w, c1b, z1bf, part);
  bnfinP_kernel<64, 256><<<64, 256, 0, stream>>>(part, g1, be1, s1, h1);
  gemm2_mfma_kernel<<<512, 256, 0, stream>>>(z1bf, s1, h1, c2w, c2b, z2bf, part2);
  bnfinP_kernel<128, 512><<<128, 256, 0, stream>>>(part2, g2, be2, s2, h2);
  bnrelu_bf16_kernel<<<4096, 256, 0, stream>>>(z2bf, s2, h2, abf);
  gemm3_mfma_kernel<<<4096, 256, 0, stream>>>(abf, wbf, c3b, pS, pQ, pMx, pMn);
  bn3fin_pool_kernel<<<64, 256, 0, stream>>>(pS, pQ, pMx, pMn, g3, be3, pooled);
  fc1_kernel<<<4096, 256, 0, stream>>>(pooled, f1w, f1b, zf1);
  statsF_kernel<<<2, 256, 0, stream>>>(zf1, gf1, bef1, 512, sf1, hf1);
  fc2_kernel<<<2048, 256, 0, stream>>>(zf1, sf1, hf1, f2w, f2b, zf2);
  head_kernel<<<32, 256, 0, stream>>>(zf2, gf2, bef2, ow, ob, out);
}

// Round 10
// 133.584 us; speedup vs baseline: 5.9155x; 1.0856x over previous
//
#include <hip/hip_runtime.h>
#include <hip/hip_bf16.h>
#include <math.h>

#define EPS_BN 1e-5f

constexpr int BATCH = 32;
constexpr int NPTS  = 2048;
constexpr int BP    = BATCH * NPTS;   // 65536

using s16x8 = __attribute__((ext_vector_type(8))) short;
using u32x4 = __attribute__((ext_vector_type(4))) unsigned;
using f32x4 = __attribute__((ext_vector_type(4))) float;

static __device__ __forceinline__ unsigned short f2bf(float f) {
  union { float f; unsigned u; } x{f};
  unsigned r = x.u + 0x7fffu + ((x.u >> 16) & 1u);  // RNE
  return (unsigned short)(r >> 16);
}
static __device__ __forceinline__ float bf2f(unsigned short s) {
  union { unsigned u; float f; } x;
  x.u = ((unsigned)s) << 16;
  return x.f;
}
static __device__ __forceinline__ unsigned pk2bf(float lo, float hi) {
  __hip_bfloat162 t = __float22bfloat162_rn(float2{lo, hi});
  unsigned r;
  __builtin_memcpy(&r, &t, 4);
  return r;
}

static __device__ __forceinline__ void gload_lds16(const void* g, void* l) {
  __builtin_amdgcn_global_load_lds((const __attribute__((address_space(1))) void*)g,
                                   (__attribute__((address_space(3))) void*)l, 16, 0, 0);
}

static __device__ __forceinline__ float wave_reduce_add(float v) {
#pragma unroll
  for (int off = 32; off > 0; off >>= 1) v += __shfl_xor(v, off);
  return v;
}

// keep-6-smallest, ASCENDING list, depth-1 branchless insert (1 min + 5 med3).
static __device__ __forceinline__ void ins6(float (&nn)[6], float c) {
  float b0 = fminf(nn[0], c);
  float b1 = __builtin_amdgcn_fmed3f(c, nn[1], nn[0]);
  float b2 = __builtin_amdgcn_fmed3f(c, nn[2], nn[1]);
  float b3 = __builtin_amdgcn_fmed3f(c, nn[3], nn[2]);
  float b4 = __builtin_amdgcn_fmed3f(c, nn[4], nn[3]);
  float b5 = __builtin_amdgcn_fmed3f(c, nn[5], nn[4]);
  nn[0] = b0; nn[1] = b1; nn[2] = b2; nn[3] = b3; nn[4] = b4; nn[5] = b5;
}

// ---------------- curvature: rank by r = 0.5|q|^2 - p.q  (d2 = |p|^2 + 2r) ----------------
constexpr int CH = 260;
__global__ __launch_bounds__(256) void curv_kernel(const float* __restrict__ x,
                                                   float* __restrict__ feat) {
  __shared__ float sx[8 * CH], sy[8 * CH], sz[8 * CH], sh[8 * CH];
  int b = blockIdx.y;
  const float* xb = x + (size_t)b * NPTS * 3;
  int tid = threadIdx.x;
#pragma unroll
  for (int k = 0; k < 8; k++) {
    int i = k * 256 + tid;
    float qx = xb[i * 3 + 0], qy = xb[i * 3 + 1], qz = xb[i * 3 + 2];
    sx[k * CH + tid] = qx;
    sy[k * CH + tid] = qy;
    sz[k * CH + tid] = qz;
    sh[k * CH + tid] = 0.5f * (qx * qx + qy * qy + qz * qz);
  }
  __syncthreads();
  int row = blockIdx.x * 32 + (tid >> 3);
  int sub = tid & 7;
  float px = sx[(row >> 8) * CH + (row & 255)];
  float py = sy[(row >> 8) * CH + (row & 255)];
  float pz = sz[(row >> 8) * CH + (row & 255)];
  float nn[6];
#pragma unroll
  for (int j = 0; j < 6; j++) nn[j] = 3.4e38f;
  const float4* cx = (const float4*)(sx + sub * CH);
  const float4* cy = (const float4*)(sy + sub * CH);
  const float4* cz = (const float4*)(sz + sub * CH);
  const float4* chq = (const float4*)(sh + sub * CH);
  for (int j = 0; j < 64; j++) {
    float4 qx = cx[j], qy = cy[j], qz = cz[j], qh = chq[j];
    ins6(nn, fmaf(-px, qx.x, fmaf(-py, qy.x, fmaf(-pz, qz.x, qh.x))));
    ins6(nn, fmaf(-px, qx.y, fmaf(-py, qy.y, fmaf(-pz, qz.y, qh.y))));
    ins6(nn, fmaf(-px, qx.z, fmaf(-py, qy.z, fmaf(-pz, qz.z, qh.z))));
    ins6(nn, fmaf(-px, qx.w, fmaf(-py, qy.w, fmaf(-pz, qz.w, qh.w))));
  }
#pragma unroll
  for (int m = 1; m <= 4; m <<= 1) {
    float other[6];
#pragma unroll
    for (int k = 0; k < 6; k++) other[k] = __shfl_xor(nn[k], m);
#pragma unroll
    for (int k = 0; k < 6; k++) ins6(nn, other[k]);
  }
  if (sub == 0) {
    float p2 = px * px + py * py + pz * pz;
    float dm = 0.f;
#pragma unroll
    for (int i = 1; i < 6; i++) dm += sqrtf(fmaxf(fmaf(2.f, nn[i], p2), 0.f));
    dm *= 0.2f;
    float curv = 1.0f / (1e-8f + dm);
    size_t o = ((size_t)b * NPTS + row) * 4;
    feat[o + 0] = px;
    feat[o + 1] = py;
    feat[o + 2] = pz;
    feat[o + 3] = curv;
  }
}

// ---------------- layer1 fused: z1bf = feat @ W1^T + b1 (bf16), + BN1 stats partials ----------------
__global__ __launch_bounds__(256) void gemm1s_kernel(const float* __restrict__ feat,
                                                     const float* __restrict__ w,
                                                     const float* __restrict__ bias,
                                                     unsigned short* __restrict__ z1bf,
                                                     float* __restrict__ part) {
  __shared__ float wT[4 * 64];
  int tid = threadIdx.x;
  { int k = tid >> 6, c = tid & 63; wT[k * 64 + c] = w[c * 4 + k]; }
  __syncthreads();
  int col = tid & 63, rg = tid >> 6;
  int row0 = blockIdx.x * 64;
  float w0 = wT[col], w1 = wT[64 + col], w2v = wT[128 + col], w3 = wT[192 + col];
  float bb = bias[col];
  float s = 0.f, q = 0.f;
  for (int i = 0; i < 16; i++) {
    int row = row0 + i * 4 + rg;
    const float4 f = *(const float4*)(feat + (size_t)row * 4);
    float acc = bb + f.x * w0 + f.y * w1 + f.z * w2v + f.w * w3;
    s += acc;
    q += acc * acc;
    z1bf[(size_t)row * 64 + col] = f2bf(acc);
  }
  __shared__ float ls[256], lq[256];
  ls[tid] = s; lq[tid] = q;
  __syncthreads();
  if (tid < 64) {
    float ss = 0.f, qq = 0.f;
#pragma unroll
    for (int i = 0; i < 4; i++) { ss += ls[i * 64 + tid]; qq += lq[i * 64 + tid]; }
    part[((size_t)blockIdx.x * 64 + tid) * 2 + 0] = ss;
    part[((size_t)blockIdx.x * 64 + tid) * 2 + 1] = qq;
  }
}

// ---------------- generic BN finalize from P partials ----------------
template <int C, int P>
__global__ __launch_bounds__(256) void bnfinP_kernel(const float* __restrict__ part,
                                                     const float* __restrict__ g,
                                                     const float* __restrict__ be,
                                                     float* __restrict__ scale,
                                                     float* __restrict__ shift) {
  int c = blockIdx.x, tid = threadIdx.x;
  float s = 0.f, q = 0.f;
  for (int i = tid; i < P; i += 256) {
    s += part[((size_t)i * C + c) * 2 + 0];
    q += part[((size_t)i * C + c) * 2 + 1];
  }
  __shared__ float ls[256], lq[256];
  ls[tid] = s; lq[tid] = q;
  __syncthreads();
  for (int off = 128; off > 0; off >>= 1) {
    if (tid < off) { ls[tid] += ls[tid + off]; lq[tid] += lq[tid + off]; }
    __syncthreads();
  }
  if (tid == 0) {
    float m = ls[0] * (1.0f / 65536.0f);
    float v = lq[0] * (1.0f / 65536.0f) - m * m;
    float a = g[c] / sqrtf(v + EPS_BN);
    scale[c] = a;
    shift[c] = be[c] - m * a;
  }
}

// ---------------- layer2 MFMA: relu(bn1(z1bf)) @ W2^T + b2 -> z2bf + BN2 stats ----------------
__global__ __launch_bounds__(256) void gemm2_mfma_kernel(const unsigned short* __restrict__ z1bf,
                                                         const float* __restrict__ s1,
                                                         const float* __restrict__ h1,
                                                         const float* __restrict__ w2,
                                                         const float* __restrict__ bias2,
                                                         unsigned short* __restrict__ z2bf,
                                                         float* __restrict__ part2) {
  __shared__ char lds[33280];  // A @0 (16KB), B @16384 (16KB), s1h1 @32768
  float* ls1 = (float*)(lds + 32768);
  float* lh1 = ls1 + 64;
  int tid = threadIdx.x;
  int row0 = blockIdx.x * 128;
  if (tid < 64) { ls1[tid] = s1[tid]; lh1[tid] = h1[tid]; }

  s16x8 araw[4];
  float4 b0[4], b1[4];
#pragma unroll
  for (int i = 0; i < 4; i++) {
    int L = tid + 256 * i;
    araw[i] = *(const s16x8*)(z1bf + (size_t)row0 * 64 + (size_t)L * 8);
    int crow = L >> 3, k0 = (L & 7) * 8;
    b0[i] = *(const float4*)(w2 + (size_t)crow * 64 + k0);
    b1[i] = *(const float4*)(w2 + (size_t)crow * 64 + k0 + 4);
  }
  __syncthreads();

#pragma unroll
  for (int i = 0; i < 4; i++) {
    int L = tid + 256 * i;
    int row = L >> 3, grp = L & 7, k0 = grp * 8;
    float4 sA = *(const float4*)(ls1 + k0);
    float4 sB = *(const float4*)(ls1 + k0 + 4);
    float4 hA = *(const float4*)(lh1 + k0);
    float4 hB = *(const float4*)(lh1 + k0 + 4);
    float v0 = fmaxf(bf2f((unsigned short)araw[i][0]) * sA.x + hA.x, 0.f);
    float v1 = fmaxf(bf2f((unsigned short)araw[i][1]) * sA.y + hA.y, 0.f);
    float v2 = fmaxf(bf2f((unsigned short)araw[i][2]) * sA.z + hA.z, 0.f);
    float v3 = fmaxf(bf2f((unsigned short)araw[i][3]) * sA.w + hA.w, 0.f);
    float v4 = fmaxf(bf2f((unsigned short)araw[i][4]) * sB.x + hB.x, 0.f);
    float v5 = fmaxf(bf2f((unsigned short)araw[i][5]) * sB.y + hB.y, 0.f);
    float v6 = fmaxf(bf2f((unsigned short)araw[i][6]) * sB.z + hB.z, 0.f);
    float v7 = fmaxf(bf2f((unsigned short)araw[i][7]) * sB.w + hB.w, 0.f);
    u32x4 pa = {pk2bf(v0, v1), pk2bf(v2, v3), pk2bf(v4, v5), pk2bf(v6, v7)};
    *(u32x4*)(lds + row * 128 + ((grp ^ (row & 7)) << 4)) = pa;
    u32x4 pb = {pk2bf(b0[i].x, b0[i].y), pk2bf(b0[i].z, b0[i].w),
                pk2bf(b1[i].x, b1[i].y), pk2bf(b1[i].z, b1[i].w)};
    *(u32x4*)(lds + 16384 + row * 128 + ((grp ^ (row & 7)) << 4)) = pb;
  }
  __syncthreads();

  int w = tid >> 6, lane = tid & 63;
  int wm = w >> 1, wn = w & 1;
  int lrow = lane & 15, lg = lane >> 4;
  int sw = (lrow & 7) << 4;
  f32x4 acc[4][4] = {};
#pragma unroll
  for (int kstep = 0; kstep < 2; kstep++) {
    s16x8 a[4], bfr[4];
#pragma unroll
    for (int m = 0; m < 4; m++) {
      int row = wm * 64 + m * 16 + lrow;
      int byte = row * 128 + ((kstep * 64 + lg * 16) ^ sw);
      a[m] = *(const s16x8*)(lds + byte);
    }
#pragma unroll
    for (int n = 0; n < 4; n++) {
      int col = wn * 64 + n * 16 + lrow;
      int byte = 16384 + col * 128 + ((kstep * 64 + lg * 16) ^ sw);
      bfr[n] = *(const s16x8*)(lds + byte);
    }
#pragma unroll
    for (int m = 0; m < 4; m++)
#pragma unroll
      for (int n = 0; n < 4; n++)
        acc[m][n] = __builtin_amdgcn_mfma_f32_16x16x32_bf16(a[m], bfr[n], acc[m][n], 0, 0, 0);
  }
  __syncthreads();

  float* sS = (float*)lds;
  float* sQ = sS + 256;
#pragma unroll
  for (int n = 0; n < 4; n++) {
    int col = wn * 64 + n * 16 + lrow;
    float bb = bias2[col];
    float s = 0.f, q = 0.f;
#pragma unroll
    for (int m = 0; m < 4; m++) {
#pragma unroll
      for (int r = 0; r < 4; r++) {
        float v = acc[m][n][r] + bb;
        s += v;
        q += v * v;
        int row = row0 + wm * 64 + m * 16 + lg * 4 + r;
        z2bf[(size_t)row * 128 + col] = f2bf(v);
      }
    }
    s += __shfl_xor(s, 16); s += __shfl_xor(s, 32);
    q += __shfl_xor(q, 16); q += __shfl_xor(q, 32);
    if (lane < 16) {
      int cidx = wn * 64 + n * 16 + lane;
      sS[wm * 128 + cidx] = s;
      sQ[wm * 128 + cidx] = q;
    }
  }
  __syncthreads();
  if (tid < 128) {
    part2[((size_t)blockIdx.x * 128 + tid) * 2 + 0] = sS[tid] + sS[128 + tid];
    part2[((size_t)blockIdx.x * 128 + tid) * 2 + 1] = sQ[tid] + sQ[128 + tid];
  }
}

// ---------------- w3 -> bf16 ----------------
__global__ __launch_bounds__(256) void wconv_kernel(const float* __restrict__ w,
                                                    unsigned short* __restrict__ wbf) {
  int g = blockIdx.x * 256 + threadIdx.x;
  const float4 v = ((const float4*)w)[g];
  unsigned short o0 = f2bf(v.x), o1 = f2bf(v.y), o2 = f2bf(v.z), o3 = f2bf(v.w);
  unsigned short* d = wbf + (size_t)g * 4;
  d[0] = o0; d[1] = o1; d[2] = o2; d[3] = o3;
}

// ---------------- layer3 MFMA: one block per 128-row panel, loop over 8 col-blocks.
// A = bf16(relu(bn2(z2bf))) transformed ONCE in reg-staging, resident in LDS.
__global__ __launch_bounds__(256) void gemm3_mfma_kernel(const unsigned short* __restrict__ z2bf,
                                                         const float* __restrict__ s2,
                                                         const float* __restrict__ h2,
                                                         const unsigned short* __restrict__ wbf,
                                                         const float* __restrict__ bias3,
                                                         float* __restrict__ pS,
                                                         float* __restrict__ pQ,
                                                         float* __restrict__ pMx,
                                                         float* __restrict__ pMn) {
  __shared__ char lds[70656];  // A[0,32768) B[32768,65536) scratch[65536,69632) s2h2[69632,70656)
  float* ls2 = (float*)(lds + 69632);
  float* lh2 = ls2 + 128;
  int tid = threadIdx.x;
  int w = tid >> 6, lane = tid & 63;
  // XCD-chunked: each XCD owns 64 contiguous row-panels.
  int bid = blockIdx.x;                 // 512 blocks
  int rblk = (bid & 7) * 64 + (bid >> 3);
  int row0 = rblk * 128;

  if (tid < 128) { ls2[tid] = s2[tid]; lh2[tid] = h2[tid]; }
  // A loads to regs (coalesced: 64 lanes = 4 rows x 256B)
  s16x8 araw[8];
#pragma unroll
  for (int i = 0; i < 8; i++) {
    int L = tid + 256 * i;
    int row = L >> 4, gc = L & 15;
    araw[i] = *(const s16x8*)(z2bf + (size_t)(row0 + row) * 128 + gc * 8);
  }
  __syncthreads();  // ls2/lh2 visible
  // transform + swizzled ds_write of A
#pragma unroll
  for (int i = 0; i < 8; i++) {
    int L = tid + 256 * i;
    int row = L >> 4, gc = L & 15, k0 = gc * 8;
    float4 sA = *(const float4*)(ls2 + k0);
    float4 sB = *(const float4*)(ls2 + k0 + 4);
    float4 hA = *(const float4*)(lh2 + k0);
    float4 hB = *(const float4*)(lh2 + k0 + 4);
    float v0 = fmaxf(bf2f((unsigned short)araw[i][0]) * sA.x + hA.x, 0.f);
    float v1 = fmaxf(bf2f((unsigned short)araw[i][1]) * sA.y + hA.y, 0.f);
    float v2 = fmaxf(bf2f((unsigned short)araw[i][2]) * sA.z + hA.z, 0.f);
    float v3 = fmaxf(bf2f((unsigned short)araw[i][3]) * sA.w + hA.w, 0.f);
    float v4 = fmaxf(bf2f((unsigned short)araw[i][4]) * sB.x + hB.x, 0.f);
    float v5 = fmaxf(bf2f((unsigned short)araw[i][5]) * sB.y + hB.y, 0.f);
    float v6 = fmaxf(bf2f((unsigned short)araw[i][6]) * sB.z + hB.z, 0.f);
    float v7 = fmaxf(bf2f((unsigned short)araw[i][7]) * sB.w + hB.w, 0.f);
    u32x4 pa = {pk2bf(v0, v1), pk2bf(v2, v3), pk2bf(v4, v5), pk2bf(v6, v7)};
    *(u32x4*)(lds + row * 256 + ((gc ^ (row & 7)) << 4)) = pa;
  }

  int wm = w >> 1, wn = w & 1;
  int lrow = lane & 15, lg = lane >> 4;
  int sw = (lrow & 7) << 4;
  float* sS = (float*)(lds + 65536);   // [2][128]
  float* sQ = sS + 256;
  float* sMx = sQ + 256;
  float* sMn = sMx + 256;

  for (int cblk = 0; cblk < 8; cblk++) {
    int col0 = cblk * 128;
    // stage B tile (pre-swizzled source, linear LDS dest)
#pragma unroll
    for (int i = 0; i < 8; i++) {
      int ldsoff = w * 8192 + i * 1024;
      int lin = ldsoff + lane * 16;
      int row = lin >> 8;
      int gc = (lin >> 4) & 15;
      int gcl = gc ^ (row & 7);
      gload_lds16(wbf + (size_t)(col0 + row) * 128 + gcl * 8, &lds[32768 + ldsoff]);
    }
    __syncthreads();  // A writes (iter 0) + B loads drained

    f32x4 acc[4][4] = {};
#pragma unroll
    for (int kstep = 0; kstep < 4; kstep++) {
      s16x8 a[4], b[4];
#pragma unroll
      for (int m = 0; m < 4; m++) {
        int row = wm * 64 + m * 16 + lrow;
        int byte = row * 256 + ((kstep * 64 + lg * 16) ^ sw);
        a[m] = *(const s16x8*)(lds + byte);
      }
#pragma unroll
      for (int n = 0; n < 4; n++) {
        int col = wn * 64 + n * 16 + lrow;
        int byte = 32768 + col * 256 + ((kstep * 64 + lg * 16) ^ sw);
        b[n] = *(const s16x8*)(lds + byte);
      }
#pragma unroll
      for (int m = 0; m < 4; m++)
#pragma unroll
        for (int n = 0; n < 4; n++)
          acc[m][n] = __builtin_amdgcn_mfma_f32_16x16x32_bf16(a[m], b[n], acc[m][n], 0, 0, 0);
    }

    // per-column stats over this panel's 128 rows
#pragma unroll
    for (int n = 0; n < 4; n++) {
      float bb = bias3[col0 + wn * 64 + n * 16 + lrow];
      float s = 0.f, q = 0.f, mx = -3.4e38f, mn = 3.4e38f;
#pragma unroll
      for (int m = 0; m < 4; m++)
#pragma unroll
        for (int r = 0; r < 4; r++) {
          float v = acc[m][n][r] + bb;
          s += v;
          q += v * v;
          mx = fmaxf(mx, v);
          mn = fminf(mn, v);
        }
      s += __shfl_xor(s, 16); s += __shfl_xor(s, 32);
      q += __shfl_xor(q, 16); q += __shfl_xor(q, 32);
      mx = fmaxf(mx, __shfl_xor(mx, 16)); mx = fmaxf(mx, __shfl_xor(mx, 32));
      mn = fminf(mn, __shfl_xor(mn, 16)); mn = fminf(mn, __shfl_xor(mn, 32));
      if (lane < 16) {
        int cidx = wn * 64 + n * 16 + lane;
        sS[wm * 128 + cidx] = s;
        sQ[wm * 128 + cidx] = q;
        sMx[wm * 128 + cidx] = mx;
        sMn[wm * 128 + cidx] = mn;
      }
    }
    __syncthreads();  // scratch writes visible; B reads done
    if (tid < 128) {
      size_t o = (size_t)rblk * 1024 + col0 + tid;
      pS[o] = sS[tid] + sS[128 + tid];
      pQ[o] = sQ[tid] + sQ[128 + tid];
      pMx[o] = fmaxf(sMx[tid], sMx[128 + tid]);
      pMn[o] = fminf(sMn[tid], sMn[128 + tid]);
    }
    __syncthreads();  // scratch reads done before next iter's writes; B safe to overwrite
  }
}

// ---------------- bn3 finalize + masked max-pool ----------------
__global__ __launch_bounds__(256) void bn3fin_pool_kernel(const float* __restrict__ pS,
                                                          const float* __restrict__ pQ,
                                                          const float* __restrict__ pMx,
                                                          const float* __restrict__ pMn,
                                                          const float* __restrict__ g,
                                                          const float* __restrict__ be,
                                                          float* __restrict__ pooled) {
  int tid = threadIdx.x;
  int chl = tid & 15, grp = tid >> 4;
  int c = blockIdx.x * 16 + chl;
  float s = 0.f, q = 0.f;
  for (int i = grp; i < 512; i += 16) {
    s += pS[(size_t)i * 1024 + c];
    q += pQ[(size_t)i * 1024 + c];
  }
  __shared__ float ls[256], lq[256], sa[16], sc[16];
  ls[chl * 16 + grp] = s;
  lq[chl * 16 + grp] = q;
  __syncthreads();
  if (tid < 16) {
    float ss = 0.f, qq = 0.f;
#pragma unroll
    for (int i = 0; i < 16; i++) { ss += ls[tid * 16 + i]; qq += lq[tid * 16 + i]; }
    float m = ss * (1.0f / 65536.0f);
    float v = qq * (1.0f / 65536.0f) - m * m;
    float a = g[blockIdx.x * 16 + tid] / sqrtf(v + EPS_BN);
    sa[tid] = a;
    sc[tid] = be[blockIdx.x * 16 + tid] - m * a;
  }
  __syncthreads();
  for (int idx = tid; idx < 512; idx += 256) {
    int b = idx >> 4, l = idx & 15;
    int cc = blockIdx.x * 16 + l;
    float mx = -3.4e38f, mn = 3.4e38f;
    for (int i = 0; i < 16; i++) {
      mx = fmaxf(mx, pMx[(size_t)(b * 16 + i) * 1024 + cc]);
      mn = fminf(mn, pMn[(size_t)(b * 16 + i) * 1024 + cc]);
    }
    float a = sa[l];
    float v = (a > 0.f) ? (a * mx + sc[l]) : (a * mn + sc[l]);
    pooled[(size_t)b * 1024 + cc] = fmaxf(v, 0.f);
  }
}

// ---------------- fc1: wave-per-output ----------------
__global__ __launch_bounds__(256) void fc1_kernel(const float* __restrict__ pooled,
                                                  const float* __restrict__ w,
                                                  const float* __restrict__ bias,
                                                  float* __restrict__ zf1) {
  int gw = blockIdx.x * 4 + (threadIdx.x >> 6);
  int lane = threadIdx.x & 63;
  int b = gw >> 9, o = gw & 511;
  const float4* pr = (const float4*)(pooled + (size_t)b * 1024);
  const float4* wr = (const float4*)(w + (size_t)o * 1024);
  float acc = 0.f;
#pragma unroll
  for (int i = 0; i < 4; i++) {
    int k = lane + i * 64;
    float4 p = pr[k], q = wr[k];
    acc += p.x * q.x + p.y * q.y + p.z * q.z + p.w * q.w;
  }
  acc = wave_reduce_add(acc);
  if (lane == 0) zf1[gw] = acc + bias[o];
}

__global__ __launch_bounds__(256) void statsF_kernel(const float* __restrict__ z,
                                                     const float* __restrict__ g,
                                                     const float* __restrict__ be, int C,
                                                     float* __restrict__ scale,
                                                     float* __restrict__ shift) {
  int c = blockIdx.x * 256 + threadIdx.x;
  if (c >= C) return;
  float s = 0.f, q = 0.f;
  for (int b = 0; b < 32; b++) {
    float v = z[(size_t)b * C + c];
    s += v;
    q += v * v;
  }
  float m = s * (1.0f / 32.0f);
  float v = q * (1.0f / 32.0f) - m * m;
  float a = g[c] / sqrtf(v + EPS_BN);
  scale[c] = a;
  shift[c] = be[c] - m * a;
}

// ---------------- fc2: wave-per-output ----------------
__global__ __launch_bounds__(256) void fc2_kernel(const float* __restrict__ zf1,
                                                  const float* __restrict__ sf1,
                                                  const float* __restrict__ hf1,
                                                  const float* __restrict__ w,
                                                  const float* __restrict__ bias,
                                                  float* __restrict__ zf2) {
  int gw = blockIdx.x * 4 + (threadIdx.x >> 6);
  int lane = threadIdx.x & 63;
  int b = gw >> 8, o = gw & 255;
  const float4* zr = (const float4*)(zf1 + (size_t)b * 512);
  const float4* sr = (const float4*)sf1;
  const float4* hr = (const float4*)hf1;
  const float4* wr = (const float4*)(w + (size_t)o * 512);
  float acc = 0.f;
#pragma unroll
  for (int i = 0; i < 2; i++) {
    int k = lane + i * 64;
    float4 z = zr[k], s = sr[k], h = hr[k], q = wr[k];
    float v0 = fmaxf(z.x * s.x + h.x, 0.f);
    float v1 = fmaxf(z.y * s.y + h.y, 0.f);
    float v2 = fmaxf(z.z * s.z + h.z, 0.f);
    float v3 = fmaxf(z.w * s.w + h.w, 0.f);
    acc += v0 * q.x + v1 * q.y + v2 * q.z + v3 * q.w;
  }
  acc = wave_reduce_add(acc);
  if (lane == 0) zf2[gw] = acc + bias[o];
}

// ---------------- head: per-block BN-f2 stats + 4 waves x 10 dots + log_softmax ----------------
__global__ __launch_bounds__(256) void head_kernel(const float* __restrict__ zf2,
                                                   const float* __restrict__ gf2,
                                                   const float* __restrict__ bef2,
                                                   const float* __restrict__ w,
                                                   const float* __restrict__ bias,
                                                   float* __restrict__ out) {
  int b = blockIdx.x, tid = threadIdx.x;
  int wv = tid >> 6, lane = tid & 63;
  __shared__ float ssf[256], shf[256], lg[40], red[2];
  {
    float s = 0.f, q = 0.f;
    for (int bb = 0; bb < 32; bb++) {
      float v = zf2[(size_t)bb * 256 + tid];
      s += v;
      q += v * v;
    }
    float m = s * (1.0f / 32.0f);
    float var = q * (1.0f / 32.0f) - m * m;
    float a = gf2[tid] / sqrtf(var + EPS_BN);
    ssf[tid] = a;
    shf[tid] = bef2[tid] - m * a;
  }
  __syncthreads();
  float4 z = ((const float4*)(zf2 + (size_t)b * 256))[lane];
  float4 s = ((const float4*)ssf)[lane];
  float4 h = ((const float4*)shf)[lane];
  float v0 = fmaxf(z.x * s.x + h.x, 0.f);
  float v1 = fmaxf(z.y * s.y + h.y, 0.f);
  float v2 = fmaxf(z.z * s.z + h.z, 0.f);
  float v3 = fmaxf(z.w * s.w + h.w, 0.f);
  for (int r = 0; r < 10; r++) {
    int o = wv * 10 + r;
    float4 q = ((const float4*)(w + (size_t)o * 256))[lane];
    float a = v0 * q.x + v1 * q.y + v2 * q.z + v3 * q.w;
    a = wave_reduce_add(a);
    if (lane == 0) lg[o] = a + bias[o];
  }
  __syncthreads();
  if (tid == 0) {
    float mx = -3.4e38f;
    for (int i = 0; i < 40; i++) mx = fmaxf(mx, lg[i]);
    float sum = 0.f;
    for (int i = 0; i < 40; i++) sum += expf(lg[i] - mx);
    red[0] = mx;
    red[1] = logf(sum);
  }
  __syncthreads();
  if (tid < 40) out[(size_t)b * 40 + tid] = lg[tid] - red[0] - red[1];
}

extern "C" void kernel_launch(void* const* d_in, const int* in_sizes, int n_in,
                              void* d_out, int out_size, void* d_ws, size_t ws_size,
                              hipStream_t stream) {
  const float* x    = (const float*)d_in[0];
  const float* c1w  = (const float*)d_in[1];
  const float* c1b  = (const float*)d_in[2];
  const float* g1   = (const float*)d_in[3];
  const float* be1  = (const float*)d_in[4];
  const float* c2w  = (const float*)d_in[5];
  const float* c2b  = (const float*)d_in[6];
  const float* g2   = (const float*)d_in[7];
  const float* be2  = (const float*)d_in[8];
  const float* c3w  = (const float*)d_in[9];
  const float* c3b  = (const float*)d_in[10];
  const float* g3   = (const float*)d_in[11];
  const float* be3  = (const float*)d_in[12];
  const float* f1w  = (const float*)d_in[13];
  const float* f1b  = (const float*)d_in[14];
  const float* gf1  = (const float*)d_in[15];
  const float* bef1 = (const float*)d_in[16];
  const float* f2w  = (const float*)d_in[17];
  const float* f2b  = (const float*)d_in[18];
  const float* gf2  = (const float*)d_in[19];
  const float* bef2 = (const float*)d_in[20];
  const float* ow   = (const float*)d_in[21];
  const float* ob   = (const float*)d_in[22];
  float* out = (float*)d_out;

  float* W = (float*)d_ws;
  float* feat   = W;                   // 262144
  float* pS     = feat + 262144;       // 524288
  float* pQ     = pS + 524288;
  float* pMx    = pQ + 524288;
  float* pMn    = pMx + 524288;
  float* part   = pMn + 524288;        // 131072 (BN1 partials 1024x64x2)
  float* part2  = part + 131072;       // 131072 (BN2 partials 512x128x2)
  float* pooled = part2 + 131072;      // 32768
  float* zf1    = pooled + 32768;      // 16384
  float* zf2    = zf1 + 16384;         // 8192
  float* s1     = zf2 + 8192;          // 64
  float* h1     = s1 + 64;
  float* s2     = h1 + 64;             // 128
  float* h2     = s2 + 128;
  float* sf1    = h2 + 128;            // 512
  float* hf1    = sf1 + 512;
  unsigned short* wbf  = (unsigned short*)(hf1 + 512);   // 131072 shorts
  unsigned short* z1bf = wbf + 131072;                   // 65536*64
  unsigned short* z2bf = z1bf + (size_t)BP * 64;         // 65536*128

  wconv_kernel<<<128, 256, 0, stream>>>(c3w, wbf);
  curv_kernel<<<dim3(64, 32), 256, 0, stream>>>(x, feat);
  gemm1s_kernel<<<1024, 256, 0, stream>>>(feat, c1w, c1b, z1bf, part);
  bnfinP_kernel<64, 1024><<<64, 256, 0, stream>>>(part, g1, be1, s1, h1);
  gemm2_mfma_kernel<<<512, 256, 0, stream>>>(z1bf, s1, h1, c2w, c2b, z2bf, part2);
  bnfinP_kernel<128, 512><<<128, 256, 0, stream>>>(part2, g2, be2, s2, h2);
  gemm3_mfma_kernel<<<512, 256, 0, stream>>>(z2bf, s2, h2, wbf, c3b, pS, pQ, pMx, pMn);
  bn3fin_pool_kernel<<<64, 256, 0, stream>>>(pS, pQ, pMx, pMn, g3, be3, pooled);
  fc1_kernel<<<4096, 256, 0, stream>>>(pooled, f1w, f1b, zf1);
  statsF_kernel<<<2, 256, 0, stream>>>(zf1, gf1, bef1, 512, sf1, hf1);
  fc2_kernel<<<2048, 256, 0, stream>>>(zf1, sf1, hf1, f2w, f2b, zf2);
  head_kernel<<<32, 256, 0, stream>>>(zf2, gf2, bef2, ow, ob, out);
}

// Round 11
// 130.628 us; speedup vs baseline: 6.0494x; 1.0226x over previous
//
#include <hip/hip_runtime.h>
#include <hip/hip_bf16.h>
#include <math.h>

#define EPS_BN 1e-5f

constexpr int BATCH = 32;
constexpr int NPTS  = 2048;
constexpr int BP    = BATCH * NPTS;   // 65536

using s16x8 = __attribute__((ext_vector_type(8))) short;
using u32x4 = __attribute__((ext_vector_type(4))) unsigned;
using f32x4 = __attribute__((ext_vector_type(4))) float;

static __device__ __forceinline__ unsigned short f2bf(float f) {
  union { float f; unsigned u; } x{f};
  unsigned r = x.u + 0x7fffu + ((x.u >> 16) & 1u);  // RNE
  return (unsigned short)(r >> 16);
}
static __device__ __forceinline__ float bf2f(unsigned short s) {
  union { unsigned u; float f; } x;
  x.u = ((unsigned)s) << 16;
  return x.f;
}
static __device__ __forceinline__ unsigned pk2bf(float lo, float hi) {
  __hip_bfloat162 t = __float22bfloat162_rn(float2{lo, hi});
  unsigned r;
  __builtin_memcpy(&r, &t, 4);
  return r;
}

static __device__ __forceinline__ void gload_lds16(const void* g, void* l) {
  __builtin_amdgcn_global_load_lds((const __attribute__((address_space(1))) void*)g,
                                   (__attribute__((address_space(3))) void*)l, 16, 0, 0);
}

static __device__ __forceinline__ float wave_reduce_add(float v) {
#pragma unroll
  for (int off = 32; off > 0; off >>= 1) v += __shfl_xor(v, off);
  return v;
}

// keep-6-smallest, ASCENDING list, depth-1 branchless insert (1 min + 5 med3).
static __device__ __forceinline__ void ins6(float (&nn)[6], float c) {
  float b0 = fminf(nn[0], c);
  float b1 = __builtin_amdgcn_fmed3f(c, nn[1], nn[0]);
  float b2 = __builtin_amdgcn_fmed3f(c, nn[2], nn[1]);
  float b3 = __builtin_amdgcn_fmed3f(c, nn[3], nn[2]);
  float b4 = __builtin_amdgcn_fmed3f(c, nn[4], nn[3]);
  float b5 = __builtin_amdgcn_fmed3f(c, nn[5], nn[4]);
  nn[0] = b0; nn[1] = b1; nn[2] = b2; nn[3] = b3; nn[4] = b4; nn[5] = b5;
}

// ---------------- curvature + fused layer1 ----------------
// rank by r = 0.5|q|^2 - p.q  (d2 = |p|^2 + 2r); then per-block 32x4 @ 4x64 matmul
// writes z1bf (bf16) + BN1 stats partials. feat never hits HBM.
constexpr int CH = 260;
__global__ __launch_bounds__(256) void curv1_kernel(const float* __restrict__ x,
                                                    const float* __restrict__ c1w,
                                                    const float* __restrict__ c1b,
                                                    unsigned short* __restrict__ z1bf,
                                                    float* __restrict__ part) {
  __shared__ float sx[8 * CH], sy[8 * CH], sz[8 * CH], sh[8 * CH];
  __shared__ float wT[4 * 64], lb1[64], sfeat[32 * 4];
  __shared__ float ls[256], lq[256];
  int b = blockIdx.y;
  const float* xb = x + (size_t)b * NPTS * 3;
  int tid = threadIdx.x;
  {  // stage w1^T and b1
    int k = tid >> 6, c = tid & 63;
    wT[k * 64 + c] = c1w[c * 4 + k];
    if (tid < 64) lb1[tid] = c1b[tid];
  }
#pragma unroll
  for (int k = 0; k < 8; k++) {
    int i = k * 256 + tid;
    float qx = xb[i * 3 + 0], qy = xb[i * 3 + 1], qz = xb[i * 3 + 2];
    sx[k * CH + tid] = qx;
    sy[k * CH + tid] = qy;
    sz[k * CH + tid] = qz;
    sh[k * CH + tid] = 0.5f * (qx * qx + qy * qy + qz * qz);
  }
  __syncthreads();
  int row = blockIdx.x * 32 + (tid >> 3);
  int sub = tid & 7;
  float px = sx[(row >> 8) * CH + (row & 255)];
  float py = sy[(row >> 8) * CH + (row & 255)];
  float pz = sz[(row >> 8) * CH + (row & 255)];
  float nn[6];
#pragma unroll
  for (int j = 0; j < 6; j++) nn[j] = 3.4e38f;
  const float4* cx = (const float4*)(sx + sub * CH);
  const float4* cy = (const float4*)(sy + sub * CH);
  const float4* cz = (const float4*)(sz + sub * CH);
  const float4* chq = (const float4*)(sh + sub * CH);
  for (int j = 0; j < 64; j++) {
    float4 qx = cx[j], qy = cy[j], qz = cz[j], qh = chq[j];
    ins6(nn, fmaf(-px, qx.x, fmaf(-py, qy.x, fmaf(-pz, qz.x, qh.x))));
    ins6(nn, fmaf(-px, qx.y, fmaf(-py, qy.y, fmaf(-pz, qz.y, qh.y))));
    ins6(nn, fmaf(-px, qx.z, fmaf(-py, qy.z, fmaf(-pz, qz.z, qh.z))));
    ins6(nn, fmaf(-px, qx.w, fmaf(-py, qy.w, fmaf(-pz, qz.w, qh.w))));
  }
#pragma unroll
  for (int m = 1; m <= 4; m <<= 1) {
    float other[6];
#pragma unroll
    for (int k = 0; k < 6; k++) other[k] = __shfl_xor(nn[k], m);
#pragma unroll
    for (int k = 0; k < 6; k++) ins6(nn, other[k]);
  }
  if (sub == 0) {
    float p2 = px * px + py * py + pz * pz;
    float dm = 0.f;
#pragma unroll
    for (int i = 1; i < 6; i++) dm += sqrtf(fmaxf(fmaf(2.f, nn[i], p2), 0.f));
    dm *= 0.2f;
    float curv = 1.0f / (1e-8f + dm);
    int lr = tid >> 3;
    sfeat[lr * 4 + 0] = px;
    sfeat[lr * 4 + 1] = py;
    sfeat[lr * 4 + 2] = pz;
    sfeat[lr * 4 + 3] = curv;
  }
  __syncthreads();
  // fused layer1: 32 rows x 64 cols; thread = (col, rowgroup of 8)
  {
    int c = tid & 63, rg = tid >> 6;
    float w0 = wT[c], w1 = wT[64 + c], w2v = wT[128 + c], w3 = wT[192 + c];
    float bb = lb1[c];
    int growbase = b * NPTS + blockIdx.x * 32;
    float s = 0.f, q = 0.f;
#pragma unroll
    for (int i = 0; i < 8; i++) {
      int lr = rg * 8 + i;
      float4 f = *(const float4*)(sfeat + lr * 4);
      float acc = bb + f.x * w0 + f.y * w1 + f.z * w2v + f.w * w3;
      s += acc;
      q += acc * acc;
      z1bf[(size_t)(growbase + lr) * 64 + c] = f2bf(acc);
    }
    ls[tid] = s;
    lq[tid] = q;
  }
  __syncthreads();
  if (tid < 64) {
    float ss = 0.f, qq = 0.f;
#pragma unroll
    for (int i = 0; i < 4; i++) { ss += ls[i * 64 + tid]; qq += lq[i * 64 + tid]; }
    size_t bid = (size_t)b * 64 + blockIdx.x;
    part[(bid * 64 + tid) * 2 + 0] = ss;
    part[(bid * 64 + tid) * 2 + 1] = qq;
  }
}

// ---------------- generic BN finalize from P partials ----------------
template <int C, int P>
__global__ __launch_bounds__(256) void bnfinP_kernel(const float* __restrict__ part,
                                                     const float* __restrict__ g,
                                                     const float* __restrict__ be,
                                                     float* __restrict__ scale,
                                                     float* __restrict__ shift) {
  int c = blockIdx.x, tid = threadIdx.x;
  float s = 0.f, q = 0.f;
  for (int i = tid; i < P; i += 256) {
    s += part[((size_t)i * C + c) * 2 + 0];
    q += part[((size_t)i * C + c) * 2 + 1];
  }
  __shared__ float ls[256], lq[256];
  ls[tid] = s; lq[tid] = q;
  __syncthreads();
  for (int off = 128; off > 0; off >>= 1) {
    if (tid < off) { ls[tid] += ls[tid + off]; lq[tid] += lq[tid + off]; }
    __syncthreads();
  }
  if (tid == 0) {
    float m = ls[0] * (1.0f / 65536.0f);
    float v = lq[0] * (1.0f / 65536.0f) - m * m;
    float a = g[c] / sqrtf(v + EPS_BN);
    scale[c] = a;
    shift[c] = be[c] - m * a;
  }
}

// ---------------- layer2 MFMA: relu(bn1(z1bf)) @ W2^T + b2 -> z2bf + BN2 stats ----------------
__global__ __launch_bounds__(256) void gemm2_mfma_kernel(const unsigned short* __restrict__ z1bf,
                                                         const float* __restrict__ s1,
                                                         const float* __restrict__ h1,
                                                         const float* __restrict__ w2,
                                                         const float* __restrict__ bias2,
                                                         unsigned short* __restrict__ z2bf,
                                                         float* __restrict__ part2) {
  __shared__ char lds[33280];  // A @0 (16KB), B @16384 (16KB), s1h1 @32768
  float* ls1 = (float*)(lds + 32768);
  float* lh1 = ls1 + 64;
  int tid = threadIdx.x;
  int row0 = blockIdx.x * 128;
  if (tid < 64) { ls1[tid] = s1[tid]; lh1[tid] = h1[tid]; }

  s16x8 araw[4];
  float4 b0[4], b1[4];
#pragma unroll
  for (int i = 0; i < 4; i++) {
    int L = tid + 256 * i;
    araw[i] = *(const s16x8*)(z1bf + (size_t)row0 * 64 + (size_t)L * 8);
    int crow = L >> 3, k0 = (L & 7) * 8;
    b0[i] = *(const float4*)(w2 + (size_t)crow * 64 + k0);
    b1[i] = *(const float4*)(w2 + (size_t)crow * 64 + k0 + 4);
  }
  __syncthreads();

#pragma unroll
  for (int i = 0; i < 4; i++) {
    int L = tid + 256 * i;
    int row = L >> 3, grp = L & 7, k0 = grp * 8;
    float4 sA = *(const float4*)(ls1 + k0);
    float4 sB = *(const float4*)(ls1 + k0 + 4);
    float4 hA = *(const float4*)(lh1 + k0);
    float4 hB = *(const float4*)(lh1 + k0 + 4);
    float v0 = fmaxf(bf2f((unsigned short)araw[i][0]) * sA.x + hA.x, 0.f);
    float v1 = fmaxf(bf2f((unsigned short)araw[i][1]) * sA.y + hA.y, 0.f);
    float v2 = fmaxf(bf2f((unsigned short)araw[i][2]) * sA.z + hA.z, 0.f);
    float v3 = fmaxf(bf2f((unsigned short)araw[i][3]) * sA.w + hA.w, 0.f);
    float v4 = fmaxf(bf2f((unsigned short)araw[i][4]) * sB.x + hB.x, 0.f);
    float v5 = fmaxf(bf2f((unsigned short)araw[i][5]) * sB.y + hB.y, 0.f);
    float v6 = fmaxf(bf2f((unsigned short)araw[i][6]) * sB.z + hB.z, 0.f);
    float v7 = fmaxf(bf2f((unsigned short)araw[i][7]) * sB.w + hB.w, 0.f);
    u32x4 pa = {pk2bf(v0, v1), pk2bf(v2, v3), pk2bf(v4, v5), pk2bf(v6, v7)};
    *(u32x4*)(lds + row * 128 + ((grp ^ (row & 7)) << 4)) = pa;
    u32x4 pb = {pk2bf(b0[i].x, b0[i].y), pk2bf(b0[i].z, b0[i].w),
                pk2bf(b1[i].x, b1[i].y), pk2bf(b1[i].z, b1[i].w)};
    *(u32x4*)(lds + 16384 + row * 128 + ((grp ^ (row & 7)) << 4)) = pb;
  }
  __syncthreads();

  int w = tid >> 6, lane = tid & 63;
  int wm = w >> 1, wn = w & 1;
  int lrow = lane & 15, lg = lane >> 4;
  int sw = (lrow & 7) << 4;
  f32x4 acc[4][4] = {};
#pragma unroll
  for (int kstep = 0; kstep < 2; kstep++) {
    s16x8 a[4], bfr[4];
#pragma unroll
    for (int m = 0; m < 4; m++) {
      int row = wm * 64 + m * 16 + lrow;
      int byte = row * 128 + ((kstep * 64 + lg * 16) ^ sw);
      a[m] = *(const s16x8*)(lds + byte);
    }
#pragma unroll
    for (int n = 0; n < 4; n++) {
      int col = wn * 64 + n * 16 + lrow;
      int byte = 16384 + col * 128 + ((kstep * 64 + lg * 16) ^ sw);
      bfr[n] = *(const s16x8*)(lds + byte);
    }
#pragma unroll
    for (int m = 0; m < 4; m++)
#pragma unroll
      for (int n = 0; n < 4; n++)
        acc[m][n] = __builtin_amdgcn_mfma_f32_16x16x32_bf16(a[m], bfr[n], acc[m][n], 0, 0, 0);
  }
  __syncthreads();

  float* sS = (float*)lds;
  float* sQ = sS + 256;
#pragma unroll
  for (int n = 0; n < 4; n++) {
    int col = wn * 64 + n * 16 + lrow;
    float bb = bias2[col];
    float s = 0.f, q = 0.f;
#pragma unroll
    for (int m = 0; m < 4; m++) {
#pragma unroll
      for (int r = 0; r < 4; r++) {
        float v = acc[m][n][r] + bb;
        s += v;
        q += v * v;
        int row = row0 + wm * 64 + m * 16 + lg * 4 + r;
        z2bf[(size_t)row * 128 + col] = f2bf(v);
      }
    }
    s += __shfl_xor(s, 16); s += __shfl_xor(s, 32);
    q += __shfl_xor(q, 16); q += __shfl_xor(q, 32);
    if (lane < 16) {
      int cidx = wn * 64 + n * 16 + lane;
      sS[wm * 128 + cidx] = s;
      sQ[wm * 128 + cidx] = q;
    }
  }
  __syncthreads();
  if (tid < 128) {
    part2[((size_t)blockIdx.x * 128 + tid) * 2 + 0] = sS[tid] + sS[128 + tid];
    part2[((size_t)blockIdx.x * 128 + tid) * 2 + 1] = sQ[tid] + sQ[128 + tid];
  }
}

// ---------------- w3 -> bf16 ----------------
__global__ __launch_bounds__(256) void wconv_kernel(const float* __restrict__ w,
                                                    unsigned short* __restrict__ wbf) {
  int g = blockIdx.x * 256 + threadIdx.x;
  const float4 v = ((const float4*)w)[g];
  unsigned short o0 = f2bf(v.x), o1 = f2bf(v.y), o2 = f2bf(v.z), o3 = f2bf(v.w);
  unsigned short* d = wbf + (size_t)g * 4;
  d[0] = o0; d[1] = o1; d[2] = o2; d[3] = o3;
}

// ---------------- layer3 MFMA: one block per 128-row panel, loop over 8 col-blocks.
// A transformed ONCE in reg-staging; stats accumulate RAW acc, bias folded at finalize.
__global__ __launch_bounds__(256) void gemm3_mfma_kernel(const unsigned short* __restrict__ z2bf,
                                                         const float* __restrict__ s2,
                                                         const float* __restrict__ h2,
                                                         const unsigned short* __restrict__ wbf,
                                                         const float* __restrict__ bias3,
                                                         float* __restrict__ pS,
                                                         float* __restrict__ pQ,
                                                         float* __restrict__ pMx,
                                                         float* __restrict__ pMn) {
  __shared__ char lds[70656];  // A[0,32768) B[32768,65536) scratch[65536,69632) s2h2[69632,70656)
  float* ls2 = (float*)(lds + 69632);
  float* lh2 = ls2 + 128;
  int tid = threadIdx.x;
  int w = tid >> 6, lane = tid & 63;
  int bid = blockIdx.x;                 // 512 blocks, XCD-chunked
  int rblk = (bid & 7) * 64 + (bid >> 3);
  int row0 = rblk * 128;

  if (tid < 128) { ls2[tid] = s2[tid]; lh2[tid] = h2[tid]; }
  s16x8 araw[8];
#pragma unroll
  for (int i = 0; i < 8; i++) {
    int L = tid + 256 * i;
    int row = L >> 4, gc = L & 15;
    araw[i] = *(const s16x8*)(z2bf + (size_t)(row0 + row) * 128 + gc * 8);
  }
  __syncthreads();
#pragma unroll
  for (int i = 0; i < 8; i++) {
    int L = tid + 256 * i;
    int row = L >> 4, gc = L & 15, k0 = gc * 8;
    float4 sA = *(const float4*)(ls2 + k0);
    float4 sB = *(const float4*)(ls2 + k0 + 4);
    float4 hA = *(const float4*)(lh2 + k0);
    float4 hB = *(const float4*)(lh2 + k0 + 4);
    float v0 = fmaxf(bf2f((unsigned short)araw[i][0]) * sA.x + hA.x, 0.f);
    float v1 = fmaxf(bf2f((unsigned short)araw[i][1]) * sA.y + hA.y, 0.f);
    float v2 = fmaxf(bf2f((unsigned short)araw[i][2]) * sA.z + hA.z, 0.f);
    float v3 = fmaxf(bf2f((unsigned short)araw[i][3]) * sA.w + hA.w, 0.f);
    float v4 = fmaxf(bf2f((unsigned short)araw[i][4]) * sB.x + hB.x, 0.f);
    float v5 = fmaxf(bf2f((unsigned short)araw[i][5]) * sB.y + hB.y, 0.f);
    float v6 = fmaxf(bf2f((unsigned short)araw[i][6]) * sB.z + hB.z, 0.f);
    float v7 = fmaxf(bf2f((unsigned short)araw[i][7]) * sB.w + hB.w, 0.f);
    u32x4 pa = {pk2bf(v0, v1), pk2bf(v2, v3), pk2bf(v4, v5), pk2bf(v6, v7)};
    *(u32x4*)(lds + row * 256 + ((gc ^ (row & 7)) << 4)) = pa;
  }

  int wm = w >> 1, wn = w & 1;
  int lrow = lane & 15, lg = lane >> 4;
  int sw = (lrow & 7) << 4;
  float* sS = (float*)(lds + 65536);   // [2][128]
  float* sQ = sS + 256;
  float* sMx = sQ + 256;
  float* sMn = sMx + 256;

  for (int cblk = 0; cblk < 8; cblk++) {
    int col0 = cblk * 128;
#pragma unroll
    for (int i = 0; i < 8; i++) {
      int ldsoff = w * 8192 + i * 1024;
      int lin = ldsoff + lane * 16;
      int row = lin >> 8;
      int gc = (lin >> 4) & 15;
      int gcl = gc ^ (row & 7);
      gload_lds16(wbf + (size_t)(col0 + row) * 128 + gcl * 8, &lds[32768 + ldsoff]);
    }
    __syncthreads();

    f32x4 acc[4][4] = {};
#pragma unroll
    for (int kstep = 0; kstep < 4; kstep++) {
      s16x8 a[4], b[4];
#pragma unroll
      for (int m = 0; m < 4; m++) {
        int row = wm * 64 + m * 16 + lrow;
        int byte = row * 256 + ((kstep * 64 + lg * 16) ^ sw);
        a[m] = *(const s16x8*)(lds + byte);
      }
#pragma unroll
      for (int n = 0; n < 4; n++) {
        int col = wn * 64 + n * 16 + lrow;
        int byte = 32768 + col * 256 + ((kstep * 64 + lg * 16) ^ sw);
        b[n] = *(const s16x8*)(lds + byte);
      }
#pragma unroll
      for (int m = 0; m < 4; m++)
#pragma unroll
        for (int n = 0; n < 4; n++)
          acc[m][n] = __builtin_amdgcn_mfma_f32_16x16x32_bf16(a[m], b[n], acc[m][n], 0, 0, 0);
    }

    // RAW per-column stats (bias deferred to finalize)
#pragma unroll
    for (int n = 0; n < 4; n++) {
      float s = 0.f, q = 0.f, mx = -3.4e38f, mn = 3.4e38f;
#pragma unroll
      for (int m = 0; m < 4; m++)
#pragma unroll
        for (int r = 0; r < 4; r++) {
          float v = acc[m][n][r];
          s += v;
          q = fmaf(v, v, q);
          mx = fmaxf(mx, v);
          mn = fminf(mn, v);
        }
      s += __shfl_xor(s, 16); s += __shfl_xor(s, 32);
      q += __shfl_xor(q, 16); q += __shfl_xor(q, 32);
      mx = fmaxf(mx, __shfl_xor(mx, 16)); mx = fmaxf(mx, __shfl_xor(mx, 32));
      mn = fminf(mn, __shfl_xor(mn, 16)); mn = fminf(mn, __shfl_xor(mn, 32));
      if (lane < 16) {
        int cidx = wn * 64 + n * 16 + lane;
        sS[wm * 128 + cidx] = s;
        sQ[wm * 128 + cidx] = q;
        sMx[wm * 128 + cidx] = mx;
        sMn[wm * 128 + cidx] = mn;
      }
    }
    __syncthreads();
    if (tid < 128) {
      float bcol = bias3[col0 + tid];
      float S = sS[tid] + sS[128 + tid];
      float Q = sQ[tid] + sQ[128 + tid];
      size_t o = (size_t)rblk * 1024 + col0 + tid;
      pS[o] = S + 128.f * bcol;
      pQ[o] = Q + 2.f * bcol * S + 128.f * bcol * bcol;
      pMx[o] = fmaxf(sMx[tid], sMx[128 + tid]) + bcol;
      pMn[o] = fminf(sMn[tid], sMn[128 + tid]) + bcol;
    }
    __syncthreads();
  }
}

// ---------------- bn3 finalize + masked max-pool ----------------
__global__ __launch_bounds__(256) void bn3fin_pool_kernel(const float* __restrict__ pS,
                                                          const float* __restrict__ pQ,
                                                          const float* __restrict__ pMx,
                                                          const float* __restrict__ pMn,
                                                          const float* __restrict__ g,
                                                          const float* __restrict__ be,
                                                          float* __restrict__ pooled) {
  int tid = threadIdx.x;
  int chl = tid & 15, grp = tid >> 4;
  int c = blockIdx.x * 16 + chl;
  float s = 0.f, q = 0.f;
  for (int i = grp; i < 512; i += 16) {
    s += pS[(size_t)i * 1024 + c];
    q += pQ[(size_t)i * 1024 + c];
  }
  __shared__ float ls[256], lq[256], sa[16], sc[16];
  ls[chl * 16 + grp] = s;
  lq[chl * 16 + grp] = q;
  __syncthreads();
  if (tid < 16) {
    float ss = 0.f, qq = 0.f;
#pragma unroll
    for (int i = 0; i < 16; i++) { ss += ls[tid * 16 + i]; qq += lq[tid * 16 + i]; }
    float m = ss * (1.0f / 65536.0f);
    float v = qq * (1.0f / 65536.0f) - m * m;
    float a = g[blockIdx.x * 16 + tid] / sqrtf(v + EPS_BN);
    sa[tid] = a;
    sc[tid] = be[blockIdx.x * 16 + tid] - m * a;
  }
  __syncthreads();
  for (int idx = tid; idx < 512; idx += 256) {
    int b = idx >> 4, l = idx & 15;
    int cc = blockIdx.x * 16 + l;
    float mx = -3.4e38f, mn = 3.4e38f;
    for (int i = 0; i < 16; i++) {
      mx = fmaxf(mx, pMx[(size_t)(b * 16 + i) * 1024 + cc]);
      mn = fminf(mn, pMn[(size_t)(b * 16 + i) * 1024 + cc]);
    }
    float a = sa[l];
    float v = (a > 0.f) ? (a * mx + sc[l]) : (a * mn + sc[l]);
    pooled[(size_t)b * 1024 + cc] = fmaxf(v, 0.f);
  }
}

// ---------------- fc1: wave-per-output ----------------
__global__ __launch_bounds__(256) void fc1_kernel(const float* __restrict__ pooled,
                                                  const float* __restrict__ w,
                                                  const float* __restrict__ bias,
                                                  float* __restrict__ zf1) {
  int gw = blockIdx.x * 4 + (threadIdx.x >> 6);
  int lane = threadIdx.x & 63;
  int b = gw >> 9, o = gw & 511;
  const float4* pr = (const float4*)(pooled + (size_t)b * 1024);
  const float4* wr = (const float4*)(w + (size_t)o * 1024);
  float acc = 0.f;
#pragma unroll
  for (int i = 0; i < 4; i++) {
    int k = lane + i * 64;
    float4 p = pr[k], q = wr[k];
    acc += p.x * q.x + p.y * q.y + p.z * q.z + p.w * q.w;
  }
  acc = wave_reduce_add(acc);
  if (lane == 0) zf1[gw] = acc + bias[o];
}

__global__ __launch_bounds__(256) void statsF_kernel(const float* __restrict__ z,
                                                     const float* __restrict__ g,
                                                     const float* __restrict__ be, int C,
                                                     float* __restrict__ scale,
                                                     float* __restrict__ shift) {
  int c = blockIdx.x * 256 + threadIdx.x;
  if (c >= C) return;
  float s = 0.f, q = 0.f;
  for (int b = 0; b < 32; b++) {
    float v = z[(size_t)b * C + c];
    s += v;
    q += v * v;
  }
  float m = s * (1.0f / 32.0f);
  float v = q * (1.0f / 32.0f) - m * m;
  float a = g[c] / sqrtf(v + EPS_BN);
  scale[c] = a;
  shift[c] = be[c] - m * a;
}

// ---------------- fc2: wave-per-output ----------------
__global__ __launch_bounds__(256) void fc2_kernel(const float* __restrict__ zf1,
                                                  const float* __restrict__ sf1,
                                                  const float* __restrict__ hf1,
                                                  const float* __restrict__ w,
                                                  const float* __restrict__ bias,
                                                  float* __restrict__ zf2) {
  int gw = blockIdx.x * 4 + (threadIdx.x >> 6);
  int lane = threadIdx.x & 63;
  int b = gw >> 8, o = gw & 255;
  const float4* zr = (const float4*)(zf1 + (size_t)b * 512);
  const float4* sr = (const float4*)sf1;
  const float4* hr = (const float4*)hf1;
  const float4* wr = (const float4*)(w + (size_t)o * 512);
  float acc = 0.f;
#pragma unroll
  for (int i = 0; i < 2; i++) {
    int k = lane + i * 64;
    float4 z = zr[k], s = sr[k], h = hr[k], q = wr[k];
    float v0 = fmaxf(z.x * s.x + h.x, 0.f);
    float v1 = fmaxf(z.y * s.y + h.y, 0.f);
    float v2 = fmaxf(z.z * s.z + h.z, 0.f);
    float v3 = fmaxf(z.w * s.w + h.w, 0.f);
    acc += v0 * q.x + v1 * q.y + v2 * q.z + v3 * q.w;
  }
  acc = wave_reduce_add(acc);
  if (lane == 0) zf2[gw] = acc + bias[o];
}

// ---------------- head: per-block BN-f2 stats + 4 waves x 10 dots + log_softmax ----------------
__global__ __launch_bounds__(256) void head_kernel(const float* __restrict__ zf2,
                                                   const float* __restrict__ gf2,
                                                   const float* __restrict__ bef2,
                                                   const float* __restrict__ w,
                                                   const float* __restrict__ bias,
                                                   float* __restrict__ out) {
  int b = blockIdx.x, tid = threadIdx.x;
  int wv = tid >> 6, lane = tid & 63;
  __shared__ float ssf[256], shf[256], lg[40], red[2];
  {
    float s = 0.f, q = 0.f;
    for (int bb = 0; bb < 32; bb++) {
      float v = zf2[(size_t)bb * 256 + tid];
      s += v;
      q += v * v;
    }
    float m = s * (1.0f / 32.0f);
    float var = q * (1.0f / 32.0f) - m * m;
    float a = gf2[tid] / sqrtf(var + EPS_BN);
    ssf[tid] = a;
    shf[tid] = bef2[tid] - m * a;
  }
  __syncthreads();
  float4 z = ((const float4*)(zf2 + (size_t)b * 256))[lane];
  float4 s = ((const float4*)ssf)[lane];
  float4 h = ((const float4*)shf)[lane];
  float v0 = fmaxf(z.x * s.x + h.x, 0.f);
  float v1 = fmaxf(z.y * s.y + h.y, 0.f);
  float v2 = fmaxf(z.z * s.z + h.z, 0.f);
  float v3 = fmaxf(z.w * s.w + h.w, 0.f);
  for (int r = 0; r < 10; r++) {
    int o = wv * 10 + r;
    float4 q = ((const float4*)(w + (size_t)o * 256))[lane];
    float a = v0 * q.x + v1 * q.y + v2 * q.z + v3 * q.w;
    a = wave_reduce_add(a);
    if (lane == 0) lg[o] = a + bias[o];
  }
  __syncthreads();
  if (tid == 0) {
    float mx = -3.4e38f;
    for (int i = 0; i < 40; i++) mx = fmaxf(mx, lg[i]);
    float sum = 0.f;
    for (int i = 0; i < 40; i++) sum += expf(lg[i] - mx);
    red[0] = mx;
    red[1] = logf(sum);
  }
  __syncthreads();
  if (tid < 40) out[(size_t)b * 40 + tid] = lg[tid] - red[0] - red[1];
}

extern "C" void kernel_launch(void* const* d_in, const int* in_sizes, int n_in,
                              void* d_out, int out_size, void* d_ws, size_t ws_size,
                              hipStream_t stream) {
  const float* x    = (const float*)d_in[0];
  const float* c1w  = (const float*)d_in[1];
  const float* c1b  = (const float*)d_in[2];
  const float* g1   = (const float*)d_in[3];
  const float* be1  = (const float*)d_in[4];
  const float* c2w  = (const float*)d_in[5];
  const float* c2b  = (const float*)d_in[6];
  const float* g2   = (const float*)d_in[7];
  const float* be2  = (const float*)d_in[8];
  const float* c3w  = (const float*)d_in[9];
  const float* c3b  = (const float*)d_in[10];
  const float* g3   = (const float*)d_in[11];
  const float* be3  = (const float*)d_in[12];
  const float* f1w  = (const float*)d_in[13];
  const float* f1b  = (const float*)d_in[14];
  const float* gf1  = (const float*)d_in[15];
  const float* bef1 = (const float*)d_in[16];
  const float* f2w  = (const float*)d_in[17];
  const float* f2b  = (const float*)d_in[18];
  const float* gf2  = (const float*)d_in[19];
  const float* bef2 = (const float*)d_in[20];
  const float* ow   = (const float*)d_in[21];
  const float* ob   = (const float*)d_in[22];
  float* out = (float*)d_out;

  float* W = (float*)d_ws;
  float* pS     = W;                   // 524288
  float* pQ     = pS + 524288;
  float* pMx    = pQ + 524288;
  float* pMn    = pMx + 524288;
  float* part   = pMn + 524288;        // 262144 (BN1 partials 2048x64x2)
  float* part2  = part + 262144;       // 131072 (BN2 partials 512x128x2)
  float* pooled = part2 + 131072;      // 32768
  float* zf1    = pooled + 32768;      // 16384
  float* zf2    = zf1 + 16384;         // 8192
  float* s1     = zf2 + 8192;          // 64
  float* h1     = s1 + 64;
  float* s2     = h1 + 64;             // 128
  float* h2     = s2 + 128;
  float* sf1    = h2 + 128;            // 512
  float* hf1    = sf1 + 512;
  unsigned short* wbf  = (unsigned short*)(hf1 + 512);   // 131072 shorts
  unsigned short* z1bf = wbf + 131072;                   // 65536*64
  unsigned short* z2bf = z1bf + (size_t)BP * 64;         // 65536*128

  wconv_kernel<<<128, 256, 0, stream>>>(c3w, wbf);
  curv1_kernel<<<dim3(64, 32), 256, 0, stream>>>(x, c1w, c1b, z1bf, part);
  bnfinP_kernel<64, 2048><<<64, 256, 0, stream>>>(part, g1, be1, s1, h1);
  gemm2_mfma_kernel<<<512, 256, 0, stream>>>(z1bf, s1, h1, c2w, c2b, z2bf, part2);
  bnfinP_kernel<128, 512><<<128, 256, 0, stream>>>(part2, g2, be2, s2, h2);
  gemm3_mfma_kernel<<<512, 256, 0, stream>>>(z2bf, s2, h2, wbf, c3b, pS, pQ, pMx, pMn);
  bn3fin_pool_kernel<<<64, 256, 0, stream>>>(pS, pQ, pMx, pMn, g3, be3, pooled);
  fc1_kernel<<<4096, 256, 0, stream>>>(pooled, f1w, f1b, zf1);
  statsF_kernel<<<2, 256, 0, stream>>>(zf1, gf1, bef1, 512, sf1, hf1);
  fc2_kernel<<<2048, 256, 0, stream>>>(zf1, sf1, hf1, f2w, f2b, zf2);
  head_kernel<<<32, 256, 0, stream>>>(zf2, gf2, bef2, ow, ob, out);
}

// Round 13
// 130.007 us; speedup vs baseline: 6.0783x; 1.0048x over previous
//
#include <hip/hip_runtime.h>
#include <hip/hip_bf16.h>
#include <math.h>

#define EPS_BN 1e-5f

constexpr int BATCH = 32;
constexpr int NPTS  = 2048;
constexpr int BP    = BATCH * NPTS;   // 65536

using s16x8 = __attribute__((ext_vector_type(8))) short;
using u32x4 = __attribute__((ext_vector_type(4))) unsigned;
using f32x4 = __attribute__((ext_vector_type(4))) float;

static __device__ __forceinline__ unsigned short f2bf(float f) {
  union { float f; unsigned u; } x{f};
  unsigned r = x.u + 0x7fffu + ((x.u >> 16) & 1u);  // RNE
  return (unsigned short)(r >> 16);
}
static __device__ __forceinline__ float bf2f(unsigned short s) {
  union { unsigned u; float f; } x;
  x.u = ((unsigned)s) << 16;
  return x.f;
}
static __device__ __forceinline__ unsigned pk2bf(float lo, float hi) {
  __hip_bfloat162 t = __float22bfloat162_rn(float2{lo, hi});
  unsigned r;
  __builtin_memcpy(&r, &t, 4);
  return r;
}

static __device__ __forceinline__ void gload_lds16(const void* g, void* l) {
  __builtin_amdgcn_global_load_lds((const __attribute__((address_space(1))) void*)g,
                                   (__attribute__((address_space(3))) void*)l, 16, 0, 0);
}

static __device__ __forceinline__ float wave_reduce_add(float v) {
#pragma unroll
  for (int off = 32; off > 0; off >>= 1) v += __shfl_xor(v, off);
  return v;
}

// keep-6-smallest, ASCENDING list, depth-1 branchless insert (1 min + 5 med3).
static __device__ __forceinline__ void ins6(float (&nn)[6], float c) {
  float b0 = fminf(nn[0], c);
  float b1 = __builtin_amdgcn_fmed3f(c, nn[1], nn[0]);
  float b2 = __builtin_amdgcn_fmed3f(c, nn[2], nn[1]);
  float b3 = __builtin_amdgcn_fmed3f(c, nn[3], nn[2]);
  float b4 = __builtin_amdgcn_fmed3f(c, nn[4], nn[3]);
  float b5 = __builtin_amdgcn_fmed3f(c, nn[5], nn[4]);
  nn[0] = b0; nn[1] = b1; nn[2] = b2; nn[3] = b3; nn[4] = b4; nn[5] = b5;
}

// ---------------- curvature + fused layer1 ----------------
// rank by r = 0.5|q|^2 - p.q  (d2 = |p|^2 + 2r). Points stored interleaved as
// float4 {x,y,z,0.5|q|^2} with 257-stride chunks: 1 ds_read_b128 per candidate,
// single base pointer + immediate offsets, conflict-free (sub*1028 word offset).
constexpr int CHP = 257;  // float4 stride per 256-pt chunk
__global__ __launch_bounds__(256) void curv1_kernel(const float* __restrict__ x,
                                                    const float* __restrict__ c1w,
                                                    const float* __restrict__ c1b,
                                                    unsigned short* __restrict__ z1bf,
                                                    float* __restrict__ part) {
  __shared__ float4 pts[8 * CHP];   // 32896 B
  __shared__ float wT[4 * 64], lb1[64], sfeat[32 * 4];
  __shared__ float ls[256], lq[256];
  int b = blockIdx.y;
  const float* xb = x + (size_t)b * NPTS * 3;
  int tid = threadIdx.x;
  {
    int k = tid >> 6, c = tid & 63;
    wT[k * 64 + c] = c1w[c * 4 + k];
    if (tid < 64) lb1[tid] = c1b[tid];
  }
#pragma unroll
  for (int k = 0; k < 8; k++) {
    int i = k * 256 + tid;
    float qx = xb[i * 3 + 0], qy = xb[i * 3 + 1], qz = xb[i * 3 + 2];
    pts[k * CHP + tid] = make_float4(qx, qy, qz, 0.5f * (qx * qx + qy * qy + qz * qz));
  }
  __syncthreads();
  int row = blockIdx.x * 32 + (tid >> 3);
  int sub = tid & 7;
  float4 p = pts[(row >> 8) * CHP + (row & 255)];
  float px = p.x, py = p.y, pz = p.z;
  float nn[6];
#pragma unroll
  for (int j = 0; j < 6; j++) nn[j] = 3.4e38f;
  const float4* cp = pts + sub * CHP;
  for (int j = 0; j < 256; j += 4) {
    float4 q0 = cp[j + 0], q1 = cp[j + 1], q2 = cp[j + 2], q3 = cp[j + 3];
    ins6(nn, fmaf(-px, q0.x, fmaf(-py, q0.y, fmaf(-pz, q0.z, q0.w))));
    ins6(nn, fmaf(-px, q1.x, fmaf(-py, q1.y, fmaf(-pz, q1.z, q1.w))));
    ins6(nn, fmaf(-px, q2.x, fmaf(-py, q2.y, fmaf(-pz, q2.z, q2.w))));
    ins6(nn, fmaf(-px, q3.x, fmaf(-py, q3.y, fmaf(-pz, q3.z, q3.w))));
  }
  // butterfly merge across the 8 subthreads: snapshot partner's list, then insert.
#pragma unroll
  for (int m = 1; m <= 4; m <<= 1) {
    float other[6];
#pragma unroll
    for (int k = 0; k < 6; k++) other[k] = __shfl_xor(nn[k], m);
#pragma unroll
    for (int k = 0; k < 6; k++) ins6(nn, other[k]);
  }
  if (sub == 0) {
    float p2 = px * px + py * py + pz * pz;
    float dm = 0.f;
#pragma unroll
    for (int i = 1; i < 6; i++) dm += sqrtf(fmaxf(fmaf(2.f, nn[i], p2), 0.f));
    dm *= 0.2f;
    float curv = 1.0f / (1e-8f + dm);
    int lr = tid >> 3;
    sfeat[lr * 4 + 0] = px;
    sfeat[lr * 4 + 1] = py;
    sfeat[lr * 4 + 2] = pz;
    sfeat[lr * 4 + 3] = curv;
  }
  __syncthreads();
  // fused layer1: 32 rows x 64 cols; thread = (col, rowgroup of 8)
  {
    int c = tid & 63, rg = tid >> 6;
    float w0 = wT[c], w1 = wT[64 + c], w2v = wT[128 + c], w3 = wT[192 + c];
    float bb = lb1[c];
    int growbase = b * NPTS + blockIdx.x * 32;
    float s = 0.f, q = 0.f;
#pragma unroll
    for (int i = 0; i < 8; i++) {
      int lr = rg * 8 + i;
      float4 f = *(const float4*)(sfeat + lr * 4);
      float acc = bb + f.x * w0 + f.y * w1 + f.z * w2v + f.w * w3;
      s += acc;
      q += acc * acc;
      z1bf[(size_t)(growbase + lr) * 64 + c] = f2bf(acc);
    }
    ls[tid] = s;
    lq[tid] = q;
  }
  __syncthreads();
  if (tid < 64) {
    float ss = 0.f, qq = 0.f;
#pragma unroll
    for (int i = 0; i < 4; i++) { ss += ls[i * 64 + tid]; qq += lq[i * 64 + tid]; }
    size_t bid = (size_t)b * 64 + blockIdx.x;
    part[(bid * 64 + tid) * 2 + 0] = ss;
    part[(bid * 64 + tid) * 2 + 1] = qq;
  }
}

// ---------------- generic BN finalize from P partials ----------------
template <int C, int P>
__global__ __launch_bounds__(256) void bnfinP_kernel(const float* __restrict__ part,
                                                     const float* __restrict__ g,
                                                     const float* __restrict__ be,
                                                     float* __restrict__ scale,
                                                     float* __restrict__ shift) {
  int c = blockIdx.x, tid = threadIdx.x;
  float s = 0.f, q = 0.f;
  for (int i = tid; i < P; i += 256) {
    s += part[((size_t)i * C + c) * 2 + 0];
    q += part[((size_t)i * C + c) * 2 + 1];
  }
  __shared__ float ls[256], lq[256];
  ls[tid] = s; lq[tid] = q;
  __syncthreads();
  for (int off = 128; off > 0; off >>= 1) {
    if (tid < off) { ls[tid] += ls[tid + off]; lq[tid] += lq[tid + off]; }
    __syncthreads();
  }
  if (tid == 0) {
    float m = ls[0] * (1.0f / 65536.0f);
    float v = lq[0] * (1.0f / 65536.0f) - m * m;
    float a = g[c] / sqrtf(v + EPS_BN);
    scale[c] = a;
    shift[c] = be[c] - m * a;
  }
}

// ---------------- w3 + w2 -> bf16 (one launch) ----------------
__global__ __launch_bounds__(256) void wconv_kernel(const float* __restrict__ w3,
                                                    const float* __restrict__ w2,
                                                    unsigned short* __restrict__ w3bf,
                                                    unsigned short* __restrict__ w2bf) {
  int g = blockIdx.x * 256 + threadIdx.x;
  if (blockIdx.x < 128) {
    const float4 v = ((const float4*)w3)[g];
    unsigned short* d = w3bf + (size_t)g * 4;
    d[0] = f2bf(v.x); d[1] = f2bf(v.y); d[2] = f2bf(v.z); d[3] = f2bf(v.w);
  } else {
    int gg = g - 128 * 256;  // 0..2047
    const float4 v = ((const float4*)w2)[gg];
    unsigned short* d = w2bf + (size_t)gg * 4;
    d[0] = f2bf(v.x); d[1] = f2bf(v.y); d[2] = f2bf(v.z); d[3] = f2bf(v.w);
  }
}

// ---------------- layer2 MFMA: relu(bn1(z1bf)) @ W2^T + b2 -> z2bf + BN2 stats ----------------
__global__ __launch_bounds__(256) void gemm2_mfma_kernel(const unsigned short* __restrict__ z1bf,
                                                         const float* __restrict__ s1,
                                                         const float* __restrict__ h1,
                                                         const unsigned short* __restrict__ w2bf,
                                                         const float* __restrict__ bias2,
                                                         unsigned short* __restrict__ z2bf,
                                                         float* __restrict__ part2) {
  __shared__ char lds[33280];  // A @0 (16KB), B @16384 (16KB), s1h1 @32768
  float* ls1 = (float*)(lds + 32768);
  float* lh1 = ls1 + 64;
  int tid = threadIdx.x;
  int row0 = blockIdx.x * 128;
  if (tid < 64) { ls1[tid] = s1[tid]; lh1[tid] = h1[tid]; }

  s16x8 araw[4], braw[4];
#pragma unroll
  for (int i = 0; i < 4; i++) {
    int L = tid + 256 * i;  // 16B chunk id, 0..1023
    araw[i] = *(const s16x8*)(z1bf + (size_t)row0 * 64 + (size_t)L * 8);
    braw[i] = *(const s16x8*)(w2bf + (size_t)L * 8);  // (L>>3)*64 + (L&7)*8 == L*8
  }
  __syncthreads();  // ls1/lh1 ready

#pragma unroll
  for (int i = 0; i < 4; i++) {
    int L = tid + 256 * i;
    int row = L >> 3, grp = L & 7, k0 = grp * 8;
    float4 sA = *(const float4*)(ls1 + k0);
    float4 sB = *(const float4*)(ls1 + k0 + 4);
    float4 hA = *(const float4*)(lh1 + k0);
    float4 hB = *(const float4*)(lh1 + k0 + 4);
    float v0 = fmaxf(bf2f((unsigned short)araw[i][0]) * sA.x + hA.x, 0.f);
    float v1 = fmaxf(bf2f((unsigned short)araw[i][1]) * sA.y + hA.y, 0.f);
    float v2 = fmaxf(bf2f((unsigned short)araw[i][2]) * sA.z + hA.z, 0.f);
    float v3 = fmaxf(bf2f((unsigned short)araw[i][3]) * sA.w + hA.w, 0.f);
    float v4 = fmaxf(bf2f((unsigned short)araw[i][4]) * sB.x + hB.x, 0.f);
    float v5 = fmaxf(bf2f((unsigned short)araw[i][5]) * sB.y + hB.y, 0.f);
    float v6 = fmaxf(bf2f((unsigned short)araw[i][6]) * sB.z + hB.z, 0.f);
    float v7 = fmaxf(bf2f((unsigned short)araw[i][7]) * sB.w + hB.w, 0.f);
    u32x4 pa = {pk2bf(v0, v1), pk2bf(v2, v3), pk2bf(v4, v5), pk2bf(v6, v7)};
    *(u32x4*)(lds + row * 128 + ((grp ^ (row & 7)) << 4)) = pa;
    *(s16x8*)(lds + 16384 + row * 128 + ((grp ^ (row & 7)) << 4)) = braw[i];
  }
  __syncthreads();

  int w = tid >> 6, lane = tid & 63;
  int wm = w >> 1, wn = w & 1;
  int lrow = lane & 15, lg = lane >> 4;
  int sw = (lrow & 7) << 4;
  f32x4 acc[4][4] = {};
#pragma unroll
  for (int kstep = 0; kstep < 2; kstep++) {
    s16x8 a[4], bfr[4];
#pragma unroll
    for (int m = 0; m < 4; m++) {
      int row = wm * 64 + m * 16 + lrow;
      int byte = row * 128 + ((kstep * 64 + lg * 16) ^ sw);
      a[m] = *(const s16x8*)(lds + byte);
    }
#pragma unroll
    for (int n = 0; n < 4; n++) {
      int col = wn * 64 + n * 16 + lrow;
      int byte = 16384 + col * 128 + ((kstep * 64 + lg * 16) ^ sw);
      bfr[n] = *(const s16x8*)(lds + byte);
    }
#pragma unroll
    for (int m = 0; m < 4; m++)
#pragma unroll
      for (int n = 0; n < 4; n++)
        acc[m][n] = __builtin_amdgcn_mfma_f32_16x16x32_bf16(a[m], bfr[n], acc[m][n], 0, 0, 0);
  }
  __syncthreads();

  float* sS = (float*)lds;
  float* sQ = sS + 256;
#pragma unroll
  for (int n = 0; n < 4; n++) {
    int col = wn * 64 + n * 16 + lrow;
    float bb = bias2[col];
    float s = 0.f, q = 0.f;
#pragma unroll
    for (int m = 0; m < 4; m++) {
#pragma unroll
      for (int r = 0; r < 4; r++) {
        float v = acc[m][n][r] + bb;
        s += v;
        q += v * v;
        int row = row0 + wm * 64 + m * 16 + lg * 4 + r;
        z2bf[(size_t)row * 128 + col] = f2bf(v);
      }
    }
    s += __shfl_xor(s, 16); s += __shfl_xor(s, 32);
    q += __shfl_xor(q, 16); q += __shfl_xor(q, 32);
    if (lane < 16) {
      int cidx = wn * 64 + n * 16 + lane;
      sS[wm * 128 + cidx] = s;
      sQ[wm * 128 + cidx] = q;
    }
  }
  __syncthreads();
  if (tid < 128) {
    part2[((size_t)blockIdx.x * 128 + tid) * 2 + 0] = sS[tid] + sS[128 + tid];
    part2[((size_t)blockIdx.x * 128 + tid) * 2 + 1] = sQ[tid] + sQ[128 + tid];
  }
}

// ---------------- layer3 MFMA: one block per 128-row panel, loop over 8 col-blocks.
// A transformed ONCE in reg-staging; stats accumulate RAW acc, bias folded at finalize.
__global__ __launch_bounds__(256) void gemm3_mfma_kernel(const unsigned short* __restrict__ z2bf,
                                                         const float* __restrict__ s2,
                                                         const float* __restrict__ h2,
                                                         const unsigned short* __restrict__ wbf,
                                                         const float* __restrict__ bias3,
                                                         float* __restrict__ pS,
                                                         float* __restrict__ pQ,
                                                         float* __restrict__ pMx,
                                                         float* __restrict__ pMn) {
  __shared__ char lds[70656];  // A[0,32768) B[32768,65536) scratch[65536,69632) s2h2[69632,70656)
  float* ls2 = (float*)(lds + 69632);
  float* lh2 = ls2 + 128;
  int tid = threadIdx.x;
  int w = tid >> 6, lane = tid & 63;
  int bid = blockIdx.x;                 // 512 blocks, XCD-chunked
  int rblk = (bid & 7) * 64 + (bid >> 3);
  int row0 = rblk * 128;

  if (tid < 128) { ls2[tid] = s2[tid]; lh2[tid] = h2[tid]; }
  s16x8 araw[8];
#pragma unroll
  for (int i = 0; i < 8; i++) {
    int L = tid + 256 * i;
    int row = L >> 4, gc = L & 15;
    araw[i] = *(const s16x8*)(z2bf + (size_t)(row0 + row) * 128 + gc * 8);
  }
  __syncthreads();
#pragma unroll
  for (int i = 0; i < 8; i++) {
    int L = tid + 256 * i;
    int row = L >> 4, gc = L & 15, k0 = gc * 8;
    float4 sA = *(const float4*)(ls2 + k0);
    float4 sB = *(const float4*)(ls2 + k0 + 4);
    float4 hA = *(const float4*)(lh2 + k0);
    float4 hB = *(const float4*)(lh2 + k0 + 4);
    float v0 = fmaxf(bf2f((unsigned short)araw[i][0]) * sA.x + hA.x, 0.f);
    float v1 = fmaxf(bf2f((unsigned short)araw[i][1]) * sA.y + hA.y, 0.f);
    float v2 = fmaxf(bf2f((unsigned short)araw[i][2]) * sA.z + hA.z, 0.f);
    float v3 = fmaxf(bf2f((unsigned short)araw[i][3]) * sA.w + hA.w, 0.f);
    float v4 = fmaxf(bf2f((unsigned short)araw[i][4]) * sB.x + hB.x, 0.f);
    float v5 = fmaxf(bf2f((unsigned short)araw[i][5]) * sB.y + hB.y, 0.f);
    float v6 = fmaxf(bf2f((unsigned short)araw[i][6]) * sB.z + hB.z, 0.f);
    float v7 = fmaxf(bf2f((unsigned short)araw[i][7]) * sB.w + hB.w, 0.f);
    u32x4 pa = {pk2bf(v0, v1), pk2bf(v2, v3), pk2bf(v4, v5), pk2bf(v6, v7)};
    *(u32x4*)(lds + row * 256 + ((gc ^ (row & 7)) << 4)) = pa;
  }

  int wm = w >> 1, wn = w & 1;
  int lrow = lane & 15, lg = lane >> 4;
  int sw = (lrow & 7) << 4;
  float* sS = (float*)(lds + 65536);   // [2][128]
  float* sQ = sS + 256;
  float* sMx = sQ + 256;
  float* sMn = sMx + 256;

  for (int cblk = 0; cblk < 8; cblk++) {
    int col0 = cblk * 128;
#pragma unroll
    for (int i = 0; i < 8; i++) {
      int ldsoff = w * 8192 + i * 1024;
      int lin = ldsoff + lane * 16;
      int row = lin >> 8;
      int gc = (lin >> 4) & 15;
      int gcl = gc ^ (row & 7);
      gload_lds16(wbf + (size_t)(col0 + row) * 128 + gcl * 8, &lds[32768 + ldsoff]);
    }
    __syncthreads();

    f32x4 acc[4][4] = {};
#pragma unroll
    for (int kstep = 0; kstep < 4; kstep++) {
      s16x8 a[4], b[4];
#pragma unroll
      for (int m = 0; m < 4; m++) {
        int row = wm * 64 + m * 16 + lrow;
        int byte = row * 256 + ((kstep * 64 + lg * 16) ^ sw);
        a[m] = *(const s16x8*)(lds + byte);
      }
#pragma unroll
      for (int n = 0; n < 4; n++) {
        int col = wn * 64 + n * 16 + lrow;
        int byte = 32768 + col * 256 + ((kstep * 64 + lg * 16) ^ sw);
        b[n] = *(const s16x8*)(lds + byte);
      }
#pragma unroll
      for (int m = 0; m < 4; m++)
#pragma unroll
        for (int n = 0; n < 4; n++)
          acc[m][n] = __builtin_amdgcn_mfma_f32_16x16x32_bf16(a[m], b[n], acc[m][n], 0, 0, 0);
    }

    // RAW per-column stats (bias deferred to finalize)
#pragma unroll
    for (int n = 0; n < 4; n++) {
      float s = 0.f, q = 0.f, mx = -3.4e38f, mn = 3.4e38f;
#pragma unroll
      for (int m = 0; m < 4; m++)
#pragma unroll
        for (int r = 0; r < 4; r++) {
          float v = acc[m][n][r];
          s += v;
          q = fmaf(v, v, q);
          mx = fmaxf(mx, v);
          mn = fminf(mn, v);
        }
      s += __shfl_xor(s, 16); s += __shfl_xor(s, 32);
      q += __shfl_xor(q, 16); q += __shfl_xor(q, 32);
      mx = fmaxf(mx, __shfl_xor(mx, 16)); mx = fmaxf(mx, __shfl_xor(mx, 32));
      mn = fminf(mn, __shfl_xor(mn, 16)); mn = fminf(mn, __shfl_xor(mn, 32));
      if (lane < 16) {
        int cidx = wn * 64 + n * 16 + lane;
        sS[wm * 128 + cidx] = s;
        sQ[wm * 128 + cidx] = q;
        sMx[wm * 128 + cidx] = mx;
        sMn[wm * 128 + cidx] = mn;
      }
    }
    __syncthreads();
    if (tid < 128) {
      float bcol = bias3[col0 + tid];
      float S = sS[tid] + sS[128 + tid];
      float Q = sQ[tid] + sQ[128 + tid];
      size_t o = (size_t)rblk * 1024 + col0 + tid;
      pS[o] = S + 128.f * bcol;
      pQ[o] = Q + 2.f * bcol * S + 128.f * bcol * bcol;
      pMx[o] = fmaxf(sMx[tid], sMx[128 + tid]) + bcol;
      pMn[o] = fminf(sMn[tid], sMn[128 + tid]) + bcol;
    }
    __syncthreads();
  }
}

// ---------------- bn3 finalize + masked max-pool ----------------
__global__ __launch_bounds__(256) void bn3fin_pool_kernel(const float* __restrict__ pS,
                                                          const float* __restrict__ pQ,
                                                          const float* __restrict__ pMx,
                                                          const float* __restrict__ pMn,
                                                          const float* __restrict__ g,
                                                          const float* __restrict__ be,
                                                          float* __restrict__ pooled) {
  int tid = threadIdx.x;
  int chl = tid & 15, grp = tid >> 4;
  int c = blockIdx.x * 16 + chl;
  float s = 0.f, q = 0.f;
  for (int i = grp; i < 512; i += 16) {
    s += pS[(size_t)i * 1024 + c];
    q += pQ[(size_t)i * 1024 + c];
  }
  __shared__ float ls[256], lq[256], sa[16], sc[16];
  ls[chl * 16 + grp] = s;
  lq[chl * 16 + grp] = q;
  __syncthreads();
  if (tid < 16) {
    float ss = 0.f, qq = 0.f;
#pragma unroll
    for (int i = 0; i < 16; i++) { ss += ls[tid * 16 + i]; qq += lq[tid * 16 + i]; }
    float m = ss * (1.0f / 65536.0f);
    float v = qq * (1.0f / 65536.0f) - m * m;
    float a = g[blockIdx.x * 16 + tid] / sqrtf(v + EPS_BN);
    sa[tid] = a;
    sc[tid] = be[blockIdx.x * 16 + tid] - m * a;
  }
  __syncthreads();
  for (int idx = tid; idx < 512; idx += 256) {
    int b = idx >> 4, l = idx & 15;
    int cc = blockIdx.x * 16 + l;
    float mx = -3.4e38f, mn = 3.4e38f;
    for (int i = 0; i < 16; i++) {
      mx = fmaxf(mx, pMx[(size_t)(b * 16 + i) * 1024 + cc]);
      mn = fminf(mn, pMn[(size_t)(b * 16 + i) * 1024 + cc]);
    }
    float a = sa[l];
    float v = (a > 0.f) ? (a * mx + sc[l]) : (a * mn + sc[l]);
    pooled[(size_t)b * 1024 + cc] = fmaxf(v, 0.f);
  }
}

// ---------------- fc1: wave-per-output ----------------
__global__ __launch_bounds__(256) void fc1_kernel(const float* __restrict__ pooled,
                                                  const float* __restrict__ w,
                                                  const float* __restrict__ bias,
                                                  float* __restrict__ zf1) {
  int gw = blockIdx.x * 4 + (threadIdx.x >> 6);
  int lane = threadIdx.x & 63;
  int b = gw >> 9, o = gw & 511;
  const float4* pr = (const float4*)(pooled + (size_t)b * 1024);
  const float4* wr = (const float4*)(w + (size_t)o * 1024);
  float acc = 0.f;
#pragma unroll
  for (int i = 0; i < 4; i++) {
    int k = lane + i * 64;
    float4 p = pr[k], q = wr[k];
    acc += p.x * q.x + p.y * q.y + p.z * q.z + p.w * q.w;
  }
  acc = wave_reduce_add(acc);
  if (lane == 0) zf1[gw] = acc + bias[o];
}

__global__ __launch_bounds__(256) void statsF_kernel(const float* __restrict__ z,
                                                     const float* __restrict__ g,
                                                     const float* __restrict__ be, int C,
                                                     float* __restrict__ scale,
                                                     float* __restrict__ shift) {
  int c = blockIdx.x * 256 + threadIdx.x;
  if (c >= C) return;
  float s = 0.f, q = 0.f;
  for (int b = 0; b < 32; b++) {
    float v = z[(size_t)b * C + c];
    s += v;
    q += v * v;
  }
  float m = s * (1.0f / 32.0f);
  float v = q * (1.0f / 32.0f) - m * m;
  float a = g[c] / sqrtf(v + EPS_BN);
  scale[c] = a;
  shift[c] = be[c] - m * a;
}

// ---------------- fc2: wave-per-output ----------------
__global__ __launch_bounds__(256) void fc2_kernel(const float* __restrict__ zf1,
                                                  const float* __restrict__ sf1,
                                                  const float* __restrict__ hf1,
                                                  const float* __restrict__ w,
                                                  const float* __restrict__ bias,
                                                  float* __restrict__ zf2) {
  int gw = blockIdx.x * 4 + (threadIdx.x >> 6);
  int lane = threadIdx.x & 63;
  int b = gw >> 8, o = gw & 255;
  const float4* zr = (const float4*)(zf1 + (size_t)b * 512);
  const float4* sr = (const float4*)sf1;
  const float4* hr = (const float4*)hf1;
  const float4* wr = (const float4*)(w + (size_t)o * 512);
  float acc = 0.f;
#pragma unroll
  for (int i = 0; i < 2; i++) {
    int k = lane + i * 64;
    float4 z = zr[k], s = sr[k], h = hr[k], q = wr[k];
    float v0 = fmaxf(z.x * s.x + h.x, 0.f);
    float v1 = fmaxf(z.y * s.y + h.y, 0.f);
    float v2 = fmaxf(z.z * s.z + h.z, 0.f);
    float v3 = fmaxf(z.w * s.w + h.w, 0.f);
    acc += v0 * q.x + v1 * q.y + v2 * q.z + v3 * q.w;
  }
  acc = wave_reduce_add(acc);
  if (lane == 0) zf2[gw] = acc + bias[o];
}

// ---------------- head: per-block BN-f2 stats + 4 waves x 10 dots + log_softmax ----------------
__global__ __launch_bounds__(256) void head_kernel(const float* __restrict__ zf2,
                                                   const float* __restrict__ gf2,
                                                   const float* __restrict__ bef2,
                                                   const float* __restrict__ w,
                                                   const float* __restrict__ bias,
                                                   float* __restrict__ out) {
  int b = blockIdx.x, tid = threadIdx.x;
  int wv = tid >> 6, lane = tid & 63;
  __shared__ float ssf[256], shf[256], lg[40], red[2];
  {
    float s = 0.f, q = 0.f;
    for (int bb = 0; bb < 32; bb++) {
      float v = zf2[(size_t)bb * 256 + tid];
      s += v;
      q += v * v;
    }
    float m = s * (1.0f / 32.0f);
    float var = q * (1.0f / 32.0f) - m * m;
    float a = gf2[tid] / sqrtf(var + EPS_BN);
    ssf[tid] = a;
    shf[tid] = bef2[tid] - m * a;
  }
  __syncthreads();
  float4 z = ((const float4*)(zf2 + (size_t)b * 256))[lane];
  float4 s = ((const float4*)ssf)[lane];
  float4 h = ((const float4*)shf)[lane];
  float v0 = fmaxf(z.x * s.x + h.x, 0.f);
  float v1 = fmaxf(z.y * s.y + h.y, 0.f);
  float v2 = fmaxf(z.z * s.z + h.z, 0.f);
  float v3 = fmaxf(z.w * s.w + h.w, 0.f);
  for (int r = 0; r < 10; r++) {
    int o = wv * 10 + r;
    float4 q = ((const float4*)(w + (size_t)o * 256))[lane];
    float a = v0 * q.x + v1 * q.y + v2 * q.z + v3 * q.w;
    a = wave_reduce_add(a);
    if (lane == 0) lg[o] = a + bias[o];
  }
  __syncthreads();
  if (tid == 0) {
    float mx = -3.4e38f;
    for (int i = 0; i < 40; i++) mx = fmaxf(mx, lg[i]);
    float sum = 0.f;
    for (int i = 0; i < 40; i++) sum += expf(lg[i] - mx);
    red[0] = mx;
    red[1] = logf(sum);
  }
  __syncthreads();
  if (tid < 40) out[(size_t)b * 40 + tid] = lg[tid] - red[0] - red[1];
}

extern "C" void kernel_launch(void* const* d_in, const int* in_sizes, int n_in,
                              void* d_out, int out_size, void* d_ws, size_t ws_size,
                              hipStream_t stream) {
  const float* x    = (const float*)d_in[0];
  const float* c1w  = (const float*)d_in[1];
  const float* c1b  = (const float*)d_in[2];
  const float* g1   = (const float*)d_in[3];
  const float* be1  = (const float*)d_in[4];
  const float* c2w  = (const float*)d_in[5];
  const float* c2b  = (const float*)d_in[6];
  const float* g2   = (const float*)d_in[7];
  const float* be2  = (const float*)d_in[8];
  const float* c3w  = (const float*)d_in[9];
  const float* c3b  = (const float*)d_in[10];
  const float* g3   = (const float*)d_in[11];
  const float* be3  = (const float*)d_in[12];
  const float* f1w  = (const float*)d_in[13];
  const float* f1b  = (const float*)d_in[14];
  const float* gf1  = (const float*)d_in[15];
  const float* bef1 = (const float*)d_in[16];
  const float* f2w  = (const float*)d_in[17];
  const float* f2b  = (const float*)d_in[18];
  const float* gf2  = (const float*)d_in[19];
  const float* bef2 = (const float*)d_in[20];
  const float* ow   = (const float*)d_in[21];
  const float* ob   = (const float*)d_in[22];
  float* out = (float*)d_out;

  float* W = (float*)d_ws;
  float* pS     = W;                   // 524288
  float* pQ     = pS + 524288;
  float* pMx    = pQ + 524288;
  float* pMn    = pMx + 524288;
  float* part   = pMn + 524288;        // 262144 (BN1 partials 2048x64x2)
  float* part2  = part + 262144;       // 131072 (BN2 partials 512x128x2)
  float* pooled = part2 + 131072;      // 32768
  float* zf1    = pooled + 32768;      // 16384
  float* zf2    = zf1 + 16384;         // 8192
  float* s1     = zf2 + 8192;          // 64
  float* h1     = s1 + 64;
  float* s2     = h1 + 64;             // 128
  float* h2     = s2 + 128;
  float* sf1    = h2 + 128;            // 512
  float* hf1    = sf1 + 512;
  unsigned short* wbf  = (unsigned short*)(hf1 + 512);   // 131072 shorts (w3 bf16)
  unsigned short* w2bf = wbf + 131072;                   // 8192 shorts (w2 bf16)
  unsigned short* z1bf = w2bf + 8192;                    // 65536*64
  unsigned short* z2bf = z1bf + (size_t)BP * 64;         // 65536*128

  wconv_kernel<<<136, 256, 0, stream>>>(c3w, c2w, wbf, w2bf);
  curv1_kernel<<<dim3(64, 32), 256, 0, stream>>>(x, c1w, c1b, z1bf, part);
  bnfinP_kernel<64, 2048><<<64, 256, 0, stream>>>(part, g1, be1, s1, h1);
  gemm2_mfma_kernel<<<512, 256, 0, stream>>>(z1bf, s1, h1, w2bf, c2b, z2bf, part2);
  bnfinP_kernel<128, 512><<<128, 256, 0, stream>>>(part2, g2, be2, s2, h2);
  gemm3_mfma_kernel<<<512, 256, 0, stream>>>(z2bf, s2, h2, wbf, c3b, pS, pQ, pMx, pMn);
  bn3fin_pool_kernel<<<64, 256, 0, stream>>>(pS, pQ, pMx, pMn, g3, be3, pooled);
  fc1_kernel<<<4096, 256, 0, stream>>>(pooled, f1w, f1b, zf1);
  statsF_kernel<<<2, 256, 0, stream>>>(zf1, gf1, bef1, 512, sf1, hf1);
  fc2_kernel<<<2048, 256, 0, stream>>>(zf1, sf1, hf1, f2w, f2b, zf2);
  head_kernel<<<32, 256, 0, stream>>>(zf2, gf2, bef2, ow, ob, out);
}